// Round 1
// baseline (1173.532 us; speedup 1.0000x reference)
//
#include <hip/hip_runtime.h>
#include <math.h>

#define B_ 64
#define S_ 128
#define F_ 62
#define D_ 256
#define H_ 4
#define L_ 6
#define NSUB_ 32
#define DFF_ 512
#define DH_ 128
#define DEPTH_ 32
#define MS_ (B_*S_)                 // 8192 rows
#define NEGV (-1000000000.0f)
#define SCALE_ 0.17677669529663687f // 1/sqrt(32)

// ---------------- mask: (sum_F x == 0) * NEG, pre-multiplied ----------------
__global__ __launch_bounds__(256) void mask_kernel(const float* __restrict__ x,
                                                   float* __restrict__ maskb){
  int r = blockIdx.x*256 + threadIdx.x;
  if(r >= MS_) return;
  const float* row = x + (size_t)r*F_;
  float s = 0.f;
  #pragma unroll
  for(int f=0; f<F_; f++) s += row[f];
  maskb[r] = (s == 0.0f) ? NEGV : 0.0f;
}

// ------------- dist rescale: (1+e)/(1+exp(1-w)) * scale (pre-scaled) --------
__global__ __launch_bounds__(256) void rescale_kernel(const float* __restrict__ dist,
                                                      float* __restrict__ distr){
  int i = blockIdx.x*256 + threadIdx.x;
  float w = dist[i];
  const float e1 = 2.718281828459045f;
  distr[i] = (1.0f + e1) / (1.0f + expf(1.0f - w)) * SCALE_;
}

// ---------------- embed: h = relu(x @ emb_W + emb_b), K=62 ------------------
__global__ __launch_bounds__(256) void embed_kernel(const float* __restrict__ x,
    const float* __restrict__ W, const float* __restrict__ bias,
    float* __restrict__ h){
  __shared__ float xs[4][F_];
  int r0 = blockIdx.x*4;
  int t = threadIdx.x;
  if(t < 4*F_){ int rr = t / F_, ff = t - rr*F_; xs[rr][ff] = x[(size_t)(r0+rr)*F_ + ff]; }
  __syncthreads();
  float b = bias[t];
  float a0=b, a1=b, a2=b, a3=b;
  for(int k=0; k<F_; k++){
    float w = W[k*D_ + t];
    a0 = fmaf(xs[0][k], w, a0);
    a1 = fmaf(xs[1][k], w, a1);
    a2 = fmaf(xs[2][k], w, a2);
    a3 = fmaf(xs[3][k], w, a3);
  }
  h[(size_t)(r0+0)*D_ + t] = fmaxf(a0, 0.f);
  h[(size_t)(r0+1)*D_ + t] = fmaxf(a1, 0.f);
  h[(size_t)(r0+2)*D_ + t] = fmaxf(a2, 0.f);
  h[(size_t)(r0+3)*D_ + t] = fmaxf(a3, 0.f);
}

// ---------------- generic 64x64-tile GEMM, 256 thr, 4x4/thread --------------
__device__ __forceinline__ float apply_act(float v, int act){
  if(act == 1) return fmaxf(v, 0.f);
  if(act == 2) return 0.5f*v*(1.0f + erff(v*0.70710678118654752f)); // exact gelu
  return v;
}

__device__ __forceinline__ void gemm_tile_64x64(
    const float* __restrict__ A, int lda,
    const float* __restrict__ W, int ldw,
    const float* __restrict__ bias,
    float* __restrict__ C, int ldc,
    int K, int act, int m0, int n0)
{
  __shared__ float As[16][64];   // [k][m] (transposed)
  __shared__ float Ws[16][64];   // [k][n]
  const int t  = threadIdx.x;
  const int tm = (t & 15) * 4;
  const int tn = (t >> 4) * 4;
  const int lm = t >> 2;         // A-tile row    0..63
  const int lk = (t & 3) * 4;    // A-tile k base 0,4,8,12
  const int wk = t >> 4;         // W-tile k      0..15
  const int wn = (t & 15) * 4;   // W-tile n base 0..60
  float acc[4][4] = {};
  for(int k0 = 0; k0 < K; k0 += 16){
    float4 av = *(const float4*)(A + (size_t)(m0+lm)*lda + k0 + lk);
    float4 wv = *(const float4*)(W + (size_t)(k0+wk)*ldw + n0 + wn);
    __syncthreads();
    As[lk+0][lm] = av.x; As[lk+1][lm] = av.y; As[lk+2][lm] = av.z; As[lk+3][lm] = av.w;
    *(float4*)&Ws[wk][wn] = wv;
    __syncthreads();
    #pragma unroll
    for(int k = 0; k < 16; k++){
      float4 a = *(const float4*)&As[k][tm];
      float4 b = *(const float4*)&Ws[k][tn];
      float avr[4] = {a.x, a.y, a.z, a.w};
      float bvr[4] = {b.x, b.y, b.z, b.w};
      #pragma unroll
      for(int i = 0; i < 4; i++)
        #pragma unroll
        for(int j = 0; j < 4; j++)
          acc[i][j] = fmaf(avr[i], bvr[j], acc[i][j]);
    }
  }
  #pragma unroll
  for(int i = 0; i < 4; i++){
    float4 o;
    o.x = apply_act(acc[i][0] + bias[n0+tn+0], act);
    o.y = apply_act(acc[i][1] + bias[n0+tn+1], act);
    o.z = apply_act(acc[i][2] + bias[n0+tn+2], act);
    o.w = apply_act(acc[i][3] + bias[n0+tn+3], act);
    *(float4*)(C + (size_t)(m0+tm+i)*ldc + n0+tn) = o;
  }
}

__global__ __launch_bounds__(256) void gemm_kernel(
    const float* __restrict__ A, int lda,
    const float* __restrict__ W, int ldw,
    const float* __restrict__ bias,
    float* __restrict__ C, int ldc, int K, int act)
{
  gemm_tile_64x64(A, lda, W, ldw, bias, C, ldc, K, act, blockIdx.x*64, blockIdx.y*64);
}

// --------------- QKV: z-multiplexed 6 GEMMs (q1,k1,v1,q2,k2,v2) -------------
struct QKVArgs {
  const float* W[6];
  const float* bias[6];
  float* out[6];
};

__global__ __launch_bounds__(256) void qkv_kernel(const float* __restrict__ h,
                                                  QKVArgs args, int l){
  int z = blockIdx.z;
  int branch = z / 3;                       // 0: x1 (cols 0..127), 1: x2
  const float* A    = h + branch*DH_;
  const float* W    = args.W[z]    + (size_t)l*DH_*DH_;
  const float* bias = args.bias[z] + (size_t)l*DH_;
  float* C          = args.out[z];
  gemm_tile_64x64(A, D_, W, DH_, bias, C, DH_, DH_, 0, blockIdx.x*64, blockIdx.y*64);
}

// ---------------- fused attention: one block per (b, head, branch) ----------
__global__ __launch_bounds__(256) void attn_kernel(
    const float* __restrict__ q1, const float* __restrict__ k1, const float* __restrict__ v1,
    const float* __restrict__ q2, const float* __restrict__ k2, const float* __restrict__ v2,
    const float* __restrict__ adj, const float* __restrict__ distr,
    const float* __restrict__ maskb,
    float* __restrict__ o1, float* __restrict__ o2)
{
  __shared__ float Qs[S_*33];        // padded rows (conflict-free row access); reused as O
  __shared__ float Ks[S_][DEPTH_];
  __shared__ float Vs[S_][DEPTH_];
  __shared__ float msk[S_];
  const int bh = blockIdx.x;
  const int b  = bh >> 2;            // H_=4
  const int hh = bh & 3;
  const int branch = blockIdx.y;
  const float* Qg = branch ? q2 : q1;
  const float* Kg = branch ? k2 : k1;
  const float* Vg = branch ? v2 : v1;
  const int t = threadIdx.x;
  for(int idx = t; idx < S_*DEPTH_; idx += 256){
    int s = idx >> 5, d = idx & 31;
    size_t g = (size_t)(b*S_ + s)*DH_ + hh*DEPTH_ + d;
    Qs[s*33 + d] = Qg[g];
    Ks[s][d] = Kg[g];
    Vs[s][d] = Vg[g];
  }
  if(t < S_) msk[t] = maskb[b*S_ + t];
  __syncthreads();

  const int i  = t >> 1;             // score row 0..127, two threads per row
  const int jb = (t & 1) * 64;       // each owns 64 cols
  float q[32];
  #pragma unroll
  for(int d = 0; d < 32; d++) q[d] = Qs[i*33 + d];

  const float* arow = adj   + ((size_t)b*S_ + i)*S_ + jb;
  const float* drow = distr + ((size_t)b*S_ + i)*S_ + jb;
  float sc[64];
  if(branch == 0){
    #pragma unroll
    for(int j = 0; j < 64; j++){
      const float4* kr = (const float4*)&Ks[jb+j][0];
      float dot = 0.f;
      #pragma unroll
      for(int dq = 0; dq < 8; dq++){
        float4 kv = kr[dq];
        dot += q[dq*4+0]*kv.x + q[dq*4+1]*kv.y + q[dq*4+2]*kv.z + q[dq*4+3]*kv.w;
      }
      sc[j] = dot*SCALE_ + msk[jb+j] + arow[j];
    }
  } else {
    #pragma unroll
    for(int j = 0; j < 64; j++){
      const float4* kr = (const float4*)&Ks[jb+j][0];
      float dot = 0.f;
      #pragma unroll
      for(int dq = 0; dq < 8; dq++){
        float4 kv = kr[dq];
        dot += q[dq*4+0]*kv.x + q[dq*4+1]*kv.y + q[dq*4+2]*kv.z + q[dq*4+3]*kv.w;
      }
      sc[j] = fmaxf(dot, 0.f)*drow[j] + msk[jb+j];   // distr pre-scaled
    }
  }
  // softmax across thread pair (t, t^1)
  float m = -3.4e38f;
  #pragma unroll
  for(int j = 0; j < 64; j++) m = fmaxf(m, sc[j]);
  m = fmaxf(m, __shfl_xor(m, 1));
  float sum = 0.f;
  #pragma unroll
  for(int j = 0; j < 64; j++){ float e = __expf(sc[j] - m); sc[j] = e; sum += e; }
  sum += __shfl_xor(sum, 1);
  float inv = 1.0f / sum;
  // P @ V (partial over this thread's 64 j's)
  float o[32] = {};
  #pragma unroll
  for(int j = 0; j < 64; j++){
    float p = sc[j] * inv;
    const float4* vr = (const float4*)&Vs[jb+j][0];
    #pragma unroll
    for(int dq = 0; dq < 8; dq++){
      float4 vv = vr[dq];
      o[dq*4+0] = fmaf(p, vv.x, o[dq*4+0]);
      o[dq*4+1] = fmaf(p, vv.y, o[dq*4+1]);
      o[dq*4+2] = fmaf(p, vv.z, o[dq*4+2]);
      o[dq*4+3] = fmaf(p, vv.w, o[dq*4+3]);
    }
  }
  __syncthreads();
  if((t & 1) == 0){
    #pragma unroll
    for(int d = 0; d < 32; d++) Qs[i*33 + d] = o[d];
  }
  __syncthreads();
  if(t & 1){
    #pragma unroll
    for(int d = 0; d < 32; d++) Qs[i*33 + d] += o[d];
  }
  __syncthreads();
  float* Og = branch ? o2 : o1;
  for(int idx = t; idx < S_*DEPTH_; idx += 256){
    int s = idx >> 5, d = idx & 31;
    Og[(size_t)(b*S_ + s)*DH_ + hh*DEPTH_ + d] = Qs[s*33 + d];
  }
}

// ---------------- LayerNorm(a + res) * g + be, one wave per row -------------
__global__ __launch_bounds__(256) void ln_kernel(
    const float* __restrict__ a, const float* __restrict__ res,
    const float* __restrict__ g, const float* __restrict__ be,
    float* __restrict__ out)
{
  int w = threadIdx.x >> 6, lane = threadIdx.x & 63;
  int row = blockIdx.x*4 + w;
  const float* pa = a   + (size_t)row*D_;
  const float* pr = res + (size_t)row*D_;
  float v[4];
  float s = 0.f;
  #pragma unroll
  for(int i = 0; i < 4; i++){ int c = lane + i*64; v[i] = pa[c] + pr[c]; s += v[i]; }
  #pragma unroll
  for(int off = 32; off; off >>= 1) s += __shfl_xor(s, off);
  float mu = s * (1.0f/D_);
  float qv = 0.f;
  #pragma unroll
  for(int i = 0; i < 4; i++){ float d = v[i] - mu; qv += d*d; }
  #pragma unroll
  for(int off = 32; off; off >>= 1) qv += __shfl_xor(qv, off);
  float invs = rsqrtf(qv*(1.0f/D_) + 1e-6f);
  #pragma unroll
  for(int i = 0; i < 4; i++){
    int c = lane + i*64;
    out[(size_t)row*D_ + c] = (v[i] - mu)*invs*g[c] + be[c];
  }
}

// ---------------- pooled[b,n,:] = (amm[b,n,:] @ h[b]) / sum_atoms -----------
__global__ __launch_bounds__(256) void pool_kernel(
    const float* __restrict__ amm, const float* __restrict__ sum_atoms,
    const float* __restrict__ h, float* __restrict__ pooled)
{
  __shared__ float as[S_];
  int bn = blockIdx.x;
  int b  = bn >> 5;                  // NSUB=32
  int t  = threadIdx.x;              // output col 0..255
  if(t < S_) as[t] = amm[(size_t)bn*S_ + t];
  __syncthreads();
  float acc = 0.f;
  const float* hb = h + (size_t)b*S_*D_ + t;
  #pragma unroll 4
  for(int s = 0; s < S_; s++) acc = fmaf(as[s], hb[(size_t)s*D_], acc);
  pooled[(size_t)bn*D_ + t] = acc / sum_atoms[bn];
}

// ============================ host-side launcher ============================
extern "C" void kernel_launch(void* const* d_in, const int* in_sizes, int n_in,
                              void* d_out, int out_size, void* d_ws, size_t ws_size,
                              hipStream_t stream)
{
  const float* x     = (const float*)d_in[0];
  const float* adj   = (const float*)d_in[1];
  const float* dist  = (const float*)d_in[2];
  const float* amm   = (const float*)d_in[3];
  const float* sum_a = (const float*)d_in[4];
  const float* embW  = (const float*)d_in[5];
  const float* embB  = (const float*)d_in[6];
  const float* globW = (const float*)d_in[7];
  const float* globB = (const float*)d_in[8];
  const float* Wq1 = (const float*)d_in[9],  *Wk1 = (const float*)d_in[10],
             *Wv1 = (const float*)d_in[11], *Wo1 = (const float*)d_in[12],
             *Wq2 = (const float*)d_in[13], *Wk2 = (const float*)d_in[14],
             *Wv2 = (const float*)d_in[15], *Wo2 = (const float*)d_in[16];
  const float* bq1 = (const float*)d_in[17], *bk1 = (const float*)d_in[18],
             *bv1 = (const float*)d_in[19], *bo1 = (const float*)d_in[20],
             *bq2 = (const float*)d_in[21], *bk2 = (const float*)d_in[22],
             *bv2 = (const float*)d_in[23], *bo2 = (const float*)d_in[24];
  const float* Wf1 = (const float*)d_in[25], *bf1 = (const float*)d_in[26],
             *Wf2 = (const float*)d_in[27], *bf2 = (const float*)d_in[28],
             *g1  = (const float*)d_in[29], *be1 = (const float*)d_in[30],
             *g2  = (const float*)d_in[31], *be2 = (const float*)d_in[32];

  float* ws = (float*)d_ws;
  float* h     = ws; ws += (size_t)MS_*D_;      // 2,097,152
  float* maskb = ws; ws += MS_;                 // 8,192
  float* distr = ws; ws += (size_t)B_*S_*S_;    // 1,048,576
  float* q1b = ws; ws += (size_t)MS_*DH_;
  float* k1b = ws; ws += (size_t)MS_*DH_;
  float* v1b = ws; ws += (size_t)MS_*DH_;
  float* q2b = ws; ws += (size_t)MS_*DH_;
  float* k2b = ws; ws += (size_t)MS_*DH_;
  float* v2b = ws; ws += (size_t)MS_*DH_;
  float* o1b = ws; ws += (size_t)MS_*DH_;
  float* o2b = ws; ws += (size_t)MS_*DH_;
  float* attnb = ws; ws += (size_t)MS_*D_;      // concat[x_l|x_g]; later reused as ffn2
  float* out1  = ws; ws += (size_t)MS_*D_;
  float* pooled = ws; ws += (size_t)B_*NSUB_*D_;
  float* ffn1 = q1b;  // reuse QKV region (6.29M floats >= 4.19M needed)

  mask_kernel   <<<MS_/256,          256, 0, stream>>>(x, maskb);
  rescale_kernel<<<(B_*S_*S_)/256,   256, 0, stream>>>(dist, distr);
  embed_kernel  <<<MS_/4,            256, 0, stream>>>(x, embW, embB, h);

  QKVArgs qa;
  qa.W[0]=Wq1; qa.W[1]=Wk1; qa.W[2]=Wv1; qa.W[3]=Wq2; qa.W[4]=Wk2; qa.W[5]=Wv2;
  qa.bias[0]=bq1; qa.bias[1]=bk1; qa.bias[2]=bv1; qa.bias[3]=bq2; qa.bias[4]=bk2; qa.bias[5]=bv2;
  qa.out[0]=q1b; qa.out[1]=k1b; qa.out[2]=v1b; qa.out[3]=q2b; qa.out[4]=k2b; qa.out[5]=v2b;

  for(int l = 0; l < L_; l++){
    qkv_kernel<<<dim3(MS_/64, DH_/64, 6), 256, 0, stream>>>(h, qa, l);
    attn_kernel<<<dim3(B_*H_, 2), 256, 0, stream>>>(q1b,k1b,v1b, q2b,k2b,v2b,
                                                    adj, distr, maskb, o1b, o2b);
    gemm_kernel<<<dim3(MS_/64, 2), 256, 0, stream>>>(o1b, DH_, Wo1 + (size_t)l*DH_*DH_, DH_,
                                                     bo1 + (size_t)l*DH_, attnb,      D_, DH_, 0);
    gemm_kernel<<<dim3(MS_/64, 2), 256, 0, stream>>>(o2b, DH_, Wo2 + (size_t)l*DH_*DH_, DH_,
                                                     bo2 + (size_t)l*DH_, attnb+DH_,  D_, DH_, 0);
    ln_kernel<<<MS_/4, 256, 0, stream>>>(attnb, h, g1 + (size_t)l*D_, be1 + (size_t)l*D_, out1);
    gemm_kernel<<<dim3(MS_/64, DFF_/64), 256, 0, stream>>>(out1, D_, Wf1 + (size_t)l*D_*DFF_, DFF_,
                                                     bf1 + (size_t)l*DFF_, ffn1, DFF_, D_, 2);
    gemm_kernel<<<dim3(MS_/64, D_/64), 256, 0, stream>>>(ffn1, DFF_, Wf2 + (size_t)l*DFF_*D_, D_,
                                                     bf2 + (size_t)l*D_, attnb, D_, DFF_, 0);
    ln_kernel<<<MS_/4, 256, 0, stream>>>(attnb, out1, g2 + (size_t)l*D_, be2 + (size_t)l*D_, h);
  }

  pool_kernel<<<B_*NSUB_, 256, 0, stream>>>(amm, sum_a, h, pooled);
  gemm_kernel<<<dim3((B_*NSUB_)/64, D_/64), 256, 0, stream>>>(pooled, D_, globW, D_, globB,
                                                     (float*)d_out, D_, D_, 1);
}

// Round 2
// 795.224 us; speedup vs baseline: 1.4757x; 1.4757x over previous
//
#include <hip/hip_runtime.h>
#include <math.h>

#define B_ 64
#define S_ 128
#define F_ 62
#define D_ 256
#define H_ 4
#define L_ 6
#define NSUB_ 32
#define DFF_ 512
#define DH_ 128
#define DEPTH_ 32
#define MS_ (B_*S_)                 // 8192 rows
#define NEGV (-1000000000.0f)
#define SCALE_ 0.17677669529663687f // 1/sqrt(32)

typedef unsigned short u16;
typedef __attribute__((ext_vector_type(8))) short short8;
typedef __attribute__((ext_vector_type(4))) float f32x4;

// f32 -> bf16 round-to-nearest-even
__device__ __forceinline__ u16 f2b(float f){
  unsigned u = __float_as_uint(f);
  unsigned r = (u + 0x7fffu + ((u >> 16) & 1u)) >> 16;
  return (u16)r;
}

__device__ __forceinline__ void glds16(const void* g, void* l){
  __builtin_amdgcn_global_load_lds(
      (const __attribute__((address_space(1))) unsigned int*)g,
      (__attribute__((address_space(3))) unsigned int*)l, 16, 0, 0);
}

// ---------------- mask: (sum_F x == 0) * NEG, pre-multiplied ----------------
__global__ __launch_bounds__(256) void mask_kernel(const float* __restrict__ x,
                                                   float* __restrict__ maskb){
  int r = blockIdx.x*256 + threadIdx.x;
  if(r >= MS_) return;
  const float* row = x + (size_t)r*F_;
  float s = 0.f;
  #pragma unroll
  for(int f=0; f<F_; f++) s += row[f];
  maskb[r] = (s == 0.0f) ? NEGV : 0.0f;
}

// ------------- dist rescale: (1+e)/(1+exp(1-w)) * scale (pre-scaled) --------
__global__ __launch_bounds__(256) void rescale_kernel(const float* __restrict__ dist,
                                                      float* __restrict__ distr){
  int i = blockIdx.x*256 + threadIdx.x;
  float w = dist[i];
  const float e1 = 2.718281828459045f;
  distr[i] = (1.0f + e1) / (1.0f + expf(1.0f - w)) * SCALE_;
}

// --------- weight transpose + bf16 convert: dst[l][n][k] = src[l][k][n] -----
__global__ __launch_bounds__(256) void transpose_kernel(const float* __restrict__ src,
                                                        u16* __restrict__ dst,
                                                        int K, int N){
  __shared__ float tbuf[32][33];
  int l = blockIdx.z;
  src += (size_t)l*K*N;
  dst += (size_t)l*K*N;
  int n0 = blockIdx.x*32, k0 = blockIdx.y*32;
  int tx = threadIdx.x, ty = threadIdx.y;   // 32 x 8
  #pragma unroll
  for(int i = 0; i < 4; i++)
    tbuf[ty + i*8][tx] = src[(size_t)(k0 + ty + i*8)*N + n0 + tx];
  __syncthreads();
  #pragma unroll
  for(int i = 0; i < 4; i++)
    dst[(size_t)(n0 + ty + i*8)*K + k0 + tx] = f2b(tbuf[tx][ty + i*8]);
}

// ---------------- embed: h = relu(x @ emb_W + emb_b), K=62 ------------------
__global__ __launch_bounds__(256) void embed_kernel(const float* __restrict__ x,
    const float* __restrict__ W, const float* __restrict__ bias,
    float* __restrict__ h, u16* __restrict__ h_bf){
  __shared__ float xs[4][F_];
  int r0 = blockIdx.x*4;
  int t = threadIdx.x;
  if(t < 4*F_){ int rr = t / F_, ff = t - rr*F_; xs[rr][ff] = x[(size_t)(r0+rr)*F_ + ff]; }
  __syncthreads();
  float b = bias[t];
  float a0=b, a1=b, a2=b, a3=b;
  for(int k=0; k<F_; k++){
    float w = W[k*D_ + t];
    a0 = fmaf(xs[0][k], w, a0);
    a1 = fmaf(xs[1][k], w, a1);
    a2 = fmaf(xs[2][k], w, a2);
    a3 = fmaf(xs[3][k], w, a3);
  }
  a0 = fmaxf(a0, 0.f); a1 = fmaxf(a1, 0.f); a2 = fmaxf(a2, 0.f); a3 = fmaxf(a3, 0.f);
  h[(size_t)(r0+0)*D_ + t] = a0;  h_bf[(size_t)(r0+0)*D_ + t] = f2b(a0);
  h[(size_t)(r0+1)*D_ + t] = a1;  h_bf[(size_t)(r0+1)*D_ + t] = f2b(a1);
  h[(size_t)(r0+2)*D_ + t] = a2;  h_bf[(size_t)(r0+2)*D_ + t] = f2b(a2);
  h[(size_t)(r0+3)*D_ + t] = a3;  h_bf[(size_t)(r0+3)*D_ + t] = f2b(a3);
}

// =================== bf16 MFMA GEMM (m97-style, TNx128 tile) ================
// A: [M][lda] bf16 row-major (k contiguous), W: [N][K] bf16 (pre-transposed),
// C: f32 or bf16, C[m][n] = sum_k A[m][k]*W_t[n][k] + bias[n], then act.
struct MG {
  const u16* A; const u16* W; const float* bias; void* C;
  int lda, K, ldc, aofs, cofs;
};
struct MG6 { MG g[6]; };

template<int TM, bool OUTBF, int ACT>
__global__ __launch_bounds__(256) void mgemm_kernel(MG6 args){
  const MG p = args.g[blockIdx.z];
  __shared__ u16 As[TM*32];
  __shared__ u16 Bs[128*32];
  const int t    = threadIdx.x;
  const int lane = t & 63;
  const int w    = t >> 6;
  const int ln   = lane & 15;
  const int qd   = lane >> 4;
  const int mw   = (w & 1) * (TM/2);
  const int nw   = (w >> 1) * 64;
  const int m0   = blockIdx.x * TM;
  const int n0   = blockIdx.y * 128;
  constexpr int MI = TM/32;           // m-tiles per wave (16-row tiles)
  f32x4 acc[MI][4];
  #pragma unroll
  for(int i=0;i<MI;i++)
    #pragma unroll
    for(int j=0;j<4;j++) acc[i][j] = (f32x4){0.f,0.f,0.f,0.f};

  const int srow = t >> 2;            // staging row 0..63
  const int sc8  = (t & 3) * 8;       // staging k offset (8 bf16 = 16 B)

  for(int k0 = 0; k0 < p.K; k0 += 32){
    __syncthreads();  // protect LDS from overwrite while prior reads in flight
    // ---- stage A tile [TM][32] bf16 via global_load_lds width=16 ----
    glds16(p.A + (size_t)(m0 + srow)*p.lda + p.aofs + k0 + sc8, As + t*8);
    if(TM == 128)
      glds16(p.A + (size_t)(m0 + 64 + srow)*p.lda + p.aofs + k0 + sc8, As + (t+256)*8);
    // ---- stage B tile [128][32] bf16 ----
    glds16(p.W + (size_t)(n0 + srow)*p.K + k0 + sc8, Bs + t*8);
    glds16(p.W + (size_t)(n0 + 64 + srow)*p.K + k0 + sc8, Bs + (t+256)*8);
    __syncthreads();  // drain vmcnt (compiler emits waitcnt before barrier)

    short8 a[MI], b[4];
    #pragma unroll
    for(int i=0;i<MI;i++) a[i] = *(const short8*)&As[(mw + i*16 + ln)*32 + qd*8];
    #pragma unroll
    for(int j=0;j<4;j++)  b[j] = *(const short8*)&Bs[(nw + j*16 + ln)*32 + qd*8];
    #pragma unroll
    for(int i=0;i<MI;i++)
      #pragma unroll
      for(int j=0;j<4;j++)
        acc[i][j] = __builtin_amdgcn_mfma_f32_16x16x32_bf16(a[i], b[j], acc[i][j], 0, 0, 0);
  }

  // ---- epilogue: C/D layout col=lane&15, row=quad*4+reg ----
  #pragma unroll
  for(int i=0;i<MI;i++){
    #pragma unroll
    for(int j=0;j<4;j++){
      int col = n0 + nw + j*16 + ln;
      float bv = p.bias[col];
      int rowb = m0 + mw + i*16 + qd*4;
      #pragma unroll
      for(int r=0;r<4;r++){
        float v = acc[i][j][r] + bv;
        if(ACT == 1) v = fmaxf(v, 0.f);
        if(ACT == 2) v = 0.5f*v*(1.0f + erff(v*0.70710678118654752f));
        size_t idx = (size_t)(rowb + r)*p.ldc + p.cofs + col;
        if(OUTBF) ((u16*)p.C)[idx] = f2b(v);
        else      ((float*)p.C)[idx] = v;
      }
    }
  }
}

// ---------------- fused attention: one block per (b, head, branch) ----------
__global__ __launch_bounds__(256) void attn_kernel(
    const float* __restrict__ q1, const float* __restrict__ k1, const float* __restrict__ v1,
    const float* __restrict__ q2, const float* __restrict__ k2, const float* __restrict__ v2,
    const float* __restrict__ adj, const float* __restrict__ distr,
    const float* __restrict__ maskb,
    u16* __restrict__ o1, u16* __restrict__ o2)
{
  __shared__ float Qs[S_*33];        // padded rows; reused as O
  __shared__ float Ks[S_][DEPTH_];
  __shared__ float Vs[S_][DEPTH_];
  __shared__ float msk[S_];
  const int bh = blockIdx.x;
  const int b  = bh >> 2;            // H_=4
  const int hh = bh & 3;
  const int branch = blockIdx.y;
  const float* Qg = branch ? q2 : q1;
  const float* Kg = branch ? k2 : k1;
  const float* Vg = branch ? v2 : v1;
  const int t = threadIdx.x;
  for(int idx = t; idx < S_*DEPTH_; idx += 256){
    int s = idx >> 5, d = idx & 31;
    size_t g = (size_t)(b*S_ + s)*DH_ + hh*DEPTH_ + d;
    Qs[s*33 + d] = Qg[g];
    Ks[s][d] = Kg[g];
    Vs[s][d] = Vg[g];
  }
  if(t < S_) msk[t] = maskb[b*S_ + t];
  __syncthreads();

  const int i  = t >> 1;             // score row, two threads per row
  const int jb = (t & 1) * 64;
  float q[32];
  #pragma unroll
  for(int d = 0; d < 32; d++) q[d] = Qs[i*33 + d];

  const float* arow = adj   + ((size_t)b*S_ + i)*S_ + jb;
  const float* drow = distr + ((size_t)b*S_ + i)*S_ + jb;
  float sc[64];
  if(branch == 0){
    #pragma unroll
    for(int j = 0; j < 64; j++){
      const float4* kr = (const float4*)&Ks[jb+j][0];
      float dot = 0.f;
      #pragma unroll
      for(int dq = 0; dq < 8; dq++){
        float4 kv = kr[dq];
        dot += q[dq*4+0]*kv.x + q[dq*4+1]*kv.y + q[dq*4+2]*kv.z + q[dq*4+3]*kv.w;
      }
      sc[j] = dot*SCALE_ + msk[jb+j] + arow[j];
    }
  } else {
    #pragma unroll
    for(int j = 0; j < 64; j++){
      const float4* kr = (const float4*)&Ks[jb+j][0];
      float dot = 0.f;
      #pragma unroll
      for(int dq = 0; dq < 8; dq++){
        float4 kv = kr[dq];
        dot += q[dq*4+0]*kv.x + q[dq*4+1]*kv.y + q[dq*4+2]*kv.z + q[dq*4+3]*kv.w;
      }
      sc[j] = fmaxf(dot, 0.f)*drow[j] + msk[jb+j];
    }
  }
  float m = -3.4e38f;
  #pragma unroll
  for(int j = 0; j < 64; j++) m = fmaxf(m, sc[j]);
  m = fmaxf(m, __shfl_xor(m, 1));
  float sum = 0.f;
  #pragma unroll
  for(int j = 0; j < 64; j++){ float e = __expf(sc[j] - m); sc[j] = e; sum += e; }
  sum += __shfl_xor(sum, 1);
  float inv = 1.0f / sum;
  float o[32] = {};
  #pragma unroll
  for(int j = 0; j < 64; j++){
    float p = sc[j] * inv;
    const float4* vr = (const float4*)&Vs[jb+j][0];
    #pragma unroll
    for(int dq = 0; dq < 8; dq++){
      float4 vv = vr[dq];
      o[dq*4+0] = fmaf(p, vv.x, o[dq*4+0]);
      o[dq*4+1] = fmaf(p, vv.y, o[dq*4+1]);
      o[dq*4+2] = fmaf(p, vv.z, o[dq*4+2]);
      o[dq*4+3] = fmaf(p, vv.w, o[dq*4+3]);
    }
  }
  __syncthreads();
  if((t & 1) == 0){
    #pragma unroll
    for(int d = 0; d < 32; d++) Qs[i*33 + d] = o[d];
  }
  __syncthreads();
  if(t & 1){
    #pragma unroll
    for(int d = 0; d < 32; d++) Qs[i*33 + d] += o[d];
  }
  __syncthreads();
  u16* Og = branch ? o2 : o1;
  for(int idx = t; idx < S_*DEPTH_; idx += 256){
    int s = idx >> 5, d = idx & 31;
    Og[(size_t)(b*S_ + s)*DH_ + hh*DEPTH_ + d] = f2b(Qs[s*33 + d]);
  }
}

// ------------- LayerNorm(a + res) * g + be, dual f32+bf16 output ------------
__global__ __launch_bounds__(256) void ln_kernel(
    const float* __restrict__ a, const float* __restrict__ res,
    const float* __restrict__ g, const float* __restrict__ be,
    float* __restrict__ out, u16* __restrict__ outb)
{
  int w = threadIdx.x >> 6, lane = threadIdx.x & 63;
  int row = blockIdx.x*4 + w;
  const float* pa = a   + (size_t)row*D_;
  const float* pr = res + (size_t)row*D_;
  float v[4];
  float s = 0.f;
  #pragma unroll
  for(int i = 0; i < 4; i++){ int c = lane + i*64; v[i] = pa[c] + pr[c]; s += v[i]; }
  #pragma unroll
  for(int off = 32; off; off >>= 1) s += __shfl_xor(s, off);
  float mu = s * (1.0f/D_);
  float qv = 0.f;
  #pragma unroll
  for(int i = 0; i < 4; i++){ float d = v[i] - mu; qv += d*d; }
  #pragma unroll
  for(int off = 32; off; off >>= 1) qv += __shfl_xor(qv, off);
  float invs = rsqrtf(qv*(1.0f/D_) + 1e-6f);
  #pragma unroll
  for(int i = 0; i < 4; i++){
    int c = lane + i*64;
    float y = (v[i] - mu)*invs*g[c] + be[c];
    out[(size_t)row*D_ + c] = y;
    outb[(size_t)row*D_ + c] = f2b(y);
  }
}

// ---------------- pooled[b,n,:] = (amm[b,n,:] @ h[b]) / sum_atoms -----------
__global__ __launch_bounds__(256) void pool_kernel(
    const float* __restrict__ amm, const float* __restrict__ sum_atoms,
    const float* __restrict__ h, float* __restrict__ pooled)
{
  __shared__ float as[S_];
  int bn = blockIdx.x;
  int b  = bn >> 5;                  // NSUB=32
  int t  = threadIdx.x;              // output col 0..255
  if(t < S_) as[t] = amm[(size_t)bn*S_ + t];
  __syncthreads();
  float acc = 0.f;
  const float* hb = h + (size_t)b*S_*D_ + t;
  #pragma unroll 4
  for(int s = 0; s < S_; s++) acc = fmaf(as[s], hb[(size_t)s*D_], acc);
  pooled[(size_t)bn*D_ + t] = acc / sum_atoms[bn];
}

// ------------- small f32 GEMM (final pooled @ glob_W only) ------------------
__global__ __launch_bounds__(256) void gemm_kernel(
    const float* __restrict__ A, int lda,
    const float* __restrict__ W, int ldw,
    const float* __restrict__ bias,
    float* __restrict__ C, int ldc, int K, int act)
{
  __shared__ float As[16][64];
  __shared__ float Ws[16][64];
  const int m0 = blockIdx.x*64, n0 = blockIdx.y*64;
  const int t  = threadIdx.x;
  const int tm = (t & 15) * 4;
  const int tn = (t >> 4) * 4;
  const int lm = t >> 2;
  const int lk = (t & 3) * 4;
  const int wk = t >> 4;
  const int wn = (t & 15) * 4;
  float acc[4][4] = {};
  for(int k0 = 0; k0 < K; k0 += 16){
    float4 av = *(const float4*)(A + (size_t)(m0+lm)*lda + k0 + lk);
    float4 wv = *(const float4*)(W + (size_t)(k0+wk)*ldw + n0 + wn);
    __syncthreads();
    As[lk+0][lm] = av.x; As[lk+1][lm] = av.y; As[lk+2][lm] = av.z; As[lk+3][lm] = av.w;
    *(float4*)&Ws[wk][wn] = wv;
    __syncthreads();
    #pragma unroll
    for(int k = 0; k < 16; k++){
      float4 a = *(const float4*)&As[k][tm];
      float4 b = *(const float4*)&Ws[k][tn];
      float avr[4] = {a.x, a.y, a.z, a.w};
      float bvr[4] = {b.x, b.y, b.z, b.w};
      #pragma unroll
      for(int i = 0; i < 4; i++)
        #pragma unroll
        for(int j = 0; j < 4; j++)
          acc[i][j] = fmaf(avr[i], bvr[j], acc[i][j]);
    }
  }
  #pragma unroll
  for(int i = 0; i < 4; i++){
    #pragma unroll
    for(int j = 0; j < 4; j++){
      float v = acc[i][j] + bias[n0+tn+j];
      if(act == 1) v = fmaxf(v, 0.f);
      C[(size_t)(m0+tm+i)*ldc + n0+tn+j] = v;
    }
  }
}

// ============================ host-side launcher ============================
extern "C" void kernel_launch(void* const* d_in, const int* in_sizes, int n_in,
                              void* d_out, int out_size, void* d_ws, size_t ws_size,
                              hipStream_t stream)
{
  const float* x     = (const float*)d_in[0];
  const float* adj   = (const float*)d_in[1];
  const float* dist  = (const float*)d_in[2];
  const float* amm   = (const float*)d_in[3];
  const float* sum_a = (const float*)d_in[4];
  const float* embW  = (const float*)d_in[5];
  const float* embB  = (const float*)d_in[6];
  const float* globW = (const float*)d_in[7];
  const float* globB = (const float*)d_in[8];
  const float* Wq1 = (const float*)d_in[9],  *Wk1 = (const float*)d_in[10],
             *Wv1 = (const float*)d_in[11], *Wo1 = (const float*)d_in[12],
             *Wq2 = (const float*)d_in[13], *Wk2 = (const float*)d_in[14],
             *Wv2 = (const float*)d_in[15], *Wo2 = (const float*)d_in[16];
  const float* bq1 = (const float*)d_in[17], *bk1 = (const float*)d_in[18],
             *bv1 = (const float*)d_in[19], *bo1 = (const float*)d_in[20],
             *bq2 = (const float*)d_in[21], *bk2 = (const float*)d_in[22],
             *bv2 = (const float*)d_in[23], *bo2 = (const float*)d_in[24];
  const float* Wf1 = (const float*)d_in[25], *bf1 = (const float*)d_in[26],
             *Wf2 = (const float*)d_in[27], *bf2 = (const float*)d_in[28],
             *g1  = (const float*)d_in[29], *be1 = (const float*)d_in[30],
             *g2  = (const float*)d_in[31], *be2 = (const float*)d_in[32];

  float* wsf = (float*)d_ws;
  float* h     = wsf; wsf += (size_t)MS_*D_;      // 2,097,152
  float* maskb = wsf; wsf += MS_;                 // 8,192
  float* distr = wsf; wsf += (size_t)B_*S_*S_;    // 1,048,576
  float* q1b = wsf; wsf += (size_t)MS_*DH_;
  float* k1b = wsf; wsf += (size_t)MS_*DH_;
  float* v1b = wsf; wsf += (size_t)MS_*DH_;
  float* q2b = wsf; wsf += (size_t)MS_*DH_;
  float* k2b = wsf; wsf += (size_t)MS_*DH_;
  float* v2b = wsf; wsf += (size_t)MS_*DH_;
  float* attnb = wsf; wsf += (size_t)MS_*D_;
  float* out1  = wsf; wsf += (size_t)MS_*D_;
  float* pooled = wsf; wsf += (size_t)B_*NSUB_*D_;
  // bf16 region
  u16* bb = (u16*)wsf;
  u16* h_bf    = bb; bb += (size_t)MS_*D_;        // 2,097,152
  u16* out1_bf = bb; bb += (size_t)MS_*D_;        // 2,097,152
  u16* wq1t = bb; bb += (size_t)L_*DH_*DH_;
  u16* wk1t = bb; bb += (size_t)L_*DH_*DH_;
  u16* wv1t = bb; bb += (size_t)L_*DH_*DH_;
  u16* wo1t = bb; bb += (size_t)L_*DH_*DH_;
  u16* wq2t = bb; bb += (size_t)L_*DH_*DH_;
  u16* wk2t = bb; bb += (size_t)L_*DH_*DH_;
  u16* wv2t = bb; bb += (size_t)L_*DH_*DH_;
  u16* wo2t = bb; bb += (size_t)L_*DH_*DH_;
  u16* wf1t = bb; bb += (size_t)L_*D_*DFF_;       // [L][512][256]
  u16* wf2t = bb; bb += (size_t)L_*DFF_*D_;       // [L][256][512]
  // aliases (lifetime-disjoint)
  u16* ffn1_bf = (u16*)q1b;                       // 4.19M u16 fits in q..v region
  u16* o1_bf = (u16*)out1;                        // o_bf dead before ln1 writes out1
  u16* o2_bf = o1_bf + (size_t)MS_*DH_;

  mask_kernel   <<<MS_/256,        256, 0, stream>>>(x, maskb);
  rescale_kernel<<<(B_*S_*S_)/256, 256, 0, stream>>>(dist, distr);
  embed_kernel  <<<MS_/4,          256, 0, stream>>>(x, embW, embB, h, h_bf);

  dim3 tb(32, 8);
  transpose_kernel<<<dim3(4,4,L_),  tb, 0, stream>>>(Wq1, wq1t, DH_, DH_);
  transpose_kernel<<<dim3(4,4,L_),  tb, 0, stream>>>(Wk1, wk1t, DH_, DH_);
  transpose_kernel<<<dim3(4,4,L_),  tb, 0, stream>>>(Wv1, wv1t, DH_, DH_);
  transpose_kernel<<<dim3(4,4,L_),  tb, 0, stream>>>(Wo1, wo1t, DH_, DH_);
  transpose_kernel<<<dim3(4,4,L_),  tb, 0, stream>>>(Wq2, wq2t, DH_, DH_);
  transpose_kernel<<<dim3(4,4,L_),  tb, 0, stream>>>(Wk2, wk2t, DH_, DH_);
  transpose_kernel<<<dim3(4,4,L_),  tb, 0, stream>>>(Wv2, wv2t, DH_, DH_);
  transpose_kernel<<<dim3(4,4,L_),  tb, 0, stream>>>(Wo2, wo2t, DH_, DH_);
  transpose_kernel<<<dim3(16,8,L_), tb, 0, stream>>>(Wf1, wf1t, D_, DFF_);
  transpose_kernel<<<dim3(8,16,L_), tb, 0, stream>>>(Wf2, wf2t, DFF_, D_);

  for(int l = 0; l < L_; l++){
    // QKV: 6 GEMMs M=8192 N=128 K=128, A = h_bf halves, out f32
    {
      MG6 a;
      const u16* Wt[6] = {wq1t, wk1t, wv1t, wq2t, wk2t, wv2t};
      const float* bs[6] = {bq1, bk1, bv1, bq2, bk2, bv2};
      float* Cs[6] = {q1b, k1b, v1b, q2b, k2b, v2b};
      for(int z = 0; z < 6; z++){
        a.g[z].A = h_bf; a.g[z].W = Wt[z] + (size_t)l*DH_*DH_;
        a.g[z].bias = bs[z] + (size_t)l*DH_; a.g[z].C = Cs[z];
        a.g[z].lda = D_; a.g[z].K = DH_; a.g[z].ldc = DH_;
        a.g[z].aofs = (z/3)*DH_; a.g[z].cofs = 0;
      }
      mgemm_kernel<128,false,0><<<dim3(MS_/128, 1, 6), 256, 0, stream>>>(a);
    }
    attn_kernel<<<dim3(B_*H_, 2), 256, 0, stream>>>(q1b,k1b,v1b, q2b,k2b,v2b,
                                                    adj, distr, maskb, o1_bf, o2_bf);
    // out-proj: 2 GEMMs M=8192 N=128 K=128 -> attnb cols [0:128],[128:256]
    {
      MG6 a;
      const u16* At[2] = {o1_bf, o2_bf};
      const u16* Wt[2] = {wo1t, wo2t};
      const float* bs[2] = {bo1, bo2};
      for(int z = 0; z < 2; z++){
        a.g[z].A = At[z]; a.g[z].W = Wt[z] + (size_t)l*DH_*DH_;
        a.g[z].bias = bs[z] + (size_t)l*DH_; a.g[z].C = attnb;
        a.g[z].lda = DH_; a.g[z].K = DH_; a.g[z].ldc = D_;
        a.g[z].aofs = 0; a.g[z].cofs = z*DH_;
      }
      mgemm_kernel<64,false,0><<<dim3(MS_/64, 1, 2), 256, 0, stream>>>(a);
    }
    ln_kernel<<<MS_/4, 256, 0, stream>>>(attnb, h, g1 + (size_t)l*D_, be1 + (size_t)l*D_,
                                         out1, out1_bf);
    // FFN1: M=8192 N=512 K=256, gelu, out bf16
    {
      MG6 a;
      a.g[0].A = out1_bf; a.g[0].W = wf1t + (size_t)l*D_*DFF_;
      a.g[0].bias = bf1 + (size_t)l*DFF_; a.g[0].C = ffn1_bf;
      a.g[0].lda = D_; a.g[0].K = D_; a.g[0].ldc = DFF_;
      a.g[0].aofs = 0; a.g[0].cofs = 0;
      mgemm_kernel<128,true,2><<<dim3(MS_/128, DFF_/128, 1), 256, 0, stream>>>(a);
    }
    // FFN2: M=8192 N=256 K=512, out f32 attnb
    {
      MG6 a;
      a.g[0].A = ffn1_bf; a.g[0].W = wf2t + (size_t)l*DFF_*D_;
      a.g[0].bias = bf2 + (size_t)l*D_; a.g[0].C = attnb;
      a.g[0].lda = DFF_; a.g[0].K = DFF_; a.g[0].ldc = D_;
      a.g[0].aofs = 0; a.g[0].cofs = 0;
      mgemm_kernel<64,false,0><<<dim3(MS_/64, D_/128, 1), 256, 0, stream>>>(a);
    }
    ln_kernel<<<MS_/4, 256, 0, stream>>>(attnb, out1, g2 + (size_t)l*D_, be2 + (size_t)l*D_,
                                         h, h_bf);
  }

  pool_kernel<<<B_*NSUB_, 256, 0, stream>>>(amm, sum_a, h, pooled);
  gemm_kernel<<<dim3((B_*NSUB_)/64, D_/64), 256, 0, stream>>>(pooled, D_, globW, D_, globB,
                                                     (float*)d_out, D_, D_, 1);
}

// Round 3
// 685.571 us; speedup vs baseline: 1.7118x; 1.1599x over previous
//
#include <hip/hip_runtime.h>
#include <math.h>

#define B_ 64
#define S_ 128
#define F_ 62
#define D_ 256
#define H_ 4
#define L_ 6
#define NSUB_ 32
#define DFF_ 512
#define DH_ 128
#define DEPTH_ 32
#define MS_ (B_*S_)                 // 8192 rows
#define NEGV (-1000000000.0f)
#define SCALE_ 0.17677669529663687f // 1/sqrt(32)

typedef unsigned short u16;
typedef __attribute__((ext_vector_type(8))) short short8;
typedef __attribute__((ext_vector_type(4))) float f32x4;

// f32 -> bf16 round-to-nearest-even
__device__ __forceinline__ u16 f2b(float f){
  unsigned u = __float_as_uint(f);
  unsigned r = (u + 0x7fffu + ((u >> 16) & 1u)) >> 16;
  return (u16)r;
}

__device__ __forceinline__ void glds16(const void* g, void* l){
  __builtin_amdgcn_global_load_lds(
      (const __attribute__((address_space(1))) unsigned int*)g,
      (__attribute__((address_space(3))) unsigned int*)l, 16, 0, 0);
}

// ---------------- mask: (sum_F x == 0) * NEG, pre-multiplied ----------------
__global__ __launch_bounds__(256) void mask_kernel(const float* __restrict__ x,
                                                   float* __restrict__ maskb){
  int r = blockIdx.x*256 + threadIdx.x;
  if(r >= MS_) return;
  const float* row = x + (size_t)r*F_;
  float s = 0.f;
  #pragma unroll
  for(int f=0; f<F_; f++) s += row[f];
  maskb[r] = (s == 0.0f) ? NEGV : 0.0f;
}

// ------------- dist rescale: (1+e)/(1+exp(1-w)) * scale (pre-scaled) --------
__global__ __launch_bounds__(256) void rescale_kernel(const float* __restrict__ dist,
                                                      float* __restrict__ distr){
  int i = blockIdx.x*256 + threadIdx.x;
  float w = dist[i];
  const float e1 = 2.718281828459045f;
  distr[i] = (1.0f + e1) / (1.0f + expf(1.0f - w)) * SCALE_;
}

// --------- weight transpose + bf16 convert: dst[l][n][k] = src[l][k][n] -----
__global__ __launch_bounds__(256) void transpose_kernel(const float* __restrict__ src,
                                                        u16* __restrict__ dst,
                                                        int K, int N){
  __shared__ float tbuf[32][33];
  int l = blockIdx.z;
  src += (size_t)l*K*N;
  dst += (size_t)l*K*N;
  int n0 = blockIdx.x*32, k0 = blockIdx.y*32;
  int tx = threadIdx.x, ty = threadIdx.y;   // 32 x 8
  #pragma unroll
  for(int i = 0; i < 4; i++)
    tbuf[ty + i*8][tx] = src[(size_t)(k0 + ty + i*8)*N + n0 + tx];
  __syncthreads();
  #pragma unroll
  for(int i = 0; i < 4; i++)
    dst[(size_t)(n0 + ty + i*8)*K + k0 + tx] = f2b(tbuf[tx][ty + i*8]);
}

// ---------------- embed: h = relu(x @ emb_W + emb_b), K=62 ------------------
__global__ __launch_bounds__(256) void embed_kernel(const float* __restrict__ x,
    const float* __restrict__ W, const float* __restrict__ bias,
    float* __restrict__ h, u16* __restrict__ h_bf){
  __shared__ float xs[4][F_];
  int r0 = blockIdx.x*4;
  int t = threadIdx.x;
  if(t < 4*F_){ int rr = t / F_, ff = t - rr*F_; xs[rr][ff] = x[(size_t)(r0+rr)*F_ + ff]; }
  __syncthreads();
  float b = bias[t];
  float a0=b, a1=b, a2=b, a3=b;
  for(int k=0; k<F_; k++){
    float w = W[k*D_ + t];
    a0 = fmaf(xs[0][k], w, a0);
    a1 = fmaf(xs[1][k], w, a1);
    a2 = fmaf(xs[2][k], w, a2);
    a3 = fmaf(xs[3][k], w, a3);
  }
  a0 = fmaxf(a0, 0.f); a1 = fmaxf(a1, 0.f); a2 = fmaxf(a2, 0.f); a3 = fmaxf(a3, 0.f);
  h[(size_t)(r0+0)*D_ + t] = a0;  h_bf[(size_t)(r0+0)*D_ + t] = f2b(a0);
  h[(size_t)(r0+1)*D_ + t] = a1;  h_bf[(size_t)(r0+1)*D_ + t] = f2b(a1);
  h[(size_t)(r0+2)*D_ + t] = a2;  h_bf[(size_t)(r0+2)*D_ + t] = f2b(a2);
  h[(size_t)(r0+3)*D_ + t] = a3;  h_bf[(size_t)(r0+3)*D_ + t] = f2b(a3);
}

// =================== bf16 MFMA GEMM (m97-style, TNx128 tile) ================
struct MG {
  const u16* A; const u16* W; const float* bias; void* C;
  int lda, K, ldc, aofs, cofs;
};
struct MG6 { MG g[6]; };

template<int TM, bool OUTBF, int ACT>
__global__ __launch_bounds__(256) void mgemm_kernel(MG6 args){
  const MG p = args.g[blockIdx.z];
  __shared__ u16 As[TM*32];
  __shared__ u16 Bs[128*32];
  const int t    = threadIdx.x;
  const int lane = t & 63;
  const int w    = t >> 6;
  const int ln   = lane & 15;
  const int qd   = lane >> 4;
  const int mw   = (w & 1) * (TM/2);
  const int nw   = (w >> 1) * 64;
  const int m0   = blockIdx.x * TM;
  const int n0   = blockIdx.y * 128;
  constexpr int MI = TM/32;
  f32x4 acc[MI][4];
  #pragma unroll
  for(int i=0;i<MI;i++)
    #pragma unroll
    for(int j=0;j<4;j++) acc[i][j] = (f32x4){0.f,0.f,0.f,0.f};

  const int srow = t >> 2;
  const int sc8  = (t & 3) * 8;

  for(int k0 = 0; k0 < p.K; k0 += 32){
    __syncthreads();
    glds16(p.A + (size_t)(m0 + srow)*p.lda + p.aofs + k0 + sc8, As + t*8);
    if(TM == 128)
      glds16(p.A + (size_t)(m0 + 64 + srow)*p.lda + p.aofs + k0 + sc8, As + (t+256)*8);
    glds16(p.W + (size_t)(n0 + srow)*p.K + k0 + sc8, Bs + t*8);
    glds16(p.W + (size_t)(n0 + 64 + srow)*p.K + k0 + sc8, Bs + (t+256)*8);
    __syncthreads();

    short8 a[MI], b[4];
    #pragma unroll
    for(int i=0;i<MI;i++) a[i] = *(const short8*)&As[(mw + i*16 + ln)*32 + qd*8];
    #pragma unroll
    for(int j=0;j<4;j++)  b[j] = *(const short8*)&Bs[(nw + j*16 + ln)*32 + qd*8];
    #pragma unroll
    for(int i=0;i<MI;i++)
      #pragma unroll
      for(int j=0;j<4;j++)
        acc[i][j] = __builtin_amdgcn_mfma_f32_16x16x32_bf16(a[i], b[j], acc[i][j], 0, 0, 0);
  }

  #pragma unroll
  for(int i=0;i<MI;i++){
    #pragma unroll
    for(int j=0;j<4;j++){
      int col = n0 + nw + j*16 + ln;
      float bv = p.bias[col];
      int rowb = m0 + mw + i*16 + qd*4;
      #pragma unroll
      for(int r=0;r<4;r++){
        float v = acc[i][j][r] + bv;
        if(ACT == 1) v = fmaxf(v, 0.f);
        if(ACT == 2) v = 0.5f*v*(1.0f + erff(v*0.70710678118654752f));
        size_t idx = (size_t)(rowb + r)*p.ldc + p.cofs + col;
        if(OUTBF) ((u16*)p.C)[idx] = f2b(v);
        else      ((float*)p.C)[idx] = v;
      }
    }
  }
}

// =============== MFMA attention: block per (b, head, branch) ================
// S=128, DEPTH=32=K of one 16x16x32 MFMA. 4 waves; wave w owns rows 32w..32w+31.
// QK^T frags straight from global (k contiguous); P -> LDS (own rows only, no
// barrier); V transposed into padded LDS once (one barrier).
__global__ __launch_bounds__(256) void attn_mfma_kernel(
    const u16* __restrict__ q1, const u16* __restrict__ k1, const u16* __restrict__ v1,
    const u16* __restrict__ q2, const u16* __restrict__ k2, const u16* __restrict__ v2,
    const float* __restrict__ adj, const float* __restrict__ distr,
    const float* __restrict__ maskb,
    u16* __restrict__ o1, u16* __restrict__ o2)
{
  __shared__ u16 Vt[DEPTH_][136];   // V^T, padded: banks 2-way at worst
  __shared__ u16 Ps[S_][136];       // P bf16, per-wave-private rows
  const int bh = blockIdx.x;
  const int b  = bh >> 2;
  const int hh = bh & 3;
  const int branch = blockIdx.y;
  const u16* Qg = branch ? q2 : q1;
  const u16* Kg = branch ? k2 : k1;
  const u16* Vg = branch ? v2 : v1;
  const int t = threadIdx.x;
  const int w = t >> 6, lane = t & 63;
  const int ln = lane & 15, qd = lane >> 4;
  const size_t rowbase = (size_t)b * S_;

  // ---- stage V transposed (coalesced 32B read, u16 scatter write) ----
  {
    int s = t >> 1, dbase = (t & 1) * 16;
    const u16* src = Vg + (rowbase + s)*DH_ + hh*DEPTH_ + dbase;
    u16 vals[16];
    *(uint4*)&vals[0] = *(const uint4*)(src);
    *(uint4*)&vals[8] = *(const uint4*)(src + 8);
    #pragma unroll
    for(int d = 0; d < 16; d++) Vt[dbase + d][s] = vals[d];
  }
  __syncthreads();

  const int mbase = w * 32;
  // ---- Q A-frags, K B-frags from global ----
  short8 qf[2];
  #pragma unroll
  for(int mt = 0; mt < 2; mt++)
    qf[mt] = *(const short8*)(Qg + (rowbase + mbase + mt*16 + ln)*DH_ + hh*DEPTH_ + qd*8);
  short8 kf[8];
  #pragma unroll
  for(int nt = 0; nt < 8; nt++)
    kf[nt] = *(const short8*)(Kg + (rowbase + nt*16 + ln)*DH_ + hh*DEPTH_ + qd*8);

  // ---- QK^T: 16 MFMAs ----
  f32x4 sc[2][8];
  #pragma unroll
  for(int mt = 0; mt < 2; mt++)
    #pragma unroll
    for(int nt = 0; nt < 8; nt++)
      sc[mt][nt] = __builtin_amdgcn_mfma_f32_16x16x32_bf16(
          qf[mt], kf[nt], (f32x4){0.f,0.f,0.f,0.f}, 0, 0, 0);

  // ---- score fixup (C layout: col = nt*16+ln, row = mbase+mt*16+qd*4+r) ----
  float mskv[8];
  #pragma unroll
  for(int nt = 0; nt < 8; nt++) mskv[nt] = maskb[rowbase + nt*16 + ln];

  #pragma unroll
  for(int mt = 0; mt < 2; mt++){
    #pragma unroll
    for(int r = 0; r < 4; r++){
      int row = mbase + mt*16 + qd*4 + r;
      const float* arow = (branch ? distr : adj) + (rowbase + row)*S_ + ln;
      #pragma unroll
      for(int nt = 0; nt < 8; nt++){
        float g = arow[nt*16];
        float v;
        if(branch == 0) v = sc[mt][nt][r]*SCALE_ + mskv[nt] + g;
        else            v = fmaxf(sc[mt][nt][r], 0.f)*g + mskv[nt];
        sc[mt][nt][r] = v;
      }
    }
  }

  // ---- softmax per row (16-lane quad-group shuffle reduce) + P->LDS ----
  #pragma unroll
  for(int mt = 0; mt < 2; mt++){
    #pragma unroll
    for(int r = 0; r < 4; r++){
      float m = -3.4e38f;
      #pragma unroll
      for(int nt = 0; nt < 8; nt++) m = fmaxf(m, sc[mt][nt][r]);
      m = fmaxf(m, __shfl_xor(m, 1));
      m = fmaxf(m, __shfl_xor(m, 2));
      m = fmaxf(m, __shfl_xor(m, 4));
      m = fmaxf(m, __shfl_xor(m, 8));
      float sum = 0.f;
      float e[8];
      #pragma unroll
      for(int nt = 0; nt < 8; nt++){ e[nt] = __expf(sc[mt][nt][r] - m); sum += e[nt]; }
      sum += __shfl_xor(sum, 1);
      sum += __shfl_xor(sum, 2);
      sum += __shfl_xor(sum, 4);
      sum += __shfl_xor(sum, 8);
      float inv = 1.0f / sum;
      int row = mbase + mt*16 + qd*4 + r;
      #pragma unroll
      for(int nt = 0; nt < 8; nt++) Ps[row][nt*16 + ln] = f2b(e[nt] * inv);
    }
  }
  // no barrier: each wave reads only its own P rows

  // ---- PV: A = P (own rows), B = V^T; 16 MFMAs ----
  f32x4 oacc[2][2];
  #pragma unroll
  for(int mt = 0; mt < 2; mt++)
    #pragma unroll
    for(int n2 = 0; n2 < 2; n2++) oacc[mt][n2] = (f32x4){0.f,0.f,0.f,0.f};
  #pragma unroll
  for(int kk = 0; kk < 4; kk++){
    short8 pa[2], vb[2];
    #pragma unroll
    for(int mt = 0; mt < 2; mt++)
      pa[mt] = *(const short8*)&Ps[mbase + mt*16 + ln][kk*32 + qd*8];
    #pragma unroll
    for(int n2 = 0; n2 < 2; n2++)
      vb[n2] = *(const short8*)&Vt[n2*16 + ln][kk*32 + qd*8];
    #pragma unroll
    for(int mt = 0; mt < 2; mt++)
      #pragma unroll
      for(int n2 = 0; n2 < 2; n2++)
        oacc[mt][n2] = __builtin_amdgcn_mfma_f32_16x16x32_bf16(pa[mt], vb[n2], oacc[mt][n2], 0, 0, 0);
  }

  // ---- store O (bf16) ----
  u16* Og = branch ? o2 : o1;
  #pragma unroll
  for(int mt = 0; mt < 2; mt++){
    #pragma unroll
    for(int n2 = 0; n2 < 2; n2++){
      #pragma unroll
      for(int r = 0; r < 4; r++){
        int row = mbase + mt*16 + qd*4 + r;
        int d   = n2*16 + ln;
        Og[(rowbase + row)*DH_ + hh*DEPTH_ + d] = f2b(oacc[mt][n2][r]);
      }
    }
  }
}

// ------------- LayerNorm(a + res) * g + be, dual f32+bf16 output ------------
__global__ __launch_bounds__(256) void ln_kernel(
    const float* __restrict__ a, const float* __restrict__ res,
    const float* __restrict__ g, const float* __restrict__ be,
    float* __restrict__ out, u16* __restrict__ outb)
{
  int w = threadIdx.x >> 6, lane = threadIdx.x & 63;
  int row = blockIdx.x*4 + w;
  const float* pa = a   + (size_t)row*D_;
  const float* pr = res + (size_t)row*D_;
  float v[4];
  float s = 0.f;
  #pragma unroll
  for(int i = 0; i < 4; i++){ int c = lane + i*64; v[i] = pa[c] + pr[c]; s += v[i]; }
  #pragma unroll
  for(int off = 32; off; off >>= 1) s += __shfl_xor(s, off);
  float mu = s * (1.0f/D_);
  float qv = 0.f;
  #pragma unroll
  for(int i = 0; i < 4; i++){ float d = v[i] - mu; qv += d*d; }
  #pragma unroll
  for(int off = 32; off; off >>= 1) qv += __shfl_xor(qv, off);
  float invs = rsqrtf(qv*(1.0f/D_) + 1e-6f);
  #pragma unroll
  for(int i = 0; i < 4; i++){
    int c = lane + i*64;
    float y = (v[i] - mu)*invs*g[c] + be[c];
    out[(size_t)row*D_ + c] = y;
    outb[(size_t)row*D_ + c] = f2b(y);
  }
}

// ---------------- pooled[b,n,:] = (amm[b,n,:] @ h[b]) / sum_atoms -----------
__global__ __launch_bounds__(256) void pool_kernel(
    const float* __restrict__ amm, const float* __restrict__ sum_atoms,
    const float* __restrict__ h, float* __restrict__ pooled)
{
  __shared__ float as[S_];
  int bn = blockIdx.x;
  int b  = bn >> 5;
  int t  = threadIdx.x;
  if(t < S_) as[t] = amm[(size_t)bn*S_ + t];
  __syncthreads();
  float acc = 0.f;
  const float* hb = h + (size_t)b*S_*D_ + t;
  #pragma unroll 4
  for(int s = 0; s < S_; s++) acc = fmaf(as[s], hb[(size_t)s*D_], acc);
  pooled[(size_t)bn*D_ + t] = acc / sum_atoms[bn];
}

// ------------- small f32 GEMM (final pooled @ glob_W only) ------------------
__global__ __launch_bounds__(256) void gemm_kernel(
    const float* __restrict__ A, int lda,
    const float* __restrict__ W, int ldw,
    const float* __restrict__ bias,
    float* __restrict__ C, int ldc, int K, int act)
{
  __shared__ float As[16][64];
  __shared__ float Ws[16][64];
  const int m0 = blockIdx.x*64, n0 = blockIdx.y*64;
  const int t  = threadIdx.x;
  const int tm = (t & 15) * 4;
  const int tn = (t >> 4) * 4;
  const int lm = t >> 2;
  const int lk = (t & 3) * 4;
  const int wk = t >> 4;
  const int wn = (t & 15) * 4;
  float acc[4][4] = {};
  for(int k0 = 0; k0 < K; k0 += 16){
    float4 av = *(const float4*)(A + (size_t)(m0+lm)*lda + k0 + lk);
    float4 wv = *(const float4*)(W + (size_t)(k0+wk)*ldw + n0 + wn);
    __syncthreads();
    As[lk+0][lm] = av.x; As[lk+1][lm] = av.y; As[lk+2][lm] = av.z; As[lk+3][lm] = av.w;
    *(float4*)&Ws[wk][wn] = wv;
    __syncthreads();
    #pragma unroll
    for(int k = 0; k < 16; k++){
      float4 a = *(const float4*)&As[k][tm];
      float4 b = *(const float4*)&Ws[k][tn];
      float avr[4] = {a.x, a.y, a.z, a.w};
      float bvr[4] = {b.x, b.y, b.z, b.w};
      #pragma unroll
      for(int i = 0; i < 4; i++)
        #pragma unroll
        for(int j = 0; j < 4; j++)
          acc[i][j] = fmaf(avr[i], bvr[j], acc[i][j]);
    }
  }
  #pragma unroll
  for(int i = 0; i < 4; i++){
    #pragma unroll
    for(int j = 0; j < 4; j++){
      float v = acc[i][j] + bias[n0+tn+j];
      if(act == 1) v = fmaxf(v, 0.f);
      C[(size_t)(m0+tm+i)*ldc + n0+tn+j] = v;
    }
  }
}

// ============================ host-side launcher ============================
extern "C" void kernel_launch(void* const* d_in, const int* in_sizes, int n_in,
                              void* d_out, int out_size, void* d_ws, size_t ws_size,
                              hipStream_t stream)
{
  const float* x     = (const float*)d_in[0];
  const float* adj   = (const float*)d_in[1];
  const float* dist  = (const float*)d_in[2];
  const float* amm   = (const float*)d_in[3];
  const float* sum_a = (const float*)d_in[4];
  const float* embW  = (const float*)d_in[5];
  const float* embB  = (const float*)d_in[6];
  const float* globW = (const float*)d_in[7];
  const float* globB = (const float*)d_in[8];
  const float* Wq1 = (const float*)d_in[9],  *Wk1 = (const float*)d_in[10],
             *Wv1 = (const float*)d_in[11], *Wo1 = (const float*)d_in[12],
             *Wq2 = (const float*)d_in[13], *Wk2 = (const float*)d_in[14],
             *Wv2 = (const float*)d_in[15], *Wo2 = (const float*)d_in[16];
  const float* bq1 = (const float*)d_in[17], *bk1 = (const float*)d_in[18],
             *bv1 = (const float*)d_in[19], *bo1 = (const float*)d_in[20],
             *bq2 = (const float*)d_in[21], *bk2 = (const float*)d_in[22],
             *bv2 = (const float*)d_in[23], *bo2 = (const float*)d_in[24];
  const float* Wf1 = (const float*)d_in[25], *bf1 = (const float*)d_in[26],
             *Wf2 = (const float*)d_in[27], *bf2 = (const float*)d_in[28],
             *g1  = (const float*)d_in[29], *be1 = (const float*)d_in[30],
             *g2  = (const float*)d_in[31], *be2 = (const float*)d_in[32];

  float* wsf = (float*)d_ws;
  float* h     = wsf; wsf += (size_t)MS_*D_;
  float* maskb = wsf; wsf += MS_;
  float* distr = wsf; wsf += (size_t)B_*S_*S_;
  // QKV/O now bf16; keep f32-sized slots, alias as u16
  float* qkvslab = wsf; wsf += (size_t)MS_*DH_*8;   // q1,k1,v1,q2,k2,v2,(spare o region)
  float* attnb = wsf; wsf += (size_t)MS_*D_;
  float* out1  = wsf; wsf += (size_t)MS_*D_;
  float* pooled = wsf; wsf += (size_t)B_*NSUB_*D_;
  // bf16 region
  u16* bb = (u16*)wsf;
  u16* h_bf    = bb; bb += (size_t)MS_*D_;
  u16* out1_bf = bb; bb += (size_t)MS_*D_;
  u16* wq1t = bb; bb += (size_t)L_*DH_*DH_;
  u16* wk1t = bb; bb += (size_t)L_*DH_*DH_;
  u16* wv1t = bb; bb += (size_t)L_*DH_*DH_;
  u16* wo1t = bb; bb += (size_t)L_*DH_*DH_;
  u16* wq2t = bb; bb += (size_t)L_*DH_*DH_;
  u16* wk2t = bb; bb += (size_t)L_*DH_*DH_;
  u16* wv2t = bb; bb += (size_t)L_*DH_*DH_;
  u16* wo2t = bb; bb += (size_t)L_*DH_*DH_;
  u16* wf1t = bb; bb += (size_t)L_*D_*DFF_;
  u16* wf2t = bb; bb += (size_t)L_*DFF_*D_;
  // bf16 aliases into qkvslab (lifetimes: qkv -> attn -> o -> oproj; then ffn1)
  u16* q1b = (u16*)qkvslab;
  u16* k1b = q1b + (size_t)MS_*DH_;
  u16* v1b = k1b + (size_t)MS_*DH_;
  u16* q2b = v1b + (size_t)MS_*DH_;
  u16* k2b = q2b + (size_t)MS_*DH_;
  u16* v2b = k2b + (size_t)MS_*DH_;
  u16* o1_bf = v2b + (size_t)MS_*DH_;
  u16* o2_bf = o1_bf + (size_t)MS_*DH_;
  u16* ffn1_bf = q1b;   // reused after out-proj consumes o1_bf/o2_bf

  mask_kernel   <<<MS_/256,        256, 0, stream>>>(x, maskb);
  rescale_kernel<<<(B_*S_*S_)/256, 256, 0, stream>>>(dist, distr);
  embed_kernel  <<<MS_/4,          256, 0, stream>>>(x, embW, embB, h, h_bf);

  dim3 tb(32, 8);
  transpose_kernel<<<dim3(4,4,L_),  tb, 0, stream>>>(Wq1, wq1t, DH_, DH_);
  transpose_kernel<<<dim3(4,4,L_),  tb, 0, stream>>>(Wk1, wk1t, DH_, DH_);
  transpose_kernel<<<dim3(4,4,L_),  tb, 0, stream>>>(Wv1, wv1t, DH_, DH_);
  transpose_kernel<<<dim3(4,4,L_),  tb, 0, stream>>>(Wo1, wo1t, DH_, DH_);
  transpose_kernel<<<dim3(4,4,L_),  tb, 0, stream>>>(Wq2, wq2t, DH_, DH_);
  transpose_kernel<<<dim3(4,4,L_),  tb, 0, stream>>>(Wk2, wk2t, DH_, DH_);
  transpose_kernel<<<dim3(4,4,L_),  tb, 0, stream>>>(Wv2, wv2t, DH_, DH_);
  transpose_kernel<<<dim3(4,4,L_),  tb, 0, stream>>>(Wo2, wo2t, DH_, DH_);
  transpose_kernel<<<dim3(16,8,L_), tb, 0, stream>>>(Wf1, wf1t, D_, DFF_);
  transpose_kernel<<<dim3(8,16,L_), tb, 0, stream>>>(Wf2, wf2t, DFF_, D_);

  for(int l = 0; l < L_; l++){
    // QKV: 6 GEMMs M=8192 N=128 K=128, out bf16
    {
      MG6 a;
      const u16* Wt[6] = {wq1t, wk1t, wv1t, wq2t, wk2t, wv2t};
      const float* bs[6] = {bq1, bk1, bv1, bq2, bk2, bv2};
      u16* Cs[6] = {q1b, k1b, v1b, q2b, k2b, v2b};
      for(int z = 0; z < 6; z++){
        a.g[z].A = h_bf; a.g[z].W = Wt[z] + (size_t)l*DH_*DH_;
        a.g[z].bias = bs[z] + (size_t)l*DH_; a.g[z].C = Cs[z];
        a.g[z].lda = D_; a.g[z].K = DH_; a.g[z].ldc = DH_;
        a.g[z].aofs = (z/3)*DH_; a.g[z].cofs = 0;
      }
      mgemm_kernel<128,true,0><<<dim3(MS_/128, 1, 6), 256, 0, stream>>>(a);
    }
    attn_mfma_kernel<<<dim3(B_*H_, 2), 256, 0, stream>>>(q1b,k1b,v1b, q2b,k2b,v2b,
                                                         adj, distr, maskb, o1_bf, o2_bf);
    // out-proj: 2 GEMMs M=8192 N=128 K=128 -> attnb cols [0:128],[128:256]
    {
      MG6 a;
      const u16* At[2] = {o1_bf, o2_bf};
      const u16* Wt[2] = {wo1t, wo2t};
      const float* bs[2] = {bo1, bo2};
      for(int z = 0; z < 2; z++){
        a.g[z].A = At[z]; a.g[z].W = Wt[z] + (size_t)l*DH_*DH_;
        a.g[z].bias = bs[z] + (size_t)l*DH_; a.g[z].C = attnb;
        a.g[z].lda = DH_; a.g[z].K = DH_; a.g[z].ldc = D_;
        a.g[z].aofs = 0; a.g[z].cofs = z*DH_;
      }
      mgemm_kernel<64,false,0><<<dim3(MS_/64, 1, 2), 256, 0, stream>>>(a);
    }
    ln_kernel<<<MS_/4, 256, 0, stream>>>(attnb, h, g1 + (size_t)l*D_, be1 + (size_t)l*D_,
                                         out1, out1_bf);
    // FFN1: M=8192 N=512 K=256, gelu, out bf16
    {
      MG6 a;
      a.g[0].A = out1_bf; a.g[0].W = wf1t + (size_t)l*D_*DFF_;
      a.g[0].bias = bf1 + (size_t)l*DFF_; a.g[0].C = ffn1_bf;
      a.g[0].lda = D_; a.g[0].K = D_; a.g[0].ldc = DFF_;
      a.g[0].aofs = 0; a.g[0].cofs = 0;
      mgemm_kernel<128,true,2><<<dim3(MS_/128, DFF_/128, 1), 256, 0, stream>>>(a);
    }
    // FFN2: M=8192 N=256 K=512, out f32 attnb
    {
      MG6 a;
      a.g[0].A = ffn1_bf; a.g[0].W = wf2t + (size_t)l*DFF_*D_;
      a.g[0].bias = bf2 + (size_t)l*D_; a.g[0].C = attnb;
      a.g[0].lda = DFF_; a.g[0].K = DFF_; a.g[0].ldc = D_;
      a.g[0].aofs = 0; a.g[0].cofs = 0;
      mgemm_kernel<64,false,0><<<dim3(MS_/64, D_/128, 1), 256, 0, stream>>>(a);
    }
    ln_kernel<<<MS_/4, 256, 0, stream>>>(attnb, out1, g2 + (size_t)l*D_, be2 + (size_t)l*D_,
                                         h, h_bf);
  }

  pool_kernel<<<B_*NSUB_, 256, 0, stream>>>(amm, sum_a, h, pooled);
  gemm_kernel<<<dim3((B_*NSUB_)/64, D_/64), 256, 0, stream>>>(pooled, D_, globW, D_, globB,
                                                     (float*)d_out, D_, D_, 1);
}

// Round 4
// 566.720 us; speedup vs baseline: 2.0707x; 1.2097x over previous
//
#include <hip/hip_runtime.h>
#include <math.h>

#define B_ 64
#define S_ 128
#define F_ 62
#define D_ 256
#define H_ 4
#define L_ 6
#define NSUB_ 32
#define DFF_ 512
#define DH_ 128
#define DEPTH_ 32
#define MS_ (B_*S_)                 // 8192 rows
#define NEGV (-1000000000.0f)
#define SCALE_ 0.17677669529663687f // 1/sqrt(32)

typedef unsigned short u16;
typedef __attribute__((ext_vector_type(8))) short short8;
typedef __attribute__((ext_vector_type(4))) float f32x4;

// f32 -> bf16 round-to-nearest-even
__device__ __forceinline__ u16 f2b(float f){
  unsigned u = __float_as_uint(f);
  unsigned r = (u + 0x7fffu + ((u >> 16) & 1u)) >> 16;
  return (u16)r;
}

__device__ __forceinline__ void glds16(const void* g, void* l){
  __builtin_amdgcn_global_load_lds(
      (const __attribute__((address_space(1))) unsigned int*)g,
      (__attribute__((address_space(3))) unsigned int*)l, 16, 0, 0);
}

// ---------------- mask: (sum_F x == 0) * NEG, pre-multiplied ----------------
__global__ __launch_bounds__(256) void mask_kernel(const float* __restrict__ x,
                                                   float* __restrict__ maskb){
  int r = blockIdx.x*256 + threadIdx.x;
  if(r >= MS_) return;
  const float* row = x + (size_t)r*F_;
  float s = 0.f;
  #pragma unroll
  for(int f=0; f<F_; f++) s += row[f];
  maskb[r] = (s == 0.0f) ? NEGV : 0.0f;
}

// ------------- dist rescale: (1+e)/(1+exp(1-w)) * scale (pre-scaled) --------
__global__ __launch_bounds__(256) void rescale_kernel(const float* __restrict__ dist,
                                                      float* __restrict__ distr){
  int i = blockIdx.x*256 + threadIdx.x;
  float w = dist[i];
  const float e1 = 2.718281828459045f;
  distr[i] = (1.0f + e1) / (1.0f + expf(1.0f - w)) * SCALE_;
}

// ------------- adjm = adj + mask (mask & adj constant across layers) --------
__global__ __launch_bounds__(256) void adjm_kernel(const float* __restrict__ adj,
                                                   const float* __restrict__ maskb,
                                                   float* __restrict__ adjm){
  size_t i = (size_t)blockIdx.x*256 + threadIdx.x;
  int j = (int)(i & (S_-1));
  int b = (int)(i >> 14);            // S_*S_ = 16384
  adjm[i] = adj[i] + maskb[b*S_ + j];
}

// --------- weight transpose + bf16 convert: dst[l][n][k] = src[l][k][n] -----
__global__ __launch_bounds__(256) void transpose_kernel(const float* __restrict__ src,
                                                        u16* __restrict__ dst,
                                                        int K, int N){
  __shared__ float tbuf[32][33];
  int l = blockIdx.z;
  src += (size_t)l*K*N;
  dst += (size_t)l*K*N;
  int n0 = blockIdx.x*32, k0 = blockIdx.y*32;
  int tx = threadIdx.x, ty = threadIdx.y;   // 32 x 8
  #pragma unroll
  for(int i = 0; i < 4; i++)
    tbuf[ty + i*8][tx] = src[(size_t)(k0 + ty + i*8)*N + n0 + tx];
  __syncthreads();
  #pragma unroll
  for(int i = 0; i < 4; i++)
    dst[(size_t)(n0 + ty + i*8)*K + k0 + tx] = f2b(tbuf[tx][ty + i*8]);
}

// ---------------- embed: h = relu(x @ emb_W + emb_b), K=62 ------------------
__global__ __launch_bounds__(256) void embed_kernel(const float* __restrict__ x,
    const float* __restrict__ W, const float* __restrict__ bias,
    float* __restrict__ h, u16* __restrict__ h_bf){
  __shared__ float xs[4][F_];
  int r0 = blockIdx.x*4;
  int t = threadIdx.x;
  if(t < 4*F_){ int rr = t / F_, ff = t - rr*F_; xs[rr][ff] = x[(size_t)(r0+rr)*F_ + ff]; }
  __syncthreads();
  float b = bias[t];
  float a0=b, a1=b, a2=b, a3=b;
  for(int k=0; k<F_; k++){
    float w = W[k*D_ + t];
    a0 = fmaf(xs[0][k], w, a0);
    a1 = fmaf(xs[1][k], w, a1);
    a2 = fmaf(xs[2][k], w, a2);
    a3 = fmaf(xs[3][k], w, a3);
  }
  a0 = fmaxf(a0, 0.f); a1 = fmaxf(a1, 0.f); a2 = fmaxf(a2, 0.f); a3 = fmaxf(a3, 0.f);
  h[(size_t)(r0+0)*D_ + t] = a0;  h_bf[(size_t)(r0+0)*D_ + t] = f2b(a0);
  h[(size_t)(r0+1)*D_ + t] = a1;  h_bf[(size_t)(r0+1)*D_ + t] = f2b(a1);
  h[(size_t)(r0+2)*D_ + t] = a2;  h_bf[(size_t)(r0+2)*D_ + t] = f2b(a2);
  h[(size_t)(r0+3)*D_ + t] = a3;  h_bf[(size_t)(r0+3)*D_ + t] = f2b(a3);
}

// =================== bf16 MFMA GEMM (m97-style, TM x 128 tile) ==============
struct MG {
  const u16* A; const u16* W; const float* bias; void* C;
  int lda, K, ldc, aofs, cofs;
};
struct MG6 { MG g[6]; };

template<int TM, bool OUTBF, int ACT>
__global__ __launch_bounds__(256) void mgemm_kernel(MG6 args){
  const MG p = args.g[blockIdx.z];
  __shared__ u16 As[TM*32];
  __shared__ u16 Bs[128*32];
  const int t    = threadIdx.x;
  const int lane = t & 63;
  const int w    = t >> 6;
  const int ln   = lane & 15;
  const int qd   = lane >> 4;
  const int mw   = (w & 1) * (TM/2);
  const int nw   = (w >> 1) * 64;
  const int m0   = blockIdx.x * TM;
  const int n0   = blockIdx.y * 128;
  constexpr int MI = TM/32;
  f32x4 acc[MI][4];
  #pragma unroll
  for(int i=0;i<MI;i++)
    #pragma unroll
    for(int j=0;j<4;j++) acc[i][j] = (f32x4){0.f,0.f,0.f,0.f};

  const int srow = t >> 2;
  const int sc8  = (t & 3) * 8;

  for(int k0 = 0; k0 < p.K; k0 += 32){
    __syncthreads();
    glds16(p.A + (size_t)(m0 + srow)*p.lda + p.aofs + k0 + sc8, As + t*8);
    if(TM == 128)
      glds16(p.A + (size_t)(m0 + 64 + srow)*p.lda + p.aofs + k0 + sc8, As + (t+256)*8);
    glds16(p.W + (size_t)(n0 + srow)*p.K + k0 + sc8, Bs + t*8);
    glds16(p.W + (size_t)(n0 + 64 + srow)*p.K + k0 + sc8, Bs + (t+256)*8);
    __syncthreads();

    short8 a[MI], b[4];
    #pragma unroll
    for(int i=0;i<MI;i++) a[i] = *(const short8*)&As[(mw + i*16 + ln)*32 + qd*8];
    #pragma unroll
    for(int j=0;j<4;j++)  b[j] = *(const short8*)&Bs[(nw + j*16 + ln)*32 + qd*8];
    #pragma unroll
    for(int i=0;i<MI;i++)
      #pragma unroll
      for(int j=0;j<4;j++)
        acc[i][j] = __builtin_amdgcn_mfma_f32_16x16x32_bf16(a[i], b[j], acc[i][j], 0, 0, 0);
  }

  #pragma unroll
  for(int i=0;i<MI;i++){
    #pragma unroll
    for(int j=0;j<4;j++){
      int col = n0 + nw + j*16 + ln;
      float bv = p.bias[col];
      int rowb = m0 + mw + i*16 + qd*4;
      #pragma unroll
      for(int r=0;r<4;r++){
        float v = acc[i][j][r] + bv;
        if(ACT == 1) v = fmaxf(v, 0.f);
        if(ACT == 2) v = 0.5f*v*(1.0f + erff(v*0.70710678118654752f));
        size_t idx = (size_t)(rowb + r)*p.ldc + p.cofs + col;
        if(OUTBF) ((u16*)p.C)[idx] = f2b(v);
        else      ((float*)p.C)[idx] = v;
      }
    }
  }
}

// =============== MFMA attention: block per (b, head, branch) ================
__global__ __launch_bounds__(256) void attn_mfma_kernel(
    const u16* __restrict__ q1, const u16* __restrict__ k1, const u16* __restrict__ v1,
    const u16* __restrict__ q2, const u16* __restrict__ k2, const u16* __restrict__ v2,
    const float* __restrict__ adjm, const float* __restrict__ distr,
    const float* __restrict__ maskb,
    u16* __restrict__ o1, u16* __restrict__ o2)
{
  __shared__ u16 Vt[DEPTH_][136];
  __shared__ u16 Ps[S_][136];
  const int bh = blockIdx.x;
  const int b  = bh >> 2;
  const int hh = bh & 3;
  const int branch = blockIdx.y;
  const u16* Qg = branch ? q2 : q1;
  const u16* Kg = branch ? k2 : k1;
  const u16* Vg = branch ? v2 : v1;
  const int t = threadIdx.x;
  const int w = t >> 6, lane = t & 63;
  const int ln = lane & 15, qd = lane >> 4;
  const size_t rowbase = (size_t)b * S_;

  // ---- stage V transposed ----
  {
    int s = t >> 1, dbase = (t & 1) * 16;
    const u16* src = Vg + (rowbase + s)*DH_ + hh*DEPTH_ + dbase;
    u16 vals[16];
    *(uint4*)&vals[0] = *(const uint4*)(src);
    *(uint4*)&vals[8] = *(const uint4*)(src + 8);
    #pragma unroll
    for(int d = 0; d < 16; d++) Vt[dbase + d][s] = vals[d];
  }
  __syncthreads();

  const int mbase = w * 32;
  short8 qf[2];
  #pragma unroll
  for(int mt = 0; mt < 2; mt++)
    qf[mt] = *(const short8*)(Qg + (rowbase + mbase + mt*16 + ln)*DH_ + hh*DEPTH_ + qd*8);
  short8 kf[8];
  #pragma unroll
  for(int nt = 0; nt < 8; nt++)
    kf[nt] = *(const short8*)(Kg + (rowbase + nt*16 + ln)*DH_ + hh*DEPTH_ + qd*8);

  f32x4 sc[2][8];
  #pragma unroll
  for(int mt = 0; mt < 2; mt++)
    #pragma unroll
    for(int nt = 0; nt < 8; nt++)
      sc[mt][nt] = __builtin_amdgcn_mfma_f32_16x16x32_bf16(
          qf[mt], kf[nt], (f32x4){0.f,0.f,0.f,0.f}, 0, 0, 0);

  float mskv[8];
  if(branch){
    #pragma unroll
    for(int nt = 0; nt < 8; nt++) mskv[nt] = maskb[rowbase + nt*16 + ln];
  }

  #pragma unroll
  for(int mt = 0; mt < 2; mt++){
    #pragma unroll
    for(int r = 0; r < 4; r++){
      int row = mbase + mt*16 + qd*4 + r;
      const float* arow = (branch ? distr : adjm) + (rowbase + row)*S_ + ln;
      #pragma unroll
      for(int nt = 0; nt < 8; nt++){
        float g = arow[nt*16];
        float v;
        if(branch == 0) v = sc[mt][nt][r]*SCALE_ + g;            // adjm has mask folded
        else            v = fmaxf(sc[mt][nt][r], 0.f)*g + mskv[nt];
        sc[mt][nt][r] = v;
      }
    }
  }

  #pragma unroll
  for(int mt = 0; mt < 2; mt++){
    #pragma unroll
    for(int r = 0; r < 4; r++){
      float m = -3.4e38f;
      #pragma unroll
      for(int nt = 0; nt < 8; nt++) m = fmaxf(m, sc[mt][nt][r]);
      m = fmaxf(m, __shfl_xor(m, 1));
      m = fmaxf(m, __shfl_xor(m, 2));
      m = fmaxf(m, __shfl_xor(m, 4));
      m = fmaxf(m, __shfl_xor(m, 8));
      float sum = 0.f;
      float e[8];
      #pragma unroll
      for(int nt = 0; nt < 8; nt++){ e[nt] = __expf(sc[mt][nt][r] - m); sum += e[nt]; }
      sum += __shfl_xor(sum, 1);
      sum += __shfl_xor(sum, 2);
      sum += __shfl_xor(sum, 4);
      sum += __shfl_xor(sum, 8);
      float inv = 1.0f / sum;
      int row = mbase + mt*16 + qd*4 + r;
      #pragma unroll
      for(int nt = 0; nt < 8; nt++) Ps[row][nt*16 + ln] = f2b(e[nt] * inv);
    }
  }
  // no barrier: each wave reads only its own P rows

  f32x4 oacc[2][2];
  #pragma unroll
  for(int mt = 0; mt < 2; mt++)
    #pragma unroll
    for(int n2 = 0; n2 < 2; n2++) oacc[mt][n2] = (f32x4){0.f,0.f,0.f,0.f};
  #pragma unroll
  for(int kk = 0; kk < 4; kk++){
    short8 pa[2], vb[2];
    #pragma unroll
    for(int mt = 0; mt < 2; mt++)
      pa[mt] = *(const short8*)&Ps[mbase + mt*16 + ln][kk*32 + qd*8];
    #pragma unroll
    for(int n2 = 0; n2 < 2; n2++)
      vb[n2] = *(const short8*)&Vt[n2*16 + ln][kk*32 + qd*8];
    #pragma unroll
    for(int mt = 0; mt < 2; mt++)
      #pragma unroll
      for(int n2 = 0; n2 < 2; n2++)
        oacc[mt][n2] = __builtin_amdgcn_mfma_f32_16x16x32_bf16(pa[mt], vb[n2], oacc[mt][n2], 0, 0, 0);
  }

  u16* Og = branch ? o2 : o1;
  #pragma unroll
  for(int mt = 0; mt < 2; mt++){
    #pragma unroll
    for(int n2 = 0; n2 < 2; n2++){
      #pragma unroll
      for(int r = 0; r < 4; r++){
        int row = mbase + mt*16 + qd*4 + r;
        int d   = n2*16 + ln;
        Og[(rowbase + row)*DH_ + hh*DEPTH_ + d] = f2b(oacc[mt][n2][r]);
      }
    }
  }
}

// ====== fused out-proj (both branches) + residual + LayerNorm1 ==============
// Block: 64 rows x 256 cols. Wave w owns 16 full rows -> LN in-register.
__global__ __launch_bounds__(256) void oproj_ln_kernel(
    const u16* __restrict__ o1, const u16* __restrict__ o2,
    const u16* __restrict__ w1, const u16* __restrict__ w2,
    const float* __restrict__ b1, const float* __restrict__ b2,
    const float* __restrict__ hres,
    const float* __restrict__ g, const float* __restrict__ be,
    float* __restrict__ out, u16* __restrict__ outb)
{
  __shared__ u16 As1[64*32], As2[64*32], Bs1[128*32], Bs2[128*32];
  __shared__ float biasv[256], gs[256], bes[256];
  const int t = threadIdx.x;
  const int lane = t & 63, w = t >> 6;
  const int ln = lane & 15, qd = lane >> 4;
  const int m0 = blockIdx.x * 64;
  if(t < 128){ biasv[t] = b1[t]; biasv[t+128] = b2[t]; }
  gs[t] = g[t]; bes[t] = be[t];
  const int srow = t >> 2, sc8 = (t & 3) * 8;
  f32x4 acc[16];
  #pragma unroll
  for(int i=0;i<16;i++) acc[i] = (f32x4){0.f,0.f,0.f,0.f};

  for(int k0 = 0; k0 < DH_; k0 += 32){
    __syncthreads();
    glds16(o1 + (size_t)(m0+srow)*DH_ + k0 + sc8, As1 + t*8);
    glds16(o2 + (size_t)(m0+srow)*DH_ + k0 + sc8, As2 + t*8);
    glds16(w1 + (size_t)srow*DH_      + k0 + sc8, Bs1 + t*8);
    glds16(w1 + (size_t)(64+srow)*DH_ + k0 + sc8, Bs1 + (t+256)*8);
    glds16(w2 + (size_t)srow*DH_      + k0 + sc8, Bs2 + t*8);
    glds16(w2 + (size_t)(64+srow)*DH_ + k0 + sc8, Bs2 + (t+256)*8);
    __syncthreads();
    short8 a1 = *(const short8*)&As1[(w*16+ln)*32 + qd*8];
    short8 a2 = *(const short8*)&As2[(w*16+ln)*32 + qd*8];
    #pragma unroll
    for(int nt = 0; nt < 8; nt++){
      short8 bv = *(const short8*)&Bs1[(nt*16+ln)*32 + qd*8];
      acc[nt] = __builtin_amdgcn_mfma_f32_16x16x32_bf16(a1, bv, acc[nt], 0, 0, 0);
    }
    #pragma unroll
    for(int nt = 0; nt < 8; nt++){
      short8 bv = *(const short8*)&Bs2[(nt*16+ln)*32 + qd*8];
      acc[8+nt] = __builtin_amdgcn_mfma_f32_16x16x32_bf16(a2, bv, acc[8+nt], 0, 0, 0);
    }
  }

  const int rb = m0 + w*16 + qd*4;
  float mu[4] = {0,0,0,0};
  #pragma unroll
  for(int nt = 0; nt < 16; nt++){
    int col = nt*16 + ln;
    float bv = biasv[col];
    #pragma unroll
    for(int r = 0; r < 4; r++){
      float v = acc[nt][r] + bv + hres[(size_t)(rb+r)*D_ + col];
      acc[nt][r] = v;
      mu[r] += v;
    }
  }
  #pragma unroll
  for(int r = 0; r < 4; r++){
    float s = mu[r];
    s += __shfl_xor(s,1); s += __shfl_xor(s,2); s += __shfl_xor(s,4); s += __shfl_xor(s,8);
    mu[r] = s * (1.0f/D_);
  }
  float iv[4] = {0,0,0,0};
  #pragma unroll
  for(int nt = 0; nt < 16; nt++)
    #pragma unroll
    for(int r = 0; r < 4; r++){ float d = acc[nt][r] - mu[r]; iv[r] += d*d; }
  #pragma unroll
  for(int r = 0; r < 4; r++){
    float s = iv[r];
    s += __shfl_xor(s,1); s += __shfl_xor(s,2); s += __shfl_xor(s,4); s += __shfl_xor(s,8);
    iv[r] = rsqrtf(s*(1.0f/D_) + 1e-6f);
  }
  #pragma unroll
  for(int nt = 0; nt < 16; nt++){
    int col = nt*16 + ln;
    float gg = gs[col], bb = bes[col];
    #pragma unroll
    for(int r = 0; r < 4; r++){
      float y = (acc[nt][r] - mu[r])*iv[r]*gg + bb;
      size_t idx = (size_t)(rb+r)*D_ + col;
      out[idx] = y;
      outb[idx] = f2b(y);
    }
  }
}

// ====== fused FFN2 + residual + LayerNorm2 ==================================
// C = A[M][512] @ W[256][512]^T + bias; LN(C + res). Block 64 rows, wave=16 rows.
__global__ __launch_bounds__(256) void ffn2_ln_kernel(
    const u16* __restrict__ A, const u16* __restrict__ W,
    const float* __restrict__ bias,
    const float* __restrict__ res,
    const float* __restrict__ g, const float* __restrict__ be,
    float* __restrict__ out, u16* __restrict__ outb)
{
  __shared__ u16 As[64*32], Bs[256*32];
  __shared__ float biasv[256], gs[256], bes[256];
  const int t = threadIdx.x;
  const int lane = t & 63, w = t >> 6;
  const int ln = lane & 15, qd = lane >> 4;
  const int m0 = blockIdx.x * 64;
  biasv[t] = bias[t]; gs[t] = g[t]; bes[t] = be[t];
  const int srow = t >> 2, sc8 = (t & 3) * 8;
  f32x4 acc[16];
  #pragma unroll
  for(int i=0;i<16;i++) acc[i] = (f32x4){0.f,0.f,0.f,0.f};

  for(int k0 = 0; k0 < DFF_; k0 += 32){
    __syncthreads();
    glds16(A + (size_t)(m0+srow)*DFF_ + k0 + sc8, As + t*8);
    #pragma unroll
    for(int j = 0; j < 4; j++)
      glds16(W + (size_t)(j*64+srow)*DFF_ + k0 + sc8, Bs + ((size_t)t + 256*j)*8);
    __syncthreads();
    short8 a = *(const short8*)&As[(w*16+ln)*32 + qd*8];
    #pragma unroll
    for(int nt = 0; nt < 16; nt++){
      short8 bv = *(const short8*)&Bs[(nt*16+ln)*32 + qd*8];
      acc[nt] = __builtin_amdgcn_mfma_f32_16x16x32_bf16(a, bv, acc[nt], 0, 0, 0);
    }
  }

  const int rb = m0 + w*16 + qd*4;
  float mu[4] = {0,0,0,0};
  #pragma unroll
  for(int nt = 0; nt < 16; nt++){
    int col = nt*16 + ln;
    float bv = biasv[col];
    #pragma unroll
    for(int r = 0; r < 4; r++){
      float v = acc[nt][r] + bv + res[(size_t)(rb+r)*D_ + col];
      acc[nt][r] = v;
      mu[r] += v;
    }
  }
  #pragma unroll
  for(int r = 0; r < 4; r++){
    float s = mu[r];
    s += __shfl_xor(s,1); s += __shfl_xor(s,2); s += __shfl_xor(s,4); s += __shfl_xor(s,8);
    mu[r] = s * (1.0f/D_);
  }
  float iv[4] = {0,0,0,0};
  #pragma unroll
  for(int nt = 0; nt < 16; nt++)
    #pragma unroll
    for(int r = 0; r < 4; r++){ float d = acc[nt][r] - mu[r]; iv[r] += d*d; }
  #pragma unroll
  for(int r = 0; r < 4; r++){
    float s = iv[r];
    s += __shfl_xor(s,1); s += __shfl_xor(s,2); s += __shfl_xor(s,4); s += __shfl_xor(s,8);
    iv[r] = rsqrtf(s*(1.0f/D_) + 1e-6f);
  }
  #pragma unroll
  for(int nt = 0; nt < 16; nt++){
    int col = nt*16 + ln;
    float gg = gs[col], bb = bes[col];
    #pragma unroll
    for(int r = 0; r < 4; r++){
      float y = (acc[nt][r] - mu[r])*iv[r]*gg + bb;
      size_t idx = (size_t)(rb+r)*D_ + col;
      out[idx] = y;
      outb[idx] = f2b(y);
    }
  }
}

// ---------------- pooled[b,n,:] = (amm[b,n,:] @ h[b]) / sum_atoms -----------
__global__ __launch_bounds__(256) void pool_kernel(
    const float* __restrict__ amm, const float* __restrict__ sum_atoms,
    const float* __restrict__ h, u16* __restrict__ pooled_bf)
{
  __shared__ float as[S_];
  int bn = blockIdx.x;
  int b  = bn >> 5;
  int t  = threadIdx.x;
  if(t < S_) as[t] = amm[(size_t)bn*S_ + t];
  __syncthreads();
  float acc = 0.f;
  const float* hb = h + (size_t)b*S_*D_ + t;
  #pragma unroll 4
  for(int s = 0; s < S_; s++) acc = fmaf(as[s], hb[(size_t)s*D_], acc);
  pooled_bf[(size_t)bn*D_ + t] = f2b(acc / sum_atoms[bn]);
}

// ============================ host-side launcher ============================
extern "C" void kernel_launch(void* const* d_in, const int* in_sizes, int n_in,
                              void* d_out, int out_size, void* d_ws, size_t ws_size,
                              hipStream_t stream)
{
  const float* x     = (const float*)d_in[0];
  const float* adj   = (const float*)d_in[1];
  const float* dist  = (const float*)d_in[2];
  const float* amm   = (const float*)d_in[3];
  const float* sum_a = (const float*)d_in[4];
  const float* embW  = (const float*)d_in[5];
  const float* embB  = (const float*)d_in[6];
  const float* globW = (const float*)d_in[7];
  const float* globB = (const float*)d_in[8];
  const float* Wq1 = (const float*)d_in[9],  *Wk1 = (const float*)d_in[10],
             *Wv1 = (const float*)d_in[11], *Wo1 = (const float*)d_in[12],
             *Wq2 = (const float*)d_in[13], *Wk2 = (const float*)d_in[14],
             *Wv2 = (const float*)d_in[15], *Wo2 = (const float*)d_in[16];
  const float* bq1 = (const float*)d_in[17], *bk1 = (const float*)d_in[18],
             *bv1 = (const float*)d_in[19], *bo1 = (const float*)d_in[20],
             *bq2 = (const float*)d_in[21], *bk2 = (const float*)d_in[22],
             *bv2 = (const float*)d_in[23], *bo2 = (const float*)d_in[24];
  const float* Wf1 = (const float*)d_in[25], *bf1 = (const float*)d_in[26],
             *Wf2 = (const float*)d_in[27], *bf2 = (const float*)d_in[28],
             *g1  = (const float*)d_in[29], *be1 = (const float*)d_in[30],
             *g2  = (const float*)d_in[31], *be2 = (const float*)d_in[32];

  float* wsf = (float*)d_ws;
  float* h     = wsf; wsf += (size_t)MS_*D_;
  float* maskb = wsf; wsf += MS_;
  float* distr = wsf; wsf += (size_t)B_*S_*S_;
  float* adjm  = wsf; wsf += (size_t)B_*S_*S_;
  float* qkvslab = wsf; wsf += (size_t)MS_*DH_*8;   // 8 bf16 slots (q1..v2,o1,o2)
  float* out1  = wsf; wsf += (size_t)MS_*D_;
  // bf16 region
  u16* bb = (u16*)wsf;
  u16* h_bf    = bb; bb += (size_t)MS_*D_;
  u16* out1_bf = bb; bb += (size_t)MS_*D_;
  u16* pooled_bf = bb; bb += (size_t)B_*NSUB_*D_;
  u16* globWt  = bb; bb += (size_t)D_*D_;
  u16* wq1t = bb; bb += (size_t)L_*DH_*DH_;
  u16* wk1t = bb; bb += (size_t)L_*DH_*DH_;
  u16* wv1t = bb; bb += (size_t)L_*DH_*DH_;
  u16* wo1t = bb; bb += (size_t)L_*DH_*DH_;
  u16* wq2t = bb; bb += (size_t)L_*DH_*DH_;
  u16* wk2t = bb; bb += (size_t)L_*DH_*DH_;
  u16* wv2t = bb; bb += (size_t)L_*DH_*DH_;
  u16* wo2t = bb; bb += (size_t)L_*DH_*DH_;
  u16* wf1t = bb; bb += (size_t)L_*D_*DFF_;
  u16* wf2t = bb; bb += (size_t)L_*DFF_*D_;
  // bf16 aliases into qkvslab
  u16* q1b = (u16*)qkvslab;
  u16* k1b = q1b + (size_t)MS_*DH_;
  u16* v1b = k1b + (size_t)MS_*DH_;
  u16* q2b = v1b + (size_t)MS_*DH_;
  u16* k2b = q2b + (size_t)MS_*DH_;
  u16* v2b = k2b + (size_t)MS_*DH_;
  u16* o1_bf = v2b + (size_t)MS_*DH_;
  u16* o2_bf = o1_bf + (size_t)MS_*DH_;
  u16* ffn1_bf = q1b;   // q1..q2 slots (4.19M u16), dead after attn

  mask_kernel   <<<MS_/256,        256, 0, stream>>>(x, maskb);
  rescale_kernel<<<(B_*S_*S_)/256, 256, 0, stream>>>(dist, distr);
  adjm_kernel   <<<(B_*S_*S_)/256, 256, 0, stream>>>(adj, maskb, adjm);
  embed_kernel  <<<MS_/4,          256, 0, stream>>>(x, embW, embB, h, h_bf);

  dim3 tb(32, 8);
  transpose_kernel<<<dim3(4,4,L_),  tb, 0, stream>>>(Wq1, wq1t, DH_, DH_);
  transpose_kernel<<<dim3(4,4,L_),  tb, 0, stream>>>(Wk1, wk1t, DH_, DH_);
  transpose_kernel<<<dim3(4,4,L_),  tb, 0, stream>>>(Wv1, wv1t, DH_, DH_);
  transpose_kernel<<<dim3(4,4,L_),  tb, 0, stream>>>(Wo1, wo1t, DH_, DH_);
  transpose_kernel<<<dim3(4,4,L_),  tb, 0, stream>>>(Wq2, wq2t, DH_, DH_);
  transpose_kernel<<<dim3(4,4,L_),  tb, 0, stream>>>(Wk2, wk2t, DH_, DH_);
  transpose_kernel<<<dim3(4,4,L_),  tb, 0, stream>>>(Wv2, wv2t, DH_, DH_);
  transpose_kernel<<<dim3(4,4,L_),  tb, 0, stream>>>(Wo2, wo2t, DH_, DH_);
  transpose_kernel<<<dim3(16,8,L_), tb, 0, stream>>>(Wf1, wf1t, D_, DFF_);
  transpose_kernel<<<dim3(8,16,L_), tb, 0, stream>>>(Wf2, wf2t, DFF_, D_);
  transpose_kernel<<<dim3(8,8,1),   tb, 0, stream>>>(globW, globWt, D_, D_);

  for(int l = 0; l < L_; l++){
    // QKV: 6 GEMMs M=8192 N=128 K=128, out bf16, TM=64 (768 blocks)
    {
      MG6 a;
      const u16* Wt[6] = {wq1t, wk1t, wv1t, wq2t, wk2t, wv2t};
      const float* bs[6] = {bq1, bk1, bv1, bq2, bk2, bv2};
      u16* Cs[6] = {q1b, k1b, v1b, q2b, k2b, v2b};
      for(int z = 0; z < 6; z++){
        a.g[z].A = h_bf; a.g[z].W = Wt[z] + (size_t)l*DH_*DH_;
        a.g[z].bias = bs[z] + (size_t)l*DH_; a.g[z].C = Cs[z];
        a.g[z].lda = D_; a.g[z].K = DH_; a.g[z].ldc = DH_;
        a.g[z].aofs = (z/3)*DH_; a.g[z].cofs = 0;
      }
      mgemm_kernel<64,true,0><<<dim3(MS_/64, 1, 6), 256, 0, stream>>>(a);
    }
    attn_mfma_kernel<<<dim3(B_*H_, 2), 256, 0, stream>>>(q1b,k1b,v1b, q2b,k2b,v2b,
                                                         adjm, distr, maskb, o1_bf, o2_bf);
    oproj_ln_kernel<<<MS_/64, 256, 0, stream>>>(
        o1_bf, o2_bf,
        wo1t + (size_t)l*DH_*DH_, wo2t + (size_t)l*DH_*DH_,
        bo1 + (size_t)l*DH_, bo2 + (size_t)l*DH_,
        h, g1 + (size_t)l*D_, be1 + (size_t)l*D_,
        out1, out1_bf);
    // FFN1: M=8192 N=512 K=256, gelu, out bf16, TM=64 (512 blocks)
    {
      MG6 a;
      a.g[0].A = out1_bf; a.g[0].W = wf1t + (size_t)l*D_*DFF_;
      a.g[0].bias = bf1 + (size_t)l*DFF_; a.g[0].C = ffn1_bf;
      a.g[0].lda = D_; a.g[0].K = D_; a.g[0].ldc = DFF_;
      a.g[0].aofs = 0; a.g[0].cofs = 0;
      mgemm_kernel<64,true,2><<<dim3(MS_/64, DFF_/128, 1), 256, 0, stream>>>(a);
    }
    ffn2_ln_kernel<<<MS_/64, 256, 0, stream>>>(
        ffn1_bf, wf2t + (size_t)l*DFF_*D_,
        bf2 + (size_t)l*D_,
        out1, g2 + (size_t)l*D_, be2 + (size_t)l*D_,
        h, h_bf);
  }

  pool_kernel<<<B_*NSUB_, 256, 0, stream>>>(amm, sum_a, h, pooled_bf);
  // final: relu(pooled @ glob_W + glob_b), M=2048 N=256 K=256, MFMA, out f32
  {
    MG6 a;
    a.g[0].A = pooled_bf; a.g[0].W = globWt;
    a.g[0].bias = globB; a.g[0].C = (float*)d_out;
    a.g[0].lda = D_; a.g[0].K = D_; a.g[0].ldc = D_;
    a.g[0].aofs = 0; a.g[0].cofs = 0;
    mgemm_kernel<64,false,1><<<dim3((B_*NSUB_)/64, D_/128, 1), 256, 0, stream>>>(a);
  }
}

// Round 5
// 475.146 us; speedup vs baseline: 2.4698x; 1.1927x over previous
//
#include <hip/hip_runtime.h>
#include <math.h>

#define B_ 64
#define S_ 128
#define F_ 62
#define D_ 256
#define H_ 4
#define L_ 6
#define NSUB_ 32
#define DFF_ 512
#define DH_ 128
#define DEPTH_ 32
#define MS_ (B_*S_)                 // 8192 rows
#define NEGV (-1000000000.0f)
#define SCALE_ 0.17677669529663687f // 1/sqrt(32)

typedef unsigned short u16;
typedef __attribute__((ext_vector_type(8))) short short8;
typedef __attribute__((ext_vector_type(4))) float f32x4;

// f32 -> bf16 round-to-nearest-even
__device__ __forceinline__ u16 f2b(float f){
  unsigned u = __float_as_uint(f);
  unsigned r = (u + 0x7fffu + ((u >> 16) & 1u)) >> 16;
  return (u16)r;
}

__device__ __forceinline__ void glds16(const void* g, void* l){
  __builtin_amdgcn_global_load_lds(
      (const __attribute__((address_space(1))) unsigned int*)g,
      (__attribute__((address_space(3))) unsigned int*)l, 16, 0, 0);
}

// ------- adjm = adj + mask; distr = rescale(dist)*scale (one pass) ----------
__global__ __launch_bounds__(256) void adjrescale_kernel(
    const float* __restrict__ adj, const float* __restrict__ dist,
    const float* __restrict__ maskb,
    float* __restrict__ adjm, float* __restrict__ distr){
  size_t i = (size_t)blockIdx.x*256 + threadIdx.x;
  int j = (int)(i & (S_-1));
  int b = (int)(i >> 14);            // S_*S_ = 16384
  const float e1 = 2.718281828459045f;
  distr[i] = (1.0f + e1) / (1.0f + expf(1.0f - dist[i])) * SCALE_;
  adjm[i]  = adj[i] + maskb[b*S_ + j];
}

// ------ all weight transposes in ONE dispatch: dst[l][n][k] = src[l][k][n] --
struct TD { const float* src; u16* dst; int K, N, L; };
struct TDs { TD d[11]; };
__global__ __launch_bounds__(256) void transpose_all_kernel(TDs a){
  const TD p = a.d[blockIdx.z];
  int n0 = blockIdx.x*32, k0 = blockIdx.y*32;
  if(n0 >= p.N || k0 >= p.K) return;
  __shared__ float tbuf[32][33];
  int tx = threadIdx.x, ty = threadIdx.y;   // 32 x 8
  for(int l = 0; l < p.L; l++){
    const float* src = p.src + (size_t)l*p.K*p.N;
    u16* dst = p.dst + (size_t)l*p.K*p.N;
    #pragma unroll
    for(int i = 0; i < 4; i++)
      tbuf[ty + i*8][tx] = src[(size_t)(k0 + ty + i*8)*p.N + n0 + tx];
    __syncthreads();
    #pragma unroll
    for(int i = 0; i < 4; i++)
      dst[(size_t)(n0 + ty + i*8)*p.K + k0 + tx] = f2b(tbuf[tx][ty + i*8]);
    __syncthreads();
  }
}

// --------- embed: h = relu(x @ emb_W + emb_b), K=62; also emits maskb -------
__global__ __launch_bounds__(256) void embed_kernel(const float* __restrict__ x,
    const float* __restrict__ W, const float* __restrict__ bias,
    float* __restrict__ h, u16* __restrict__ h_bf, float* __restrict__ maskb){
  __shared__ float xs[4][F_];
  int r0 = blockIdx.x*4;
  int t = threadIdx.x;
  if(t < 4*F_){ int rr = t / F_, ff = t - rr*F_; xs[rr][ff] = x[(size_t)(r0+rr)*F_ + ff]; }
  __syncthreads();
  if(t < 4){
    float s = 0.f;
    #pragma unroll
    for(int f = 0; f < F_; f++) s += xs[t][f];
    maskb[r0 + t] = (s == 0.0f) ? NEGV : 0.0f;
  }
  float b = bias[t];
  float a0=b, a1=b, a2=b, a3=b;
  for(int k=0; k<F_; k++){
    float w = W[k*D_ + t];
    a0 = fmaf(xs[0][k], w, a0);
    a1 = fmaf(xs[1][k], w, a1);
    a2 = fmaf(xs[2][k], w, a2);
    a3 = fmaf(xs[3][k], w, a3);
  }
  a0 = fmaxf(a0, 0.f); a1 = fmaxf(a1, 0.f); a2 = fmaxf(a2, 0.f); a3 = fmaxf(a3, 0.f);
  h[(size_t)(r0+0)*D_ + t] = a0;  h_bf[(size_t)(r0+0)*D_ + t] = f2b(a0);
  h[(size_t)(r0+1)*D_ + t] = a1;  h_bf[(size_t)(r0+1)*D_ + t] = f2b(a1);
  h[(size_t)(r0+2)*D_ + t] = a2;  h_bf[(size_t)(r0+2)*D_ + t] = f2b(a2);
  h[(size_t)(r0+3)*D_ + t] = a3;  h_bf[(size_t)(r0+3)*D_ + t] = f2b(a3);
}

// =================== bf16 MFMA GEMM (TM x 128 tile) =========================
struct MG {
  const u16* A; const u16* W; const float* bias; void* C;
  int lda, K, ldc, aofs, cofs;
};
struct MG6 { MG g[6]; };

template<int TM, bool OUTBF, int ACT>
__global__ __launch_bounds__(256) void mgemm_kernel(MG6 args){
  const MG p = args.g[blockIdx.z];
  __shared__ u16 As[TM*32];
  __shared__ u16 Bs[128*32];
  const int t    = threadIdx.x;
  const int lane = t & 63;
  const int w    = t >> 6;
  const int ln   = lane & 15;
  const int qd   = lane >> 4;
  const int mw   = (w & 1) * (TM/2);
  const int nw   = (w >> 1) * 64;
  const int m0   = blockIdx.x * TM;
  const int n0   = blockIdx.y * 128;
  constexpr int MI = TM/32;
  f32x4 acc[MI][4];
  #pragma unroll
  for(int i=0;i<MI;i++)
    #pragma unroll
    for(int j=0;j<4;j++) acc[i][j] = (f32x4){0.f,0.f,0.f,0.f};

  const int srow = t >> 2;
  const int sc8  = (t & 3) * 8;

  for(int k0 = 0; k0 < p.K; k0 += 32){
    __syncthreads();
    glds16(p.A + (size_t)(m0 + srow)*p.lda + p.aofs + k0 + sc8, As + t*8);
    if(TM == 128)
      glds16(p.A + (size_t)(m0 + 64 + srow)*p.lda + p.aofs + k0 + sc8, As + (t+256)*8);
    glds16(p.W + (size_t)(n0 + srow)*p.K + k0 + sc8, Bs + t*8);
    glds16(p.W + (size_t)(n0 + 64 + srow)*p.K + k0 + sc8, Bs + (t+256)*8);
    __syncthreads();

    short8 a[MI], b[4];
    #pragma unroll
    for(int i=0;i<MI;i++) a[i] = *(const short8*)&As[(mw + i*16 + ln)*32 + qd*8];
    #pragma unroll
    for(int j=0;j<4;j++)  b[j] = *(const short8*)&Bs[(nw + j*16 + ln)*32 + qd*8];
    #pragma unroll
    for(int i=0;i<MI;i++)
      #pragma unroll
      for(int j=0;j<4;j++)
        acc[i][j] = __builtin_amdgcn_mfma_f32_16x16x32_bf16(a[i], b[j], acc[i][j], 0, 0, 0);
  }

  #pragma unroll
  for(int i=0;i<MI;i++){
    #pragma unroll
    for(int j=0;j<4;j++){
      int col = n0 + nw + j*16 + ln;
      float bv = p.bias[col];
      int rowb = m0 + mw + i*16 + qd*4;
      #pragma unroll
      for(int r=0;r<4;r++){
        float v = acc[i][j][r] + bv;
        if(ACT == 1) v = fmaxf(v, 0.f);
        if(ACT == 2) v = 0.5f*v*(1.0f + erff(v*0.70710678118654752f));
        size_t idx = (size_t)(rowb + r)*p.ldc + p.cofs + col;
        if(OUTBF) ((u16*)p.C)[idx] = f2b(v);
        else      ((float*)p.C)[idx] = v;
      }
    }
  }
}

// ====== fused QKV-projection + attention: block per (b, head, branch) =======
// Phase1: Q/K/V = h @ W^T (head slice) via MFMA, K-loop over 128.
// Q,K -> LDS row-major [128][40]; V -> LDS transposed [32][136].
// Phase2: QK^T from LDS frags; softmax; P -> LDS (aliases phase1 buffers);
// PV; O -> global bf16.
struct QAArgs { const u16 *wq, *wk, *wv; const float *bq, *bk, *bv; };

__global__ __launch_bounds__(256) void qkv_attn_kernel(
    const u16* __restrict__ h_bf,
    QAArgs a1, QAArgs a2,
    const float* __restrict__ adjm, const float* __restrict__ distr,
    const float* __restrict__ maskb,
    u16* __restrict__ o1, u16* __restrict__ o2)
{
  __shared__ u16 SH[21760];          // 42.5 KB
  u16* As = SH;                      // [128][32]  (phase1 staging)
  u16* Bs = SH + 4096;               // [96][32]   rows: 0-31 Wq, 32-63 Wk, 64-95 Wv
  u16* Qs = SH + 7168;               // [128][40]
  u16* Ks = SH + 12288;              // [128][40]
  u16* Vt = SH + 17408;              // [32][136]
  u16* Ps = SH;                      // [128][136] alias of As..Ks (phase2)

  const int bh = blockIdx.x;
  const int b  = bh >> 2;
  const int hh = bh & 3;
  const int branch = blockIdx.y;
  const QAArgs qa = branch ? a2 : a1;
  const u16* wqp = qa.wq + (size_t)hh*32*DH_;
  const u16* wkp = qa.wk + (size_t)hh*32*DH_;
  const u16* wvp = qa.wv + (size_t)hh*32*DH_;
  const int t = threadIdx.x;
  const int w = t >> 6, lane = t & 63;
  const int ln = lane & 15, qd = lane >> 4;
  const size_t rowbase = (size_t)b * S_;
  const int srow = t >> 2, sc8 = (t & 3) * 8;

  // ---------------- phase 1: QKV projection ----------------
  f32x4 acc[2][6];                   // [mtile][n: q0,q1,k0,k1,v0,v1]
  #pragma unroll
  for(int i=0;i<2;i++)
    #pragma unroll
    for(int j=0;j<6;j++) acc[i][j] = (f32x4){0.f,0.f,0.f,0.f};

  for(int k0 = 0; k0 < DH_; k0 += 32){
    __syncthreads();
    // A: 128 rows x 32k = 512 chunks of 16B
    glds16(h_bf + (rowbase + srow)*D_ + branch*DH_ + k0 + sc8, As + t*8);
    glds16(h_bf + (rowbase + 64 + srow)*D_ + branch*DH_ + k0 + sc8, As + (t+256)*8);
    // B: 96 rows x 32k = 384 chunks
    {
      int r = t >> 2;                              // 0..63
      const u16* wp = (r < 32) ? wqp : wkp;
      glds16(wp + (size_t)(r & 31)*DH_ + k0 + sc8, Bs + t*8);
    }
    if(t < 128){
      int c = 256 + t;
      glds16(wvp + (size_t)((c>>2) - 64)*DH_ + k0 + (c&3)*8, Bs + c*8);
    }
    __syncthreads();
    short8 av[2];
    #pragma unroll
    for(int mt = 0; mt < 2; mt++)
      av[mt] = *(const short8*)&As[(w*32 + mt*16 + ln)*32 + qd*8];
    #pragma unroll
    for(int nt = 0; nt < 6; nt++){
      short8 bv = *(const short8*)&Bs[(nt*16 + ln)*32 + qd*8];
      #pragma unroll
      for(int mt = 0; mt < 2; mt++)
        acc[mt][nt] = __builtin_amdgcn_mfma_f32_16x16x32_bf16(av[mt], bv, acc[mt][nt], 0, 0, 0);
    }
  }

  // epilogue: bias + scatter to LDS (Q,K row-major; V transposed)
  {
    const float* bqp = qa.bq + hh*32;
    const float* bkp = qa.bk + hh*32;
    const float* bvp = qa.bv + hh*32;
    #pragma unroll
    for(int mt = 0; mt < 2; mt++){
      int rb = w*32 + mt*16 + qd*4;
      #pragma unroll
      for(int j = 0; j < 2; j++){
        int d = j*16 + ln;
        float bq_ = bqp[d], bk_ = bkp[d], bv_ = bvp[d];
        #pragma unroll
        for(int r = 0; r < 4; r++){
          Qs[(rb+r)*40 + d]   = f2b(acc[mt][j][r]   + bq_);
          Ks[(rb+r)*40 + d]   = f2b(acc[mt][2+j][r] + bk_);
          Vt[d*136 + rb + r]  = f2b(acc[mt][4+j][r] + bv_);
        }
      }
    }
  }
  __syncthreads();

  // ---------------- phase 2: attention ----------------
  const int mbase = w * 32;
  short8 qf[2];
  #pragma unroll
  for(int mt = 0; mt < 2; mt++)
    qf[mt] = *(const short8*)&Qs[(mbase + mt*16 + ln)*40 + qd*8];
  short8 kf[8];
  #pragma unroll
  for(int nt = 0; nt < 8; nt++)
    kf[nt] = *(const short8*)&Ks[(nt*16 + ln)*40 + qd*8];
  __syncthreads();   // all frags in regs before Ps overwrites Qs/Ks/staging

  f32x4 sc[2][8];
  #pragma unroll
  for(int mt = 0; mt < 2; mt++)
    #pragma unroll
    for(int nt = 0; nt < 8; nt++)
      sc[mt][nt] = __builtin_amdgcn_mfma_f32_16x16x32_bf16(
          qf[mt], kf[nt], (f32x4){0.f,0.f,0.f,0.f}, 0, 0, 0);

  float mskv[8];
  if(branch){
    #pragma unroll
    for(int nt = 0; nt < 8; nt++) mskv[nt] = maskb[rowbase + nt*16 + ln];
  }

  #pragma unroll
  for(int mt = 0; mt < 2; mt++){
    #pragma unroll
    for(int r = 0; r < 4; r++){
      int row = mbase + mt*16 + qd*4 + r;
      const float* arow = (branch ? distr : adjm) + (rowbase + row)*S_ + ln;
      #pragma unroll
      for(int nt = 0; nt < 8; nt++){
        float g = arow[nt*16];
        float v;
        if(branch == 0) v = sc[mt][nt][r]*SCALE_ + g;         // adjm has mask folded
        else            v = fmaxf(sc[mt][nt][r], 0.f)*g + mskv[nt];
        sc[mt][nt][r] = v;
      }
    }
  }

  #pragma unroll
  for(int mt = 0; mt < 2; mt++){
    #pragma unroll
    for(int r = 0; r < 4; r++){
      float m = -3.4e38f;
      #pragma unroll
      for(int nt = 0; nt < 8; nt++) m = fmaxf(m, sc[mt][nt][r]);
      m = fmaxf(m, __shfl_xor(m, 1));
      m = fmaxf(m, __shfl_xor(m, 2));
      m = fmaxf(m, __shfl_xor(m, 4));
      m = fmaxf(m, __shfl_xor(m, 8));
      float sum = 0.f;
      float e[8];
      #pragma unroll
      for(int nt = 0; nt < 8; nt++){ e[nt] = __expf(sc[mt][nt][r] - m); sum += e[nt]; }
      sum += __shfl_xor(sum, 1);
      sum += __shfl_xor(sum, 2);
      sum += __shfl_xor(sum, 4);
      sum += __shfl_xor(sum, 8);
      float inv = 1.0f / sum;
      int row = mbase + mt*16 + qd*4 + r;
      #pragma unroll
      for(int nt = 0; nt < 8; nt++) Ps[row*136 + nt*16 + ln] = f2b(e[nt] * inv);
    }
  }
  // no barrier: each wave reads only its own P rows

  f32x4 oacc[2][2];
  #pragma unroll
  for(int mt = 0; mt < 2; mt++)
    #pragma unroll
    for(int n2 = 0; n2 < 2; n2++) oacc[mt][n2] = (f32x4){0.f,0.f,0.f,0.f};
  #pragma unroll
  for(int kk = 0; kk < 4; kk++){
    short8 pa[2], vb[2];
    #pragma unroll
    for(int mt = 0; mt < 2; mt++)
      pa[mt] = *(const short8*)&Ps[(mbase + mt*16 + ln)*136 + kk*32 + qd*8];
    #pragma unroll
    for(int n2 = 0; n2 < 2; n2++)
      vb[n2] = *(const short8*)&Vt[(n2*16 + ln)*136 + kk*32 + qd*8];
    #pragma unroll
    for(int mt = 0; mt < 2; mt++)
      #pragma unroll
      for(int n2 = 0; n2 < 2; n2++)
        oacc[mt][n2] = __builtin_amdgcn_mfma_f32_16x16x32_bf16(pa[mt], vb[n2], oacc[mt][n2], 0, 0, 0);
  }

  u16* Og = branch ? o2 : o1;
  #pragma unroll
  for(int mt = 0; mt < 2; mt++){
    #pragma unroll
    for(int n2 = 0; n2 < 2; n2++){
      #pragma unroll
      for(int r = 0; r < 4; r++){
        int row = mbase + mt*16 + qd*4 + r;
        int d   = n2*16 + ln;
        Og[(rowbase + row)*DH_ + hh*DEPTH_ + d] = f2b(oacc[mt][n2][r]);
      }
    }
  }
}

// ====== fused out-proj (both branches) + residual + LayerNorm1 ==============
// 32 rows/block, 128 threads (2 waves x 16 full rows) -> grid 256 blocks.
__global__ __launch_bounds__(128) void oproj_ln_kernel(
    const u16* __restrict__ o1, const u16* __restrict__ o2,
    const u16* __restrict__ w1, const u16* __restrict__ w2,
    const float* __restrict__ b1, const float* __restrict__ b2,
    const float* __restrict__ hres,
    const float* __restrict__ g, const float* __restrict__ be,
    float* __restrict__ out, u16* __restrict__ outb)
{
  __shared__ u16 As1[32*32], As2[32*32], Bs1[128*32], Bs2[128*32];
  __shared__ float biasv[256], gs[256], bes[256];
  const int t = threadIdx.x;            // 0..127
  const int lane = t & 63, w = t >> 6;
  const int ln = lane & 15, qd = lane >> 4;
  const int m0 = blockIdx.x * 32;
  biasv[t] = b1[t & 127]; biasv[128 + t] = b2[t & 127];
  gs[t] = g[t]; gs[128+t] = g[128+t];
  bes[t] = be[t]; bes[128+t] = be[128+t];
  const int sc8 = (t & 3) * 8;
  f32x4 acc[16];
  #pragma unroll
  for(int i=0;i<16;i++) acc[i] = (f32x4){0.f,0.f,0.f,0.f};

  for(int k0 = 0; k0 < DH_; k0 += 32){
    __syncthreads();
    glds16(o1 + (size_t)(m0 + (t>>2))*DH_ + k0 + sc8, As1 + t*8);
    glds16(o2 + (size_t)(m0 + (t>>2))*DH_ + k0 + sc8, As2 + t*8);
    #pragma unroll
    for(int j = 0; j < 4; j++){
      int c = t + 128*j;
      glds16(w1 + (size_t)(c>>2)*DH_ + k0 + sc8, Bs1 + c*8);
      glds16(w2 + (size_t)(c>>2)*DH_ + k0 + sc8, Bs2 + c*8);
    }
    __syncthreads();
    short8 a1 = *(const short8*)&As1[(w*16+ln)*32 + qd*8];
    short8 a2 = *(const short8*)&As2[(w*16+ln)*32 + qd*8];
    #pragma unroll
    for(int nt = 0; nt < 8; nt++){
      short8 bv = *(const short8*)&Bs1[(nt*16+ln)*32 + qd*8];
      acc[nt] = __builtin_amdgcn_mfma_f32_16x16x32_bf16(a1, bv, acc[nt], 0, 0, 0);
    }
    #pragma unroll
    for(int nt = 0; nt < 8; nt++){
      short8 bv = *(const short8*)&Bs2[(nt*16+ln)*32 + qd*8];
      acc[8+nt] = __builtin_amdgcn_mfma_f32_16x16x32_bf16(a2, bv, acc[8+nt], 0, 0, 0);
    }
  }

  const int rb = m0 + w*16 + qd*4;
  float mu[4] = {0,0,0,0};
  #pragma unroll
  for(int nt = 0; nt < 16; nt++){
    int col = nt*16 + ln;
    float bv = biasv[col];
    #pragma unroll
    for(int r = 0; r < 4; r++){
      float v = acc[nt][r] + bv + hres[(size_t)(rb+r)*D_ + col];
      acc[nt][r] = v;
      mu[r] += v;
    }
  }
  #pragma unroll
  for(int r = 0; r < 4; r++){
    float s = mu[r];
    s += __shfl_xor(s,1); s += __shfl_xor(s,2); s += __shfl_xor(s,4); s += __shfl_xor(s,8);
    mu[r] = s * (1.0f/D_);
  }
  float iv[4] = {0,0,0,0};
  #pragma unroll
  for(int nt = 0; nt < 16; nt++)
    #pragma unroll
    for(int r = 0; r < 4; r++){ float d = acc[nt][r] - mu[r]; iv[r] += d*d; }
  #pragma unroll
  for(int r = 0; r < 4; r++){
    float s = iv[r];
    s += __shfl_xor(s,1); s += __shfl_xor(s,2); s += __shfl_xor(s,4); s += __shfl_xor(s,8);
    iv[r] = rsqrtf(s*(1.0f/D_) + 1e-6f);
  }
  #pragma unroll
  for(int nt = 0; nt < 16; nt++){
    int col = nt*16 + ln;
    float gg = gs[col], bb = bes[col];
    #pragma unroll
    for(int r = 0; r < 4; r++){
      float y = (acc[nt][r] - mu[r])*iv[r]*gg + bb;
      size_t idx = (size_t)(rb+r)*D_ + col;
      out[idx] = y;
      outb[idx] = f2b(y);
    }
  }
}

// ====== fused FFN2 + residual + LayerNorm2 (32 rows, 128 thr, grid 256) =====
__global__ __launch_bounds__(128) void ffn2_ln_kernel(
    const u16* __restrict__ A, const u16* __restrict__ W,
    const float* __restrict__ bias,
    const float* __restrict__ res,
    const float* __restrict__ g, const float* __restrict__ be,
    float* __restrict__ out, u16* __restrict__ outb)
{
  __shared__ u16 As[32*32], Bs[256*32];
  __shared__ float biasv[256], gs[256], bes[256];
  const int t = threadIdx.x;            // 0..127
  const int lane = t & 63, w = t >> 6;
  const int ln = lane & 15, qd = lane >> 4;
  const int m0 = blockIdx.x * 32;
  biasv[t] = bias[t]; biasv[128+t] = bias[128+t];
  gs[t] = g[t]; gs[128+t] = g[128+t];
  bes[t] = be[t]; bes[128+t] = be[128+t];
  const int sc8 = (t & 3) * 8;
  f32x4 acc[16];
  #pragma unroll
  for(int i=0;i<16;i++) acc[i] = (f32x4){0.f,0.f,0.f,0.f};

  for(int k0 = 0; k0 < DFF_; k0 += 32){
    __syncthreads();
    glds16(A + (size_t)(m0 + (t>>2))*DFF_ + k0 + sc8, As + t*8);
    #pragma unroll
    for(int j = 0; j < 8; j++){
      int c = t + 128*j;
      glds16(W + (size_t)(c>>2)*DFF_ + k0 + sc8, Bs + c*8);
    }
    __syncthreads();
    short8 a = *(const short8*)&As[(w*16+ln)*32 + qd*8];
    #pragma unroll
    for(int nt = 0; nt < 16; nt++){
      short8 bv = *(const short8*)&Bs[(nt*16+ln)*32 + qd*8];
      acc[nt] = __builtin_amdgcn_mfma_f32_16x16x32_bf16(a, bv, acc[nt], 0, 0, 0);
    }
  }

  const int rb = m0 + w*16 + qd*4;
  float mu[4] = {0,0,0,0};
  #pragma unroll
  for(int nt = 0; nt < 16; nt++){
    int col = nt*16 + ln;
    float bv = biasv[col];
    #pragma unroll
    for(int r = 0; r < 4; r++){
      float v = acc[nt][r] + bv + res[(size_t)(rb+r)*D_ + col];
      acc[nt][r] = v;
      mu[r] += v;
    }
  }
  #pragma unroll
  for(int r = 0; r < 4; r++){
    float s = mu[r];
    s += __shfl_xor(s,1); s += __shfl_xor(s,2); s += __shfl_xor(s,4); s += __shfl_xor(s,8);
    mu[r] = s * (1.0f/D_);
  }
  float iv[4] = {0,0,0,0};
  #pragma unroll
  for(int nt = 0; nt < 16; nt++)
    #pragma unroll
    for(int r = 0; r < 4; r++){ float d = acc[nt][r] - mu[r]; iv[r] += d*d; }
  #pragma unroll
  for(int r = 0; r < 4; r++){
    float s = iv[r];
    s += __shfl_xor(s,1); s += __shfl_xor(s,2); s += __shfl_xor(s,4); s += __shfl_xor(s,8);
    iv[r] = rsqrtf(s*(1.0f/D_) + 1e-6f);
  }
  #pragma unroll
  for(int nt = 0; nt < 16; nt++){
    int col = nt*16 + ln;
    float gg = gs[col], bb = bes[col];
    #pragma unroll
    for(int r = 0; r < 4; r++){
      float y = (acc[nt][r] - mu[r])*iv[r]*gg + bb;
      size_t idx = (size_t)(rb+r)*D_ + col;
      out[idx] = y;
      outb[idx] = f2b(y);
    }
  }
}

// ---------------- pooled[b,n,:] = (amm[b,n,:] @ h[b]) / sum_atoms -----------
__global__ __launch_bounds__(256) void pool_kernel(
    const float* __restrict__ amm, const float* __restrict__ sum_atoms,
    const float* __restrict__ h, u16* __restrict__ pooled_bf)
{
  __shared__ float as[S_];
  int bn = blockIdx.x;
  int b  = bn >> 5;
  int t  = threadIdx.x;
  if(t < S_) as[t] = amm[(size_t)bn*S_ + t];
  __syncthreads();
  float acc = 0.f;
  const float* hb = h + (size_t)b*S_*D_ + t;
  #pragma unroll 4
  for(int s = 0; s < S_; s++) acc = fmaf(as[s], hb[(size_t)s*D_], acc);
  pooled_bf[(size_t)bn*D_ + t] = f2b(acc / sum_atoms[bn]);
}

// ============================ host-side launcher ============================
extern "C" void kernel_launch(void* const* d_in, const int* in_sizes, int n_in,
                              void* d_out, int out_size, void* d_ws, size_t ws_size,
                              hipStream_t stream)
{
  const float* x     = (const float*)d_in[0];
  const float* adj   = (const float*)d_in[1];
  const float* dist  = (const float*)d_in[2];
  const float* amm   = (const float*)d_in[3];
  const float* sum_a = (const float*)d_in[4];
  const float* embW  = (const float*)d_in[5];
  const float* embB  = (const float*)d_in[6];
  const float* globW = (const float*)d_in[7];
  const float* globB = (const float*)d_in[8];
  const float* Wq1 = (const float*)d_in[9],  *Wk1 = (const float*)d_in[10],
             *Wv1 = (const float*)d_in[11], *Wo1 = (const float*)d_in[12],
             *Wq2 = (const float*)d_in[13], *Wk2 = (const float*)d_in[14],
             *Wv2 = (const float*)d_in[15], *Wo2 = (const float*)d_in[16];
  const float* bq1 = (const float*)d_in[17], *bk1 = (const float*)d_in[18],
             *bv1 = (const float*)d_in[19], *bo1 = (const float*)d_in[20],
             *bq2 = (const float*)d_in[21], *bk2 = (const float*)d_in[22],
             *bv2 = (const float*)d_in[23], *bo2 = (const float*)d_in[24];
  const float* Wf1 = (const float*)d_in[25], *bf1 = (const float*)d_in[26],
             *Wf2 = (const float*)d_in[27], *bf2 = (const float*)d_in[28],
             *g1  = (const float*)d_in[29], *be1 = (const float*)d_in[30],
             *g2  = (const float*)d_in[31], *be2 = (const float*)d_in[32];

  float* wsf = (float*)d_ws;
  float* h     = wsf; wsf += (size_t)MS_*D_;
  float* maskb = wsf; wsf += MS_;
  float* distr = wsf; wsf += (size_t)B_*S_*S_;
  float* adjm  = wsf; wsf += (size_t)B_*S_*S_;
  float* slab  = wsf; wsf += (size_t)MS_*DH_*8;   // 8 bf16 slots
  float* out1  = wsf; wsf += (size_t)MS_*D_;
  // bf16 region
  u16* bb = (u16*)wsf;
  u16* h_bf    = bb; bb += (size_t)MS_*D_;
  u16* out1_bf = bb; bb += (size_t)MS_*D_;
  u16* pooled_bf = bb; bb += (size_t)B_*NSUB_*D_;
  u16* globWt  = bb; bb += (size_t)D_*D_;
  u16* wq1t = bb; bb += (size_t)L_*DH_*DH_;
  u16* wk1t = bb; bb += (size_t)L_*DH_*DH_;
  u16* wv1t = bb; bb += (size_t)L_*DH_*DH_;
  u16* wo1t = bb; bb += (size_t)L_*DH_*DH_;
  u16* wq2t = bb; bb += (size_t)L_*DH_*DH_;
  u16* wk2t = bb; bb += (size_t)L_*DH_*DH_;
  u16* wv2t = bb; bb += (size_t)L_*DH_*DH_;
  u16* wo2t = bb; bb += (size_t)L_*DH_*DH_;
  u16* wf1t = bb; bb += (size_t)L_*D_*DFF_;
  u16* wf2t = bb; bb += (size_t)L_*DFF_*D_;
  // aliases into slab
  u16* ffn1_bf = (u16*)slab;                          // 4 slots (8192*512)
  u16* o1_bf   = (u16*)slab + (size_t)MS_*DH_*6;      // slot 6
  u16* o2_bf   = (u16*)slab + (size_t)MS_*DH_*7;      // slot 7

  embed_kernel<<<MS_/4, 256, 0, stream>>>(x, embW, embB, h, h_bf, maskb);
  adjrescale_kernel<<<(B_*S_*S_)/256, 256, 0, stream>>>(adj, dist, maskb, adjm, distr);
  {
    TDs td;
    const float* S8[8] = {Wq1, Wk1, Wv1, Wo1, Wq2, Wk2, Wv2, Wo2};
    u16* D8[8] = {wq1t, wk1t, wv1t, wo1t, wq2t, wk2t, wv2t, wo2t};
    for(int i = 0; i < 8; i++) td.d[i] = {S8[i], D8[i], DH_, DH_, L_};
    td.d[8]  = {Wf1, wf1t, D_, DFF_, L_};
    td.d[9]  = {Wf2, wf2t, DFF_, D_, L_};
    td.d[10] = {globW, globWt, D_, D_, 1};
    transpose_all_kernel<<<dim3(16,16,11), dim3(32,8), 0, stream>>>(td);
  }

  for(int l = 0; l < L_; l++){
    QAArgs a1 = { wq1t + (size_t)l*DH_*DH_, wk1t + (size_t)l*DH_*DH_, wv1t + (size_t)l*DH_*DH_,
                  bq1 + (size_t)l*DH_, bk1 + (size_t)l*DH_, bv1 + (size_t)l*DH_ };
    QAArgs a2 = { wq2t + (size_t)l*DH_*DH_, wk2t + (size_t)l*DH_*DH_, wv2t + (size_t)l*DH_*DH_,
                  bq2 + (size_t)l*DH_, bk2 + (size_t)l*DH_, bv2 + (size_t)l*DH_ };
    qkv_attn_kernel<<<dim3(B_*H_, 2), 256, 0, stream>>>(h_bf, a1, a2, adjm, distr, maskb,
                                                        o1_bf, o2_bf);
    oproj_ln_kernel<<<MS_/32, 128, 0, stream>>>(
        o1_bf, o2_bf,
        wo1t + (size_t)l*DH_*DH_, wo2t + (size_t)l*DH_*DH_,
        bo1 + (size_t)l*DH_, bo2 + (size_t)l*DH_,
        h, g1 + (size_t)l*D_, be1 + (size_t)l*D_,
        out1, out1_bf);
    // FFN1: M=8192 N=512 K=256, gelu, out bf16
    {
      MG6 a;
      a.g[0].A = out1_bf; a.g[0].W = wf1t + (size_t)l*D_*DFF_;
      a.g[0].bias = bf1 + (size_t)l*DFF_; a.g[0].C = ffn1_bf;
      a.g[0].lda = D_; a.g[0].K = D_; a.g[0].ldc = DFF_;
      a.g[0].aofs = 0; a.g[0].cofs = 0;
      mgemm_kernel<64,true,2><<<dim3(MS_/64, DFF_/128, 1), 256, 0, stream>>>(a);
    }
    ffn2_ln_kernel<<<MS_/32, 128, 0, stream>>>(
        ffn1_bf, wf2t + (size_t)l*DFF_*D_,
        bf2 + (size_t)l*D_,
        out1, g2 + (size_t)l*D_, be2 + (size_t)l*D_,
        h, h_bf);
  }

  pool_kernel<<<B_*NSUB_, 256, 0, stream>>>(amm, sum_a, h, pooled_bf);
  // final: relu(pooled @ glob_W + glob_b), M=2048 N=256 K=256
  {
    MG6 a;
    a.g[0].A = pooled_bf; a.g[0].W = globWt;
    a.g[0].bias = globB; a.g[0].C = (float*)d_out;
    a.g[0].lda = D_; a.g[0].K = D_; a.g[0].ldc = D_;
    a.g[0].aofs = 0; a.g[0].cofs = 0;
    mgemm_kernel<64,false,1><<<dim3((B_*NSUB_)/64, D_/128, 1), 256, 0, stream>>>(a);
  }
}

// Round 6
// 453.237 us; speedup vs baseline: 2.5892x; 1.0483x over previous
//
#include <hip/hip_runtime.h>
#include <math.h>

#define B_ 64
#define S_ 128
#define F_ 62
#define D_ 256
#define H_ 4
#define L_ 6
#define NSUB_ 32
#define DFF_ 512
#define DH_ 128
#define DEPTH_ 32
#define MS_ (B_*S_)                 // 8192 rows
#define NEGV (-1000000000.0f)
#define SCALE_ 0.17677669529663687f // 1/sqrt(32)

typedef unsigned short u16;
typedef __attribute__((ext_vector_type(8))) short short8;
typedef __attribute__((ext_vector_type(4))) float f32x4;

// f32 -> bf16 round-to-nearest-even
__device__ __forceinline__ u16 f2b(float f){
  unsigned u = __float_as_uint(f);
  unsigned r = (u + 0x7fffu + ((u >> 16) & 1u)) >> 16;
  return (u16)r;
}

__device__ __forceinline__ void glds16(const void* g, void* l){
  __builtin_amdgcn_global_load_lds(
      (const __attribute__((address_space(1))) unsigned int*)g,
      (__attribute__((address_space(3))) unsigned int*)l, 16, 0, 0);
}

// ------- adjm = adj + mask; distr = rescale(dist)*scale (one pass) ----------
__global__ __launch_bounds__(256) void adjrescale_kernel(
    const float* __restrict__ adj, const float* __restrict__ dist,
    const float* __restrict__ maskb,
    float* __restrict__ adjm, float* __restrict__ distr){
  size_t i = (size_t)blockIdx.x*256 + threadIdx.x;
  int j = (int)(i & (S_-1));
  int b = (int)(i >> 14);            // S_*S_ = 16384
  const float e1 = 2.718281828459045f;
  distr[i] = (1.0f + e1) / (1.0f + expf(1.0f - dist[i])) * SCALE_;
  adjm[i]  = adj[i] + maskb[b*S_ + j];
}

// ------ all weight transposes in ONE dispatch: dst[l][n][k] = src[l][k][n] --
struct TD { const float* src; u16* dst; int K, N, L; };
struct TDs { TD d[11]; };
__global__ __launch_bounds__(256) void transpose_all_kernel(TDs a){
  const TD p = a.d[blockIdx.z];
  int n0 = blockIdx.x*32, k0 = blockIdx.y*32;
  if(n0 >= p.N || k0 >= p.K) return;
  __shared__ float tbuf[32][33];
  int tx = threadIdx.x, ty = threadIdx.y;   // 32 x 8
  for(int l = 0; l < p.L; l++){
    const float* src = p.src + (size_t)l*p.K*p.N;
    u16* dst = p.dst + (size_t)l*p.K*p.N;
    #pragma unroll
    for(int i = 0; i < 4; i++)
      tbuf[ty + i*8][tx] = src[(size_t)(k0 + ty + i*8)*p.N + n0 + tx];
    __syncthreads();
    #pragma unroll
    for(int i = 0; i < 4; i++)
      dst[(size_t)(n0 + ty + i*8)*p.K + k0 + tx] = f2b(tbuf[tx][ty + i*8]);
    __syncthreads();
  }
}

// --------- embed: h = relu(x @ emb_W + emb_b), K=62; also emits maskb -------
__global__ __launch_bounds__(256) void embed_kernel(const float* __restrict__ x,
    const float* __restrict__ W, const float* __restrict__ bias,
    float* __restrict__ h, u16* __restrict__ h_bf, float* __restrict__ maskb){
  __shared__ float xs[4][F_];
  int r0 = blockIdx.x*4;
  int t = threadIdx.x;
  if(t < 4*F_){ int rr = t / F_, ff = t - rr*F_; xs[rr][ff] = x[(size_t)(r0+rr)*F_ + ff]; }
  __syncthreads();
  if(t < 4){
    float s = 0.f;
    #pragma unroll
    for(int f = 0; f < F_; f++) s += xs[t][f];
    maskb[r0 + t] = (s == 0.0f) ? NEGV : 0.0f;
  }
  float b = bias[t];
  float a0=b, a1=b, a2=b, a3=b;
  for(int k=0; k<F_; k++){
    float w = W[k*D_ + t];
    a0 = fmaf(xs[0][k], w, a0);
    a1 = fmaf(xs[1][k], w, a1);
    a2 = fmaf(xs[2][k], w, a2);
    a3 = fmaf(xs[3][k], w, a3);
  }
  a0 = fmaxf(a0, 0.f); a1 = fmaxf(a1, 0.f); a2 = fmaxf(a2, 0.f); a3 = fmaxf(a3, 0.f);
  h[(size_t)(r0+0)*D_ + t] = a0;  h_bf[(size_t)(r0+0)*D_ + t] = f2b(a0);
  h[(size_t)(r0+1)*D_ + t] = a1;  h_bf[(size_t)(r0+1)*D_ + t] = f2b(a1);
  h[(size_t)(r0+2)*D_ + t] = a2;  h_bf[(size_t)(r0+2)*D_ + t] = f2b(a2);
  h[(size_t)(r0+3)*D_ + t] = a3;  h_bf[(size_t)(r0+3)*D_ + t] = f2b(a3);
}

// =================== bf16 MFMA GEMM (final GEMM only) =======================
struct MG {
  const u16* A; const u16* W; const float* bias; void* C;
  int lda, K, ldc, aofs, cofs;
};
struct MG6 { MG g[6]; };

template<int TM, bool OUTBF, int ACT>
__global__ __launch_bounds__(256) void mgemm_kernel(MG6 args){
  const MG p = args.g[blockIdx.z];
  __shared__ u16 As[TM*32];
  __shared__ u16 Bs[128*32];
  const int t    = threadIdx.x;
  const int lane = t & 63;
  const int w    = t >> 6;
  const int ln   = lane & 15;
  const int qd   = lane >> 4;
  const int mw   = (w & 1) * (TM/2);
  const int nw   = (w >> 1) * 64;
  const int m0   = blockIdx.x * TM;
  const int n0   = blockIdx.y * 128;
  constexpr int MI = TM/32;
  f32x4 acc[MI][4];
  #pragma unroll
  for(int i=0;i<MI;i++)
    #pragma unroll
    for(int j=0;j<4;j++) acc[i][j] = (f32x4){0.f,0.f,0.f,0.f};

  const int srow = t >> 2;
  const int sc8  = (t & 3) * 8;

  for(int k0 = 0; k0 < p.K; k0 += 32){
    __syncthreads();
    glds16(p.A + (size_t)(m0 + srow)*p.lda + p.aofs + k0 + sc8, As + t*8);
    if(TM == 128)
      glds16(p.A + (size_t)(m0 + 64 + srow)*p.lda + p.aofs + k0 + sc8, As + (t+256)*8);
    glds16(p.W + (size_t)(n0 + srow)*p.K + k0 + sc8, Bs + t*8);
    glds16(p.W + (size_t)(n0 + 64 + srow)*p.K + k0 + sc8, Bs + (t+256)*8);
    __syncthreads();

    short8 a[MI], b[4];
    #pragma unroll
    for(int i=0;i<MI;i++) a[i] = *(const short8*)&As[(mw + i*16 + ln)*32 + qd*8];
    #pragma unroll
    for(int j=0;j<4;j++)  b[j] = *(const short8*)&Bs[(nw + j*16 + ln)*32 + qd*8];
    #pragma unroll
    for(int i=0;i<MI;i++)
      #pragma unroll
      for(int j=0;j<4;j++)
        acc[i][j] = __builtin_amdgcn_mfma_f32_16x16x32_bf16(a[i], b[j], acc[i][j], 0, 0, 0);
  }

  #pragma unroll
  for(int i=0;i<MI;i++){
    #pragma unroll
    for(int j=0;j<4;j++){
      int col = n0 + nw + j*16 + ln;
      float bv = p.bias[col];
      int rowb = m0 + mw + i*16 + qd*4;
      #pragma unroll
      for(int r=0;r<4;r++){
        float v = acc[i][j][r] + bv;
        if(ACT == 1) v = fmaxf(v, 0.f);
        if(ACT == 2) v = 0.5f*v*(1.0f + erff(v*0.70710678118654752f));
        size_t idx = (size_t)(rowb + r)*p.ldc + p.cofs + col;
        if(OUTBF) ((u16*)p.C)[idx] = f2b(v);
        else      ((float*)p.C)[idx] = v;
      }
    }
  }
}

// ====== fused QKV-projection + attention: block per (b, head, branch) =======
struct QAArgs { const u16 *wq, *wk, *wv; const float *bq, *bk, *bv; };

__global__ __launch_bounds__(256) void qkv_attn_kernel(
    const u16* __restrict__ h_bf,
    QAArgs a1, QAArgs a2,
    const float* __restrict__ adjm, const float* __restrict__ distr,
    const float* __restrict__ maskb,
    u16* __restrict__ o1, u16* __restrict__ o2)
{
  __shared__ u16 SH[21760];          // 42.5 KB
  u16* As = SH;                      // [128][32]  (phase1 staging)
  u16* Bs = SH + 4096;               // [96][32]   rows: 0-31 Wq, 32-63 Wk, 64-95 Wv
  u16* Qs = SH + 7168;               // [128][40]
  u16* Ks = SH + 12288;              // [128][40]
  u16* Vt = SH + 17408;              // [32][136]
  u16* Ps = SH;                      // [128][136] alias (phase2)

  const int bh = blockIdx.x;
  const int b  = bh >> 2;
  const int hh = bh & 3;
  const int branch = blockIdx.y;
  const QAArgs qa = branch ? a2 : a1;
  const u16* wqp = qa.wq + (size_t)hh*32*DH_;
  const u16* wkp = qa.wk + (size_t)hh*32*DH_;
  const u16* wvp = qa.wv + (size_t)hh*32*DH_;
  const int t = threadIdx.x;
  const int w = t >> 6, lane = t & 63;
  const int ln = lane & 15, qd = lane >> 4;
  const size_t rowbase = (size_t)b * S_;
  const int srow = t >> 2, sc8 = (t & 3) * 8;

  // ---------------- phase 1: QKV projection ----------------
  f32x4 acc[2][6];
  #pragma unroll
  for(int i=0;i<2;i++)
    #pragma unroll
    for(int j=0;j<6;j++) acc[i][j] = (f32x4){0.f,0.f,0.f,0.f};

  for(int k0 = 0; k0 < DH_; k0 += 32){
    __syncthreads();
    glds16(h_bf + (rowbase + srow)*D_ + branch*DH_ + k0 + sc8, As + t*8);
    glds16(h_bf + (rowbase + 64 + srow)*D_ + branch*DH_ + k0 + sc8, As + (t+256)*8);
    {
      int r = t >> 2;
      const u16* wp = (r < 32) ? wqp : wkp;
      glds16(wp + (size_t)(r & 31)*DH_ + k0 + sc8, Bs + t*8);
    }
    if(t < 128){
      int c = 256 + t;
      glds16(wvp + (size_t)((c>>2) - 64)*DH_ + k0 + (c&3)*8, Bs + c*8);
    }
    __syncthreads();
    short8 av[2];
    #pragma unroll
    for(int mt = 0; mt < 2; mt++)
      av[mt] = *(const short8*)&As[(w*32 + mt*16 + ln)*32 + qd*8];
    #pragma unroll
    for(int nt = 0; nt < 6; nt++){
      short8 bv = *(const short8*)&Bs[(nt*16 + ln)*32 + qd*8];
      #pragma unroll
      for(int mt = 0; mt < 2; mt++)
        acc[mt][nt] = __builtin_amdgcn_mfma_f32_16x16x32_bf16(av[mt], bv, acc[mt][nt], 0, 0, 0);
    }
  }

  {
    const float* bqp = qa.bq + hh*32;
    const float* bkp = qa.bk + hh*32;
    const float* bvp = qa.bv + hh*32;
    #pragma unroll
    for(int mt = 0; mt < 2; mt++){
      int rb = w*32 + mt*16 + qd*4;
      #pragma unroll
      for(int j = 0; j < 2; j++){
        int d = j*16 + ln;
        float bq_ = bqp[d], bk_ = bkp[d], bv_ = bvp[d];
        #pragma unroll
        for(int r = 0; r < 4; r++){
          Qs[(rb+r)*40 + d]   = f2b(acc[mt][j][r]   + bq_);
          Ks[(rb+r)*40 + d]   = f2b(acc[mt][2+j][r] + bk_);
          Vt[d*136 + rb + r]  = f2b(acc[mt][4+j][r] + bv_);
        }
      }
    }
  }
  __syncthreads();

  // ---------------- phase 2: attention ----------------
  const int mbase = w * 32;
  short8 qf[2];
  #pragma unroll
  for(int mt = 0; mt < 2; mt++)
    qf[mt] = *(const short8*)&Qs[(mbase + mt*16 + ln)*40 + qd*8];
  short8 kf[8];
  #pragma unroll
  for(int nt = 0; nt < 8; nt++)
    kf[nt] = *(const short8*)&Ks[(nt*16 + ln)*40 + qd*8];
  __syncthreads();

  f32x4 sc[2][8];
  #pragma unroll
  for(int mt = 0; mt < 2; mt++)
    #pragma unroll
    for(int nt = 0; nt < 8; nt++)
      sc[mt][nt] = __builtin_amdgcn_mfma_f32_16x16x32_bf16(
          qf[mt], kf[nt], (f32x4){0.f,0.f,0.f,0.f}, 0, 0, 0);

  float mskv[8];
  if(branch){
    #pragma unroll
    for(int nt = 0; nt < 8; nt++) mskv[nt] = maskb[rowbase + nt*16 + ln];
  }

  #pragma unroll
  for(int mt = 0; mt < 2; mt++){
    #pragma unroll
    for(int r = 0; r < 4; r++){
      int row = mbase + mt*16 + qd*4 + r;
      const float* arow = (branch ? distr : adjm) + (rowbase + row)*S_ + ln;
      #pragma unroll
      for(int nt = 0; nt < 8; nt++){
        float g = arow[nt*16];
        float v;
        if(branch == 0) v = sc[mt][nt][r]*SCALE_ + g;
        else            v = fmaxf(sc[mt][nt][r], 0.f)*g + mskv[nt];
        sc[mt][nt][r] = v;
      }
    }
  }

  #pragma unroll
  for(int mt = 0; mt < 2; mt++){
    #pragma unroll
    for(int r = 0; r < 4; r++){
      float m = -3.4e38f;
      #pragma unroll
      for(int nt = 0; nt < 8; nt++) m = fmaxf(m, sc[mt][nt][r]);
      m = fmaxf(m, __shfl_xor(m, 1));
      m = fmaxf(m, __shfl_xor(m, 2));
      m = fmaxf(m, __shfl_xor(m, 4));
      m = fmaxf(m, __shfl_xor(m, 8));
      float sum = 0.f;
      float e[8];
      #pragma unroll
      for(int nt = 0; nt < 8; nt++){ e[nt] = __expf(sc[mt][nt][r] - m); sum += e[nt]; }
      sum += __shfl_xor(sum, 1);
      sum += __shfl_xor(sum, 2);
      sum += __shfl_xor(sum, 4);
      sum += __shfl_xor(sum, 8);
      float inv = 1.0f / sum;
      int row = mbase + mt*16 + qd*4 + r;
      #pragma unroll
      for(int nt = 0; nt < 8; nt++) Ps[row*136 + nt*16 + ln] = f2b(e[nt] * inv);
    }
  }

  f32x4 oacc[2][2];
  #pragma unroll
  for(int mt = 0; mt < 2; mt++)
    #pragma unroll
    for(int n2 = 0; n2 < 2; n2++) oacc[mt][n2] = (f32x4){0.f,0.f,0.f,0.f};
  #pragma unroll
  for(int kk = 0; kk < 4; kk++){
    short8 pa[2], vb[2];
    #pragma unroll
    for(int mt = 0; mt < 2; mt++)
      pa[mt] = *(const short8*)&Ps[(mbase + mt*16 + ln)*136 + kk*32 + qd*8];
    #pragma unroll
    for(int n2 = 0; n2 < 2; n2++)
      vb[n2] = *(const short8*)&Vt[(n2*16 + ln)*136 + kk*32 + qd*8];
    #pragma unroll
    for(int mt = 0; mt < 2; mt++)
      #pragma unroll
      for(int n2 = 0; n2 < 2; n2++)
        oacc[mt][n2] = __builtin_amdgcn_mfma_f32_16x16x32_bf16(pa[mt], vb[n2], oacc[mt][n2], 0, 0, 0);
  }

  u16* Og = branch ? o2 : o1;
  #pragma unroll
  for(int mt = 0; mt < 2; mt++){
    #pragma unroll
    for(int n2 = 0; n2 < 2; n2++){
      #pragma unroll
      for(int r = 0; r < 4; r++){
        int row = mbase + mt*16 + qd*4 + r;
        int d   = n2*16 + ln;
        Og[(rowbase + row)*DH_ + hh*DEPTH_ + d] = f2b(oacc[mt][n2][r]);
      }
    }
  }
}

// ====== fused layer tail: oproj(both)+res+LN1 + FFN1+GELU + FFN2+res+LN2 ====
// 256 thr, 32 rows/block, grid 256. Wave w owns col-slice w*64 of the 256-wide
// tensors (and w*128 of the 512-wide FFN1 output). B-fragments read DIRECTLY
// from global (L2-resident weights) -> no staging barriers in K-loops.
// LN1 output kept in registers as LN2 residual; FFN intermediate in LDS.
struct TailArgs {
  const u16 *o1, *o2, *wo1, *wo2, *w1, *w2;
  const float *bo1, *bo2, *bf1, *bf2, *g1, *be1, *g2, *be2;
  float *h; u16 *h_bf;
};

__global__ __launch_bounds__(256) void tail_kernel(TailArgs p){
  __shared__ u16 X1[32*264];          // LN1 out bf16 [32][256+8pad]
  __shared__ u16 X2[32*520];          // gelu(ffn1) bf16 [32][512+8pad]
  __shared__ float redS[4][32], redQ[4][32];
  const int t = threadIdx.x;
  const int w = t >> 6, lane = t & 63;
  const int ln = lane & 15, qd = lane >> 4;
  const int m0 = blockIdx.x * 32;
  const int branch = w >> 1;
  const int c0 = w * 64;              // global col base (oproj out & ffn2 out)
  const int bc0 = (w & 1) * 64;       // col base within branch (oproj)

  // ---------------- phase A: out-projection ----------------
  const u16* Ao = branch ? p.o2 : p.o1;
  const u16* Wo = branch ? p.wo2 : p.wo1;
  const float* bo = branch ? p.bo2 : p.bo1;
  f32x4 y[2][4];
  #pragma unroll
  for(int mt=0;mt<2;mt++)
    #pragma unroll
    for(int nt=0;nt<4;nt++) y[mt][nt] = (f32x4){0.f,0.f,0.f,0.f};

  #pragma unroll
  for(int k0 = 0; k0 < DH_; k0 += 32){
    short8 af[2], bf[4];
    #pragma unroll
    for(int mt=0;mt<2;mt++)
      af[mt] = *(const short8*)(Ao + (size_t)(m0+mt*16+ln)*DH_ + k0 + qd*8);
    #pragma unroll
    for(int nt=0;nt<4;nt++)
      bf[nt] = *(const short8*)(Wo + (size_t)(bc0+nt*16+ln)*DH_ + k0 + qd*8);
    #pragma unroll
    for(int mt=0;mt<2;mt++)
      #pragma unroll
      for(int nt=0;nt<4;nt++)
        y[mt][nt] = __builtin_amdgcn_mfma_f32_16x16x32_bf16(af[mt], bf[nt], y[mt][nt], 0, 0, 0);
  }

  // bias + residual h, accumulate raw moments
  float sS[2][4] = {}, sQ[2][4] = {};
  #pragma unroll
  for(int mt=0;mt<2;mt++){
    #pragma unroll
    for(int nt=0;nt<4;nt++){
      int col = c0 + nt*16 + ln;
      float bv = bo[bc0 + nt*16 + ln];
      #pragma unroll
      for(int r=0;r<4;r++){
        float v = y[mt][nt][r] + bv + p.h[(size_t)(m0+mt*16+qd*4+r)*D_ + col];
        y[mt][nt][r] = v;
        sS[mt][r] += v;
        sQ[mt][r] += v*v;
      }
    }
  }
  #pragma unroll
  for(int mt=0;mt<2;mt++)
    #pragma unroll
    for(int r=0;r<4;r++){
      float a = sS[mt][r], b = sQ[mt][r];
      a += __shfl_xor(a,1); a += __shfl_xor(a,2); a += __shfl_xor(a,4); a += __shfl_xor(a,8);
      b += __shfl_xor(b,1); b += __shfl_xor(b,2); b += __shfl_xor(b,4); b += __shfl_xor(b,8);
      sS[mt][r] = a; sQ[mt][r] = b;
    }
  if(ln == 0){
    #pragma unroll
    for(int mt=0;mt<2;mt++)
      #pragma unroll
      for(int r=0;r<4;r++){
        int row = mt*16 + qd*4 + r;
        redS[w][row] = sS[mt][r];
        redQ[w][row] = sQ[mt][r];
      }
  }
  __syncthreads();
  float mu[2][4], iv[2][4];
  #pragma unroll
  for(int mt=0;mt<2;mt++)
    #pragma unroll
    for(int r=0;r<4;r++){
      int row = mt*16 + qd*4 + r;
      float s = redS[0][row] + redS[1][row] + redS[2][row] + redS[3][row];
      float q = redQ[0][row] + redQ[1][row] + redQ[2][row] + redQ[3][row];
      float m_ = s * (1.0f/D_);
      mu[mt][r] = m_;
      iv[mt][r] = rsqrtf(q*(1.0f/D_) - m_*m_ + 1e-6f);
    }
  // normalize -> y (kept as LN2 residual) and X1 (bf16 ffn1 input)
  #pragma unroll
  for(int mt=0;mt<2;mt++){
    #pragma unroll
    for(int nt=0;nt<4;nt++){
      int col = c0 + nt*16 + ln;
      float gg = p.g1[col], bb = p.be1[col];
      #pragma unroll
      for(int r=0;r<4;r++){
        float yy = (y[mt][nt][r] - mu[mt][r]) * iv[mt][r] * gg + bb;
        y[mt][nt][r] = yy;
        X1[(mt*16+qd*4+r)*264 + col] = f2b(yy);
      }
    }
  }
  __syncthreads();

  // ---------------- phase B: FFN1 + GELU ----------------
  {
    const int fc0 = w * 128;
    f32x4 f1[2][8];
    #pragma unroll
    for(int mt=0;mt<2;mt++)
      #pragma unroll
      for(int nt=0;nt<8;nt++) f1[mt][nt] = (f32x4){0.f,0.f,0.f,0.f};
    for(int k0 = 0; k0 < D_; k0 += 32){
      short8 a0 = *(const short8*)&X1[(ln)*264 + k0 + qd*8];
      short8 a1 = *(const short8*)&X1[(16+ln)*264 + k0 + qd*8];
      #pragma unroll
      for(int nt=0;nt<8;nt++){
        short8 bfr = *(const short8*)(p.w1 + (size_t)(fc0+nt*16+ln)*D_ + k0 + qd*8);
        f1[0][nt] = __builtin_amdgcn_mfma_f32_16x16x32_bf16(a0, bfr, f1[0][nt], 0, 0, 0);
        f1[1][nt] = __builtin_amdgcn_mfma_f32_16x16x32_bf16(a1, bfr, f1[1][nt], 0, 0, 0);
      }
    }
    #pragma unroll
    for(int mt=0;mt<2;mt++){
      #pragma unroll
      for(int nt=0;nt<8;nt++){
        int col = fc0 + nt*16 + ln;
        float bv = p.bf1[col];
        #pragma unroll
        for(int r=0;r<4;r++){
          float v = f1[mt][nt][r] + bv;
          v = 0.5f*v*(1.0f + erff(v*0.70710678118654752f));
          X2[(mt*16+qd*4+r)*520 + col] = f2b(v);
        }
      }
    }
  }
  __syncthreads();

  // ---------------- phase C: FFN2 + residual + LN2 ----------------
  f32x4 f2[2][4];
  #pragma unroll
  for(int mt=0;mt<2;mt++)
    #pragma unroll
    for(int nt=0;nt<4;nt++) f2[mt][nt] = (f32x4){0.f,0.f,0.f,0.f};
  for(int k0 = 0; k0 < DFF_; k0 += 32){
    short8 a0 = *(const short8*)&X2[(ln)*520 + k0 + qd*8];
    short8 a1 = *(const short8*)&X2[(16+ln)*520 + k0 + qd*8];
    #pragma unroll
    for(int nt=0;nt<4;nt++){
      short8 bfr = *(const short8*)(p.w2 + (size_t)(c0+nt*16+ln)*DFF_ + k0 + qd*8);
      f2[0][nt] = __builtin_amdgcn_mfma_f32_16x16x32_bf16(a0, bfr, f2[0][nt], 0, 0, 0);
      f2[1][nt] = __builtin_amdgcn_mfma_f32_16x16x32_bf16(a1, bfr, f2[1][nt], 0, 0, 0);
    }
  }
  float sS2[2][4] = {}, sQ2[2][4] = {};
  #pragma unroll
  for(int mt=0;mt<2;mt++){
    #pragma unroll
    for(int nt=0;nt<4;nt++){
      int col = c0 + nt*16 + ln;
      float bv = p.bf2[col];
      #pragma unroll
      for(int r=0;r<4;r++){
        float v = f2[mt][nt][r] + bv + y[mt][nt][r];   // residual = LN1 out (regs)
        f2[mt][nt][r] = v;
        sS2[mt][r] += v;
        sQ2[mt][r] += v*v;
      }
    }
  }
  #pragma unroll
  for(int mt=0;mt<2;mt++)
    #pragma unroll
    for(int r=0;r<4;r++){
      float a = sS2[mt][r], b = sQ2[mt][r];
      a += __shfl_xor(a,1); a += __shfl_xor(a,2); a += __shfl_xor(a,4); a += __shfl_xor(a,8);
      b += __shfl_xor(b,1); b += __shfl_xor(b,2); b += __shfl_xor(b,4); b += __shfl_xor(b,8);
      sS2[mt][r] = a; sQ2[mt][r] = b;
    }
  __syncthreads();   // all LN1 reads of redS/redQ long done; safe to reuse
  if(ln == 0){
    #pragma unroll
    for(int mt=0;mt<2;mt++)
      #pragma unroll
      for(int r=0;r<4;r++){
        int row = mt*16 + qd*4 + r;
        redS[w][row] = sS2[mt][r];
        redQ[w][row] = sQ2[mt][r];
      }
  }
  __syncthreads();
  #pragma unroll
  for(int mt=0;mt<2;mt++)
    #pragma unroll
    for(int r=0;r<4;r++){
      int row = mt*16 + qd*4 + r;
      float s = redS[0][row] + redS[1][row] + redS[2][row] + redS[3][row];
      float q = redQ[0][row] + redQ[1][row] + redQ[2][row] + redQ[3][row];
      float m_ = s * (1.0f/D_);
      mu[mt][r] = m_;
      iv[mt][r] = rsqrtf(q*(1.0f/D_) - m_*m_ + 1e-6f);
    }
  #pragma unroll
  for(int mt=0;mt<2;mt++){
    #pragma unroll
    for(int nt=0;nt<4;nt++){
      int col = c0 + nt*16 + ln;
      float gg = p.g2[col], bb = p.be2[col];
      #pragma unroll
      for(int r=0;r<4;r++){
        float yy = (f2[mt][nt][r] - mu[mt][r]) * iv[mt][r] * gg + bb;
        size_t idx = (size_t)(m0 + mt*16 + qd*4 + r)*D_ + col;
        p.h[idx] = yy;
        p.h_bf[idx] = f2b(yy);
      }
    }
  }
}

// ---------------- pooled[b,n,:] = (amm[b,n,:] @ h[b]) / sum_atoms -----------
__global__ __launch_bounds__(256) void pool_kernel(
    const float* __restrict__ amm, const float* __restrict__ sum_atoms,
    const float* __restrict__ h, u16* __restrict__ pooled_bf)
{
  __shared__ float as[S_];
  int bn = blockIdx.x;
  int b  = bn >> 5;
  int t  = threadIdx.x;
  if(t < S_) as[t] = amm[(size_t)bn*S_ + t];
  __syncthreads();
  float acc = 0.f;
  const float* hb = h + (size_t)b*S_*D_ + t;
  #pragma unroll 4
  for(int s = 0; s < S_; s++) acc = fmaf(as[s], hb[(size_t)s*D_], acc);
  pooled_bf[(size_t)bn*D_ + t] = f2b(acc / sum_atoms[bn]);
}

// ============================ host-side launcher ============================
extern "C" void kernel_launch(void* const* d_in, const int* in_sizes, int n_in,
                              void* d_out, int out_size, void* d_ws, size_t ws_size,
                              hipStream_t stream)
{
  const float* x     = (const float*)d_in[0];
  const float* adj   = (const float*)d_in[1];
  const float* dist  = (const float*)d_in[2];
  const float* amm   = (const float*)d_in[3];
  const float* sum_a = (const float*)d_in[4];
  const float* embW  = (const float*)d_in[5];
  const float* embB  = (const float*)d_in[6];
  const float* globW = (const float*)d_in[7];
  const float* globB = (const float*)d_in[8];
  const float* Wq1 = (const float*)d_in[9],  *Wk1 = (const float*)d_in[10],
             *Wv1 = (const float*)d_in[11], *Wo1 = (const float*)d_in[12],
             *Wq2 = (const float*)d_in[13], *Wk2 = (const float*)d_in[14],
             *Wv2 = (const float*)d_in[15], *Wo2 = (const float*)d_in[16];
  const float* bq1 = (const float*)d_in[17], *bk1 = (const float*)d_in[18],
             *bv1 = (const float*)d_in[19], *bo1 = (const float*)d_in[20],
             *bq2 = (const float*)d_in[21], *bk2 = (const float*)d_in[22],
             *bv2 = (const float*)d_in[23], *bo2 = (const float*)d_in[24];
  const float* Wf1 = (const float*)d_in[25], *bf1 = (const float*)d_in[26],
             *Wf2 = (const float*)d_in[27], *bf2 = (const float*)d_in[28],
             *g1  = (const float*)d_in[29], *be1 = (const float*)d_in[30],
             *g2  = (const float*)d_in[31], *be2 = (const float*)d_in[32];

  float* wsf = (float*)d_ws;
  float* h     = wsf; wsf += (size_t)MS_*D_;
  float* maskb = wsf; wsf += MS_;
  float* distr = wsf; wsf += (size_t)B_*S_*S_;
  float* adjm  = wsf; wsf += (size_t)B_*S_*S_;
  float* slab  = wsf; wsf += (size_t)MS_*DH_;     // 2 bf16 slots (o1,o2)
  // bf16 region
  u16* bb = (u16*)wsf;
  u16* h_bf    = bb; bb += (size_t)MS_*D_;
  u16* pooled_bf = bb; bb += (size_t)B_*NSUB_*D_;
  u16* globWt  = bb; bb += (size_t)D_*D_;
  u16* wq1t = bb; bb += (size_t)L_*DH_*DH_;
  u16* wk1t = bb; bb += (size_t)L_*DH_*DH_;
  u16* wv1t = bb; bb += (size_t)L_*DH_*DH_;
  u16* wo1t = bb; bb += (size_t)L_*DH_*DH_;
  u16* wq2t = bb; bb += (size_t)L_*DH_*DH_;
  u16* wk2t = bb; bb += (size_t)L_*DH_*DH_;
  u16* wv2t = bb; bb += (size_t)L_*DH_*DH_;
  u16* wo2t = bb; bb += (size_t)L_*DH_*DH_;
  u16* wf1t = bb; bb += (size_t)L_*D_*DFF_;       // [L][512][256]
  u16* wf2t = bb; bb += (size_t)L_*DFF_*D_;       // [L][256][512]
  u16* o1_bf = (u16*)slab;
  u16* o2_bf = o1_bf + (size_t)MS_*DH_;

  embed_kernel<<<MS_/4, 256, 0, stream>>>(x, embW, embB, h, h_bf, maskb);
  adjrescale_kernel<<<(B_*S_*S_)/256, 256, 0, stream>>>(adj, dist, maskb, adjm, distr);
  {
    TDs td;
    const float* S8[8] = {Wq1, Wk1, Wv1, Wo1, Wq2, Wk2, Wv2, Wo2};
    u16* D8[8] = {wq1t, wk1t, wv1t, wo1t, wq2t, wk2t, wv2t, wo2t};
    for(int i = 0; i < 8; i++) td.d[i] = {S8[i], D8[i], DH_, DH_, L_};
    td.d[8]  = {Wf1, wf1t, D_, DFF_, L_};
    td.d[9]  = {Wf2, wf2t, DFF_, D_, L_};
    td.d[10] = {globW, globWt, D_, D_, 1};
    transpose_all_kernel<<<dim3(16,16,11), dim3(32,8), 0, stream>>>(td);
  }

  for(int l = 0; l < L_; l++){
    QAArgs a1 = { wq1t + (size_t)l*DH_*DH_, wk1t + (size_t)l*DH_*DH_, wv1t + (size_t)l*DH_*DH_,
                  bq1 + (size_t)l*DH_, bk1 + (size_t)l*DH_, bv1 + (size_t)l*DH_ };
    QAArgs a2 = { wq2t + (size_t)l*DH_*DH_, wk2t + (size_t)l*DH_*DH_, wv2t + (size_t)l*DH_*DH_,
                  bq2 + (size_t)l*DH_, bk2 + (size_t)l*DH_, bv2 + (size_t)l*DH_ };
    qkv_attn_kernel<<<dim3(B_*H_, 2), 256, 0, stream>>>(h_bf, a1, a2, adjm, distr, maskb,
                                                        o1_bf, o2_bf);
    TailArgs ta;
    ta.o1 = o1_bf; ta.o2 = o2_bf;
    ta.wo1 = wo1t + (size_t)l*DH_*DH_; ta.wo2 = wo2t + (size_t)l*DH_*DH_;
    ta.w1 = wf1t + (size_t)l*D_*DFF_;  ta.w2 = wf2t + (size_t)l*DFF_*D_;
    ta.bo1 = bo1 + (size_t)l*DH_; ta.bo2 = bo2 + (size_t)l*DH_;
    ta.bf1 = bf1 + (size_t)l*DFF_; ta.bf2 = bf2 + (size_t)l*D_;
    ta.g1 = g1 + (size_t)l*D_; ta.be1 = be1 + (size_t)l*D_;
    ta.g2 = g2 + (size_t)l*D_; ta.be2 = be2 + (size_t)l*D_;
    ta.h = h; ta.h_bf = h_bf;
    tail_kernel<<<MS_/32, 256, 0, stream>>>(ta);
  }

  pool_kernel<<<B_*NSUB_, 256, 0, stream>>>(amm, sum_a, h, pooled_bf);
  // final: relu(pooled @ glob_W + glob_b), M=2048 N=256 K=256
  {
    MG6 a;
    a.g[0].A = pooled_bf; a.g[0].W = globWt;
    a.g[0].bias = globB; a.g[0].C = (float*)d_out;
    a.g[0].lda = D_; a.g[0].K = D_; a.g[0].ldc = D_;
    a.g[0].aofs = 0; a.g[0].cofs = 0;
    mgemm_kernel<64,false,1><<<dim3((B_*NSUB_)/64, D_/128, 1), 256, 0, stream>>>(a);
  }
}

// Round 7
// 449.766 us; speedup vs baseline: 2.6092x; 1.0077x over previous
//
#include <hip/hip_runtime.h>
#include <math.h>

#define B_ 64
#define S_ 128
#define F_ 62
#define D_ 256
#define H_ 4
#define L_ 6
#define NSUB_ 32
#define DFF_ 512
#define DH_ 128
#define DEPTH_ 32
#define MS_ (B_*S_)                 // 8192 rows
#define NEGV (-1000000000.0f)
#define SCALE_ 0.17677669529663687f // 1/sqrt(32)

typedef unsigned short u16;
typedef __attribute__((ext_vector_type(8))) short short8;
typedef __attribute__((ext_vector_type(4))) float f32x4;

// f32 -> bf16 round-to-nearest-even
__device__ __forceinline__ u16 f2b(float f){
  unsigned u = __float_as_uint(f);
  unsigned r = (u + 0x7fffu + ((u >> 16) & 1u)) >> 16;
  return (u16)r;
}

__device__ __forceinline__ void glds16(const void* g, void* l){
  __builtin_amdgcn_global_load_lds(
      (const __attribute__((address_space(1))) unsigned int*)g,
      (__attribute__((address_space(3))) unsigned int*)l, 16, 0, 0);
}

// ------- adjm = adj + mask; distr = rescale(dist)*scale (one pass) ----------
__global__ __launch_bounds__(256) void adjrescale_kernel(
    const float* __restrict__ adj, const float* __restrict__ dist,
    const float* __restrict__ maskb,
    float* __restrict__ adjm, float* __restrict__ distr){
  size_t i = (size_t)blockIdx.x*256 + threadIdx.x;
  int j = (int)(i & (S_-1));
  int b = (int)(i >> 14);            // S_*S_ = 16384
  const float e1 = 2.718281828459045f;
  distr[i] = (1.0f + e1) / (1.0f + expf(1.0f - dist[i])) * SCALE_;
  adjm[i]  = adj[i] + maskb[b*S_ + j];
}

// ------ all weight transposes in ONE dispatch: dst[l][n][k] = src[l][k][n] --
struct TD { const float* src; u16* dst; int K, N, L; };
struct TDs { TD d[11]; };
__global__ __launch_bounds__(256) void transpose_all_kernel(TDs a){
  const TD p = a.d[blockIdx.z];
  int n0 = blockIdx.x*32, k0 = blockIdx.y*32;
  if(n0 >= p.N || k0 >= p.K) return;
  __shared__ float tbuf[32][33];
  int tx = threadIdx.x, ty = threadIdx.y;   // 32 x 8
  for(int l = 0; l < p.L; l++){
    const float* src = p.src + (size_t)l*p.K*p.N;
    u16* dst = p.dst + (size_t)l*p.K*p.N;
    #pragma unroll
    for(int i = 0; i < 4; i++)
      tbuf[ty + i*8][tx] = src[(size_t)(k0 + ty + i*8)*p.N + n0 + tx];
    __syncthreads();
    #pragma unroll
    for(int i = 0; i < 4; i++)
      dst[(size_t)(n0 + ty + i*8)*p.K + k0 + tx] = f2b(tbuf[tx][ty + i*8]);
    __syncthreads();
  }
}

// --------- embed: h = relu(x @ emb_W + emb_b), K=62; also emits maskb -------
__global__ __launch_bounds__(256) void embed_kernel(const float* __restrict__ x,
    const float* __restrict__ W, const float* __restrict__ bias,
    float* __restrict__ h, u16* __restrict__ h_bf, float* __restrict__ maskb){
  __shared__ float xs[4][F_];
  int r0 = blockIdx.x*4;
  int t = threadIdx.x;
  if(t < 4*F_){ int rr = t / F_, ff = t - rr*F_; xs[rr][ff] = x[(size_t)(r0+rr)*F_ + ff]; }
  __syncthreads();
  if(t < 4){
    float s = 0.f;
    #pragma unroll
    for(int f = 0; f < F_; f++) s += xs[t][f];
    maskb[r0 + t] = (s == 0.0f) ? NEGV : 0.0f;
  }
  float b = bias[t];
  float a0=b, a1=b, a2=b, a3=b;
  for(int k=0; k<F_; k++){
    float w = W[k*D_ + t];
    a0 = fmaf(xs[0][k], w, a0);
    a1 = fmaf(xs[1][k], w, a1);
    a2 = fmaf(xs[2][k], w, a2);
    a3 = fmaf(xs[3][k], w, a3);
  }
  a0 = fmaxf(a0, 0.f); a1 = fmaxf(a1, 0.f); a2 = fmaxf(a2, 0.f); a3 = fmaxf(a3, 0.f);
  h[(size_t)(r0+0)*D_ + t] = a0;  h_bf[(size_t)(r0+0)*D_ + t] = f2b(a0);
  h[(size_t)(r0+1)*D_ + t] = a1;  h_bf[(size_t)(r0+1)*D_ + t] = f2b(a1);
  h[(size_t)(r0+2)*D_ + t] = a2;  h_bf[(size_t)(r0+2)*D_ + t] = f2b(a2);
  h[(size_t)(r0+3)*D_ + t] = a3;  h_bf[(size_t)(r0+3)*D_ + t] = f2b(a3);
}

// =================== bf16 MFMA GEMM (final GEMM only) =======================
struct MG {
  const u16* A; const u16* W; const float* bias; void* C;
  int lda, K, ldc, aofs, cofs;
};
struct MG6 { MG g[6]; };

template<int TM, bool OUTBF, int ACT>
__global__ __launch_bounds__(256) void mgemm_kernel(MG6 args){
  const MG p = args.g[blockIdx.z];
  __shared__ u16 As[TM*32];
  __shared__ u16 Bs[128*32];
  const int t    = threadIdx.x;
  const int lane = t & 63;
  const int w    = t >> 6;
  const int ln   = lane & 15;
  const int qd   = lane >> 4;
  const int mw   = (w & 1) * (TM/2);
  const int nw   = (w >> 1) * 64;
  const int m0   = blockIdx.x * TM;
  const int n0   = blockIdx.y * 128;
  constexpr int MI = TM/32;
  f32x4 acc[MI][4];
  #pragma unroll
  for(int i=0;i<MI;i++)
    #pragma unroll
    for(int j=0;j<4;j++) acc[i][j] = (f32x4){0.f,0.f,0.f,0.f};

  const int srow = t >> 2;
  const int sc8  = (t & 3) * 8;

  for(int k0 = 0; k0 < p.K; k0 += 32){
    __syncthreads();
    glds16(p.A + (size_t)(m0 + srow)*p.lda + p.aofs + k0 + sc8, As + t*8);
    if(TM == 128)
      glds16(p.A + (size_t)(m0 + 64 + srow)*p.lda + p.aofs + k0 + sc8, As + (t+256)*8);
    glds16(p.W + (size_t)(n0 + srow)*p.K + k0 + sc8, Bs + t*8);
    glds16(p.W + (size_t)(n0 + 64 + srow)*p.K + k0 + sc8, Bs + (t+256)*8);
    __syncthreads();

    short8 a[MI], b[4];
    #pragma unroll
    for(int i=0;i<MI;i++) a[i] = *(const short8*)&As[(mw + i*16 + ln)*32 + qd*8];
    #pragma unroll
    for(int j=0;j<4;j++)  b[j] = *(const short8*)&Bs[(nw + j*16 + ln)*32 + qd*8];
    #pragma unroll
    for(int i=0;i<MI;i++)
      #pragma unroll
      for(int j=0;j<4;j++)
        acc[i][j] = __builtin_amdgcn_mfma_f32_16x16x32_bf16(a[i], b[j], acc[i][j], 0, 0, 0);
  }

  #pragma unroll
  for(int i=0;i<MI;i++){
    #pragma unroll
    for(int j=0;j<4;j++){
      int col = n0 + nw + j*16 + ln;
      float bv = p.bias[col];
      int rowb = m0 + mw + i*16 + qd*4;
      #pragma unroll
      for(int r=0;r<4;r++){
        float v = acc[i][j][r] + bv;
        if(ACT == 1) v = fmaxf(v, 0.f);
        if(ACT == 2) v = 0.5f*v*(1.0f + erff(v*0.70710678118654752f));
        size_t idx = (size_t)(rowb + r)*p.ldc + p.cofs + col;
        if(OUTBF) ((u16*)p.C)[idx] = f2b(v);
        else      ((float*)p.C)[idx] = v;
      }
    }
  }
}

// ====== fused QKV-projection + attention: block per (b, head, branch) =======
struct QAArgs { const u16 *wq, *wk, *wv; const float *bq, *bk, *bv; };

__global__ __launch_bounds__(256) void qkv_attn_kernel(
    const u16* __restrict__ h_bf,
    QAArgs a1, QAArgs a2,
    const float* __restrict__ adjm, const float* __restrict__ distr,
    const float* __restrict__ maskb,
    u16* __restrict__ o1, u16* __restrict__ o2)
{
  __shared__ u16 SH[21760];          // 42.5 KB
  u16* As = SH;                      // [128][32]  (phase1 staging)
  u16* Bs = SH + 4096;               // [96][32]   rows: 0-31 Wq, 32-63 Wk, 64-95 Wv
  u16* Qs = SH + 7168;               // [128][40]
  u16* Ks = SH + 12288;              // [128][40]
  u16* Vt = SH + 17408;              // [32][136]
  u16* Ps = SH;                      // [128][136] alias (phase2)

  const int bh = blockIdx.x;
  const int b  = bh >> 2;
  const int hh = bh & 3;
  const int branch = blockIdx.y;
  const QAArgs qa = branch ? a2 : a1;
  const u16* wqp = qa.wq + (size_t)hh*32*DH_;
  const u16* wkp = qa.wk + (size_t)hh*32*DH_;
  const u16* wvp = qa.wv + (size_t)hh*32*DH_;
  const int t = threadIdx.x;
  const int w = t >> 6, lane = t & 63;
  const int ln = lane & 15, qd = lane >> 4;
  const size_t rowbase = (size_t)b * S_;
  const int srow = t >> 2, sc8 = (t & 3) * 8;
  const int mbase = w * 32;

  // ---- PREFETCH score-fixup operands (no deps -> issue before phase 1,
  //      hides ~64 global loads behind the projection MFMAs) ----
  float fix[2][4][8];
  {
    const float* basep = (branch ? distr : adjm) + rowbase*S_;
    #pragma unroll
    for(int mt = 0; mt < 2; mt++)
      #pragma unroll
      for(int r = 0; r < 4; r++){
        int row = mbase + mt*16 + qd*4 + r;
        #pragma unroll
        for(int nt = 0; nt < 8; nt++)
          fix[mt][r][nt] = basep[(size_t)row*S_ + nt*16 + ln];
      }
  }
  float mskv[8];
  if(branch){
    #pragma unroll
    for(int nt = 0; nt < 8; nt++) mskv[nt] = maskb[rowbase + nt*16 + ln];
  }

  // ---------------- phase 1: QKV projection ----------------
  f32x4 acc[2][6];
  #pragma unroll
  for(int i=0;i<2;i++)
    #pragma unroll
    for(int j=0;j<6;j++) acc[i][j] = (f32x4){0.f,0.f,0.f,0.f};

  for(int k0 = 0; k0 < DH_; k0 += 32){
    __syncthreads();
    glds16(h_bf + (rowbase + srow)*D_ + branch*DH_ + k0 + sc8, As + t*8);
    glds16(h_bf + (rowbase + 64 + srow)*D_ + branch*DH_ + k0 + sc8, As + (t+256)*8);
    {
      int r = t >> 2;
      const u16* wp = (r < 32) ? wqp : wkp;
      glds16(wp + (size_t)(r & 31)*DH_ + k0 + sc8, Bs + t*8);
    }
    if(t < 128){
      int c = 256 + t;
      glds16(wvp + (size_t)((c>>2) - 64)*DH_ + k0 + (c&3)*8, Bs + c*8);
    }
    __syncthreads();
    short8 av[2];
    #pragma unroll
    for(int mt = 0; mt < 2; mt++)
      av[mt] = *(const short8*)&As[(w*32 + mt*16 + ln)*32 + qd*8];
    #pragma unroll
    for(int nt = 0; nt < 6; nt++){
      short8 bv = *(const short8*)&Bs[(nt*16 + ln)*32 + qd*8];
      #pragma unroll
      for(int mt = 0; mt < 2; mt++)
        acc[mt][nt] = __builtin_amdgcn_mfma_f32_16x16x32_bf16(av[mt], bv, acc[mt][nt], 0, 0, 0);
    }
  }

  {
    const float* bqp = qa.bq + hh*32;
    const float* bkp = qa.bk + hh*32;
    const float* bvp = qa.bv + hh*32;
    #pragma unroll
    for(int mt = 0; mt < 2; mt++){
      int rb = w*32 + mt*16 + qd*4;
      #pragma unroll
      for(int j = 0; j < 2; j++){
        int d = j*16 + ln;
        float bq_ = bqp[d], bk_ = bkp[d], bv_ = bvp[d];
        #pragma unroll
        for(int r = 0; r < 4; r++){
          Qs[(rb+r)*40 + d]   = f2b(acc[mt][j][r]   + bq_);
          Ks[(rb+r)*40 + d]   = f2b(acc[mt][2+j][r] + bk_);
          Vt[d*136 + rb + r]  = f2b(acc[mt][4+j][r] + bv_);
        }
      }
    }
  }
  __syncthreads();

  // ---------------- phase 2: attention ----------------
  short8 qf[2];
  #pragma unroll
  for(int mt = 0; mt < 2; mt++)
    qf[mt] = *(const short8*)&Qs[(mbase + mt*16 + ln)*40 + qd*8];
  short8 kf[8];
  #pragma unroll
  for(int nt = 0; nt < 8; nt++)
    kf[nt] = *(const short8*)&Ks[(nt*16 + ln)*40 + qd*8];
  __syncthreads();

  f32x4 sc[2][8];
  #pragma unroll
  for(int mt = 0; mt < 2; mt++)
    #pragma unroll
    for(int nt = 0; nt < 8; nt++)
      sc[mt][nt] = __builtin_amdgcn_mfma_f32_16x16x32_bf16(
          qf[mt], kf[nt], (f32x4){0.f,0.f,0.f,0.f}, 0, 0, 0);

  #pragma unroll
  for(int mt = 0; mt < 2; mt++){
    #pragma unroll
    for(int r = 0; r < 4; r++){
      #pragma unroll
      for(int nt = 0; nt < 8; nt++){
        float g = fix[mt][r][nt];
        float v;
        if(branch == 0) v = sc[mt][nt][r]*SCALE_ + g;      // adjm has mask folded
        else            v = fmaxf(sc[mt][nt][r], 0.f)*g + mskv[nt];
        sc[mt][nt][r] = v;
      }
    }
  }

  #pragma unroll
  for(int mt = 0; mt < 2; mt++){
    #pragma unroll
    for(int r = 0; r < 4; r++){
      float m = -3.4e38f;
      #pragma unroll
      for(int nt = 0; nt < 8; nt++) m = fmaxf(m, sc[mt][nt][r]);
      m = fmaxf(m, __shfl_xor(m, 1));
      m = fmaxf(m, __shfl_xor(m, 2));
      m = fmaxf(m, __shfl_xor(m, 4));
      m = fmaxf(m, __shfl_xor(m, 8));
      float sum = 0.f;
      float e[8];
      #pragma unroll
      for(int nt = 0; nt < 8; nt++){ e[nt] = __expf(sc[mt][nt][r] - m); sum += e[nt]; }
      sum += __shfl_xor(sum, 1);
      sum += __shfl_xor(sum, 2);
      sum += __shfl_xor(sum, 4);
      sum += __shfl_xor(sum, 8);
      float inv = 1.0f / sum;
      int row = mbase + mt*16 + qd*4 + r;
      #pragma unroll
      for(int nt = 0; nt < 8; nt++) Ps[row*136 + nt*16 + ln] = f2b(e[nt] * inv);
    }
  }
  // no barrier: each wave reads only its own P rows

  f32x4 oacc[2][2];
  #pragma unroll
  for(int mt = 0; mt < 2; mt++)
    #pragma unroll
    for(int n2 = 0; n2 < 2; n2++) oacc[mt][n2] = (f32x4){0.f,0.f,0.f,0.f};
  #pragma unroll
  for(int kk = 0; kk < 4; kk++){
    short8 pa[2], vb[2];
    #pragma unroll
    for(int mt = 0; mt < 2; mt++)
      pa[mt] = *(const short8*)&Ps[(mbase + mt*16 + ln)*136 + kk*32 + qd*8];
    #pragma unroll
    for(int n2 = 0; n2 < 2; n2++)
      vb[n2] = *(const short8*)&Vt[(n2*16 + ln)*136 + kk*32 + qd*8];
    #pragma unroll
    for(int mt = 0; mt < 2; mt++)
      #pragma unroll
      for(int n2 = 0; n2 < 2; n2++)
        oacc[mt][n2] = __builtin_amdgcn_mfma_f32_16x16x32_bf16(pa[mt], vb[n2], oacc[mt][n2], 0, 0, 0);
  }

  u16* Og = branch ? o2 : o1;
  #pragma unroll
  for(int mt = 0; mt < 2; mt++){
    #pragma unroll
    for(int n2 = 0; n2 < 2; n2++){
      #pragma unroll
      for(int r = 0; r < 4; r++){
        int row = mbase + mt*16 + qd*4 + r;
        int d   = n2*16 + ln;
        Og[(rowbase + row)*DH_ + hh*DEPTH_ + d] = f2b(oacc[mt][n2][r]);
      }
    }
  }
}

// ====== fused layer tail: oproj(both)+res+LN1 + FFN1+GELU + FFN2+res+LN2 ====
// 512 thr (8 waves = 2/SIMD for latency hiding), 32 rows/block, grid 256.
// Wave w owns a 32-col slice (64-col for FFN1). B-frags direct from global.
struct TailArgs {
  const u16 *o1, *o2, *wo1, *wo2, *w1, *w2;
  const float *bo1, *bo2, *bf1, *bf2, *g1, *be1, *g2, *be2;
  float *h; u16 *h_bf;
};

__global__ __launch_bounds__(512) void tail_kernel(TailArgs p){
  __shared__ u16 X1[32*264];          // LN1 out bf16 [32][256+8pad]
  __shared__ u16 X2[32*520];          // gelu(ffn1) bf16 [32][512+8pad]
  __shared__ float redS[8][32], redQ[8][32];
  const int t = threadIdx.x;          // 0..511
  const int w = t >> 6, lane = t & 63;
  const int ln = lane & 15, qd = lane >> 4;
  const int m0 = blockIdx.x * 32;
  const int branch = w >> 2;          // waves 0-3: branch0 (cols 0-127), 4-7: branch1
  const int c0 = w * 32;              // global col base (oproj out & ffn2 out)
  const int bc0 = (w & 3) * 32;       // col base within branch

  // ---------------- phase A: out-projection ----------------
  const u16* Ao = branch ? p.o2 : p.o1;
  const u16* Wo = branch ? p.wo2 : p.wo1;
  const float* bo = branch ? p.bo2 : p.bo1;
  f32x4 y[2][2];
  #pragma unroll
  for(int mt=0;mt<2;mt++)
    #pragma unroll
    for(int nt=0;nt<2;nt++) y[mt][nt] = (f32x4){0.f,0.f,0.f,0.f};

  #pragma unroll
  for(int k0 = 0; k0 < DH_; k0 += 32){
    short8 af[2], bf[2];
    #pragma unroll
    for(int mt=0;mt<2;mt++)
      af[mt] = *(const short8*)(Ao + (size_t)(m0+mt*16+ln)*DH_ + k0 + qd*8);
    #pragma unroll
    for(int nt=0;nt<2;nt++)
      bf[nt] = *(const short8*)(Wo + (size_t)(bc0+nt*16+ln)*DH_ + k0 + qd*8);
    #pragma unroll
    for(int mt=0;mt<2;mt++)
      #pragma unroll
      for(int nt=0;nt<2;nt++)
        y[mt][nt] = __builtin_amdgcn_mfma_f32_16x16x32_bf16(af[mt], bf[nt], y[mt][nt], 0, 0, 0);
  }

  // bias + residual h, accumulate raw moments
  float sS[2][4] = {}, sQ[2][4] = {};
  #pragma unroll
  for(int mt=0;mt<2;mt++){
    #pragma unroll
    for(int nt=0;nt<2;nt++){
      int col = c0 + nt*16 + ln;
      float bv = bo[bc0 + nt*16 + ln];
      #pragma unroll
      for(int r=0;r<4;r++){
        float v = y[mt][nt][r] + bv + p.h[(size_t)(m0+mt*16+qd*4+r)*D_ + col];
        y[mt][nt][r] = v;
        sS[mt][r] += v;
        sQ[mt][r] += v*v;
      }
    }
  }
  #pragma unroll
  for(int mt=0;mt<2;mt++)
    #pragma unroll
    for(int r=0;r<4;r++){
      float a = sS[mt][r], b = sQ[mt][r];
      a += __shfl_xor(a,1); a += __shfl_xor(a,2); a += __shfl_xor(a,4); a += __shfl_xor(a,8);
      b += __shfl_xor(b,1); b += __shfl_xor(b,2); b += __shfl_xor(b,4); b += __shfl_xor(b,8);
      sS[mt][r] = a; sQ[mt][r] = b;
    }
  if(ln == 0){
    #pragma unroll
    for(int mt=0;mt<2;mt++)
      #pragma unroll
      for(int r=0;r<4;r++){
        int row = mt*16 + qd*4 + r;
        redS[w][row] = sS[mt][r];
        redQ[w][row] = sQ[mt][r];
      }
  }
  __syncthreads();
  float mu[2][4], iv[2][4];
  #pragma unroll
  for(int mt=0;mt<2;mt++)
    #pragma unroll
    for(int r=0;r<4;r++){
      int row = mt*16 + qd*4 + r;
      float s = 0.f, q = 0.f;
      #pragma unroll
      for(int ww=0;ww<8;ww++){ s += redS[ww][row]; q += redQ[ww][row]; }
      float m_ = s * (1.0f/D_);
      mu[mt][r] = m_;
      iv[mt][r] = rsqrtf(q*(1.0f/D_) - m_*m_ + 1e-6f);
    }
  // normalize -> y (kept as LN2 residual) and X1 (bf16 ffn1 input)
  #pragma unroll
  for(int mt=0;mt<2;mt++){
    #pragma unroll
    for(int nt=0;nt<2;nt++){
      int col = c0 + nt*16 + ln;
      float gg = p.g1[col], bb = p.be1[col];
      #pragma unroll
      for(int r=0;r<4;r++){
        float yy = (y[mt][nt][r] - mu[mt][r]) * iv[mt][r] * gg + bb;
        y[mt][nt][r] = yy;
        X1[(mt*16+qd*4+r)*264 + col] = f2b(yy);
      }
    }
  }
  __syncthreads();

  // ---------------- phase B: FFN1 + GELU (wave owns 64 cols) ----------------
  {
    const int fc0 = w * 64;
    f32x4 f1[2][4];
    #pragma unroll
    for(int mt=0;mt<2;mt++)
      #pragma unroll
      for(int nt=0;nt<4;nt++) f1[mt][nt] = (f32x4){0.f,0.f,0.f,0.f};
    for(int k0 = 0; k0 < D_; k0 += 32){
      short8 a0 = *(const short8*)&X1[(ln)*264 + k0 + qd*8];
      short8 a1 = *(const short8*)&X1[(16+ln)*264 + k0 + qd*8];
      #pragma unroll
      for(int nt=0;nt<4;nt++){
        short8 bfr = *(const short8*)(p.w1 + (size_t)(fc0+nt*16+ln)*D_ + k0 + qd*8);
        f1[0][nt] = __builtin_amdgcn_mfma_f32_16x16x32_bf16(a0, bfr, f1[0][nt], 0, 0, 0);
        f1[1][nt] = __builtin_amdgcn_mfma_f32_16x16x32_bf16(a1, bfr, f1[1][nt], 0, 0, 0);
      }
    }
    #pragma unroll
    for(int mt=0;mt<2;mt++){
      #pragma unroll
      for(int nt=0;nt<4;nt++){
        int col = fc0 + nt*16 + ln;
        float bv = p.bf1[col];
        #pragma unroll
        for(int r=0;r<4;r++){
          float v = f1[mt][nt][r] + bv;
          v = 0.5f*v*(1.0f + erff(v*0.70710678118654752f));
          X2[(mt*16+qd*4+r)*520 + col] = f2b(v);
        }
      }
    }
  }
  __syncthreads();

  // ---------------- phase C: FFN2 + residual + LN2 (wave owns 32 cols) ------
  f32x4 f2[2][2];
  #pragma unroll
  for(int mt=0;mt<2;mt++)
    #pragma unroll
    for(int nt=0;nt<2;nt++) f2[mt][nt] = (f32x4){0.f,0.f,0.f,0.f};
  for(int k0 = 0; k0 < DFF_; k0 += 32){
    short8 a0 = *(const short8*)&X2[(ln)*520 + k0 + qd*8];
    short8 a1 = *(const short8*)&X2[(16+ln)*520 + k0 + qd*8];
    #pragma unroll
    for(int nt=0;nt<2;nt++){
      short8 bfr = *(const short8*)(p.w2 + (size_t)(c0+nt*16+ln)*DFF_ + k0 + qd*8);
      f2[0][nt] = __builtin_amdgcn_mfma_f32_16x16x32_bf16(a0, bfr, f2[0][nt], 0, 0, 0);
      f2[1][nt] = __builtin_amdgcn_mfma_f32_16x16x32_bf16(a1, bfr, f2[1][nt], 0, 0, 0);
    }
  }
  float sS2[2][4] = {}, sQ2[2][4] = {};
  #pragma unroll
  for(int mt=0;mt<2;mt++){
    #pragma unroll
    for(int nt=0;nt<2;nt++){
      int col = c0 + nt*16 + ln;
      float bv = p.bf2[col];
      #pragma unroll
      for(int r=0;r<4;r++){
        float v = f2[mt][nt][r] + bv + y[mt][nt][r];   // residual = LN1 out (regs)
        f2[mt][nt][r] = v;
        sS2[mt][r] += v;
        sQ2[mt][r] += v*v;
      }
    }
  }
  #pragma unroll
  for(int mt=0;mt<2;mt++)
    #pragma unroll
    for(int r=0;r<4;r++){
      float a = sS2[mt][r], b = sQ2[mt][r];
      a += __shfl_xor(a,1); a += __shfl_xor(a,2); a += __shfl_xor(a,4); a += __shfl_xor(a,8);
      b += __shfl_xor(b,1); b += __shfl_xor(b,2); b += __shfl_xor(b,4); b += __shfl_xor(b,8);
      sS2[mt][r] = a; sQ2[mt][r] = b;
    }
  if(ln == 0){
    #pragma unroll
    for(int mt=0;mt<2;mt++)
      #pragma unroll
      for(int r=0;r<4;r++){
        int row = mt*16 + qd*4 + r;
        redS[w][row] = sS2[mt][r];
        redQ[w][row] = sQ2[mt][r];
      }
  }
  __syncthreads();
  #pragma unroll
  for(int mt=0;mt<2;mt++)
    #pragma unroll
    for(int r=0;r<4;r++){
      int row = mt*16 + qd*4 + r;
      float s = 0.f, q = 0.f;
      #pragma unroll
      for(int ww=0;ww<8;ww++){ s += redS[ww][row]; q += redQ[ww][row]; }
      float m_ = s * (1.0f/D_);
      mu[mt][r] = m_;
      iv[mt][r] = rsqrtf(q*(1.0f/D_) - m_*m_ + 1e-6f);
    }
  #pragma unroll
  for(int mt=0;mt<2;mt++){
    #pragma unroll
    for(int nt=0;nt<2;nt++){
      int col = c0 + nt*16 + ln;
      float gg = p.g2[col], bb = p.be2[col];
      #pragma unroll
      for(int r=0;r<4;r++){
        float yy = (f2[mt][nt][r] - mu[mt][r]) * iv[mt][r] * gg + bb;
        size_t idx = (size_t)(m0 + mt*16 + qd*4 + r)*D_ + col;
        p.h[idx] = yy;
        p.h_bf[idx] = f2b(yy);
      }
    }
  }
}

// ---------------- pooled[b,n,:] = (amm[b,n,:] @ h[b]) / sum_atoms -----------
__global__ __launch_bounds__(256) void pool_kernel(
    const float* __restrict__ amm, const float* __restrict__ sum_atoms,
    const float* __restrict__ h, u16* __restrict__ pooled_bf)
{
  __shared__ float as[S_];
  int bn = blockIdx.x;
  int b  = bn >> 5;
  int t  = threadIdx.x;
  if(t < S_) as[t] = amm[(size_t)bn*S_ + t];
  __syncthreads();
  float acc = 0.f;
  const float* hb = h + (size_t)b*S_*D_ + t;
  #pragma unroll 4
  for(int s = 0; s < S_; s++) acc = fmaf(as[s], hb[(size_t)s*D_], acc);
  pooled_bf[(size_t)bn*D_ + t] = f2b(acc / sum_atoms[bn]);
}

// ============================ host-side launcher ============================
extern "C" void kernel_launch(void* const* d_in, const int* in_sizes, int n_in,
                              void* d_out, int out_size, void* d_ws, size_t ws_size,
                              hipStream_t stream)
{
  const float* x     = (const float*)d_in[0];
  const float* adj   = (const float*)d_in[1];
  const float* dist  = (const float*)d_in[2];
  const float* amm   = (const float*)d_in[3];
  const float* sum_a = (const float*)d_in[4];
  const float* embW  = (const float*)d_in[5];
  const float* embB  = (const float*)d_in[6];
  const float* globW = (const float*)d_in[7];
  const float* globB = (const float*)d_in[8];
  const float* Wq1 = (const float*)d_in[9],  *Wk1 = (const float*)d_in[10],
             *Wv1 = (const float*)d_in[11], *Wo1 = (const float*)d_in[12],
             *Wq2 = (const float*)d_in[13], *Wk2 = (const float*)d_in[14],
             *Wv2 = (const float*)d_in[15], *Wo2 = (const float*)d_in[16];
  const float* bq1 = (const float*)d_in[17], *bk1 = (const float*)d_in[18],
             *bv1 = (const float*)d_in[19], *bo1 = (const float*)d_in[20],
             *bq2 = (const float*)d_in[21], *bk2 = (const float*)d_in[22],
             *bv2 = (const float*)d_in[23], *bo2 = (const float*)d_in[24];
  const float* Wf1 = (const float*)d_in[25], *bf1 = (const float*)d_in[26],
             *Wf2 = (const float*)d_in[27], *bf2 = (const float*)d_in[28],
             *g1  = (const float*)d_in[29], *be1 = (const float*)d_in[30],
             *g2  = (const float*)d_in[31], *be2 = (const float*)d_in[32];

  float* wsf = (float*)d_ws;
  float* h     = wsf; wsf += (size_t)MS_*D_;
  float* maskb = wsf; wsf += MS_;
  float* distr = wsf; wsf += (size_t)B_*S_*S_;
  float* adjm  = wsf; wsf += (size_t)B_*S_*S_;
  float* slab  = wsf; wsf += (size_t)MS_*DH_;     // 2 bf16 slots (o1,o2)
  // bf16 region
  u16* bb = (u16*)wsf;
  u16* h_bf    = bb; bb += (size_t)MS_*D_;
  u16* pooled_bf = bb; bb += (size_t)B_*NSUB_*D_;
  u16* globWt  = bb; bb += (size_t)D_*D_;
  u16* wq1t = bb; bb += (size_t)L_*DH_*DH_;
  u16* wk1t = bb; bb += (size_t)L_*DH_*DH_;
  u16* wv1t = bb; bb += (size_t)L_*DH_*DH_;
  u16* wo1t = bb; bb += (size_t)L_*DH_*DH_;
  u16* wq2t = bb; bb += (size_t)L_*DH_*DH_;
  u16* wk2t = bb; bb += (size_t)L_*DH_*DH_;
  u16* wv2t = bb; bb += (size_t)L_*DH_*DH_;
  u16* wo2t = bb; bb += (size_t)L_*DH_*DH_;
  u16* wf1t = bb; bb += (size_t)L_*D_*DFF_;       // [L][512][256]
  u16* wf2t = bb; bb += (size_t)L_*DFF_*D_;       // [L][256][512]
  u16* o1_bf = (u16*)slab;
  u16* o2_bf = o1_bf + (size_t)MS_*DH_;

  embed_kernel<<<MS_/4, 256, 0, stream>>>(x, embW, embB, h, h_bf, maskb);
  adjrescale_kernel<<<(B_*S_*S_)/256, 256, 0, stream>>>(adj, dist, maskb, adjm, distr);
  {
    TDs td;
    const float* S8[8] = {Wq1, Wk1, Wv1, Wo1, Wq2, Wk2, Wv2, Wo2};
    u16* D8[8] = {wq1t, wk1t, wv1t, wo1t, wq2t, wk2t, wv2t, wo2t};
    for(int i = 0; i < 8; i++) td.d[i] = {S8[i], D8[i], DH_, DH_, L_};
    td.d[8]  = {Wf1, wf1t, D_, DFF_, L_};
    td.d[9]  = {Wf2, wf2t, DFF_, D_, L_};
    td.d[10] = {globW, globWt, D_, D_, 1};
    transpose_all_kernel<<<dim3(16,16,11), dim3(32,8), 0, stream>>>(td);
  }

  for(int l = 0; l < L_; l++){
    QAArgs a1 = { wq1t + (size_t)l*DH_*DH_, wk1t + (size_t)l*DH_*DH_, wv1t + (size_t)l*DH_*DH_,
                  bq1 + (size_t)l*DH_, bk1 + (size_t)l*DH_, bv1 + (size_t)l*DH_ };
    QAArgs a2 = { wq2t + (size_t)l*DH_*DH_, wk2t + (size_t)l*DH_*DH_, wv2t + (size_t)l*DH_*DH_,
                  bq2 + (size_t)l*DH_, bk2 + (size_t)l*DH_, bv2 + (size_t)l*DH_ };
    qkv_attn_kernel<<<dim3(B_*H_, 2), 256, 0, stream>>>(h_bf, a1, a2, adjm, distr, maskb,
                                                        o1_bf, o2_bf);
    TailArgs ta;
    ta.o1 = o1_bf; ta.o2 = o2_bf;
    ta.wo1 = wo1t + (size_t)l*DH_*DH_; ta.wo2 = wo2t + (size_t)l*DH_*DH_;
    ta.w1 = wf1t + (size_t)l*D_*DFF_;  ta.w2 = wf2t + (size_t)l*DFF_*D_;
    ta.bo1 = bo1 + (size_t)l*DH_; ta.bo2 = bo2 + (size_t)l*DH_;
    ta.bf1 = bf1 + (size_t)l*DFF_; ta.bf2 = bf2 + (size_t)l*D_;
    ta.g1 = g1 + (size_t)l*D_; ta.be1 = be1 + (size_t)l*D_;
    ta.g2 = g2 + (size_t)l*D_; ta.be2 = be2 + (size_t)l*D_;
    ta.h = h; ta.h_bf = h_bf;
    tail_kernel<<<MS_/32, 512, 0, stream>>>(ta);
  }

  pool_kernel<<<B_*NSUB_, 256, 0, stream>>>(amm, sum_a, h, pooled_bf);
  // final: relu(pooled @ glob_W + glob_b), M=2048 N=256 K=256
  {
    MG6 a;
    a.g[0].A = pooled_bf; a.g[0].W = globWt;
    a.g[0].bias = globB; a.g[0].C = (float*)d_out;
    a.g[0].lda = D_; a.g[0].K = D_; a.g[0].ldc = D_;
    a.g[0].aofs = 0; a.g[0].cofs = 0;
    mgemm_kernel<64,false,1><<<dim3((B_*NSUB_)/64, D_/128, 1), 256, 0, stream>>>(a);
  }
}